// Round 10
// baseline (699.036 us; speedup 1.0000x reference)
//
#include <hip/hip_runtime.h>
#include <hip/hip_bf16.h>
#include <float.h>
#include <math.h>

#define B 32
#define NN 999
#define S 1000
#define D 128
#define F 512
#define L 6
#define EPSN 1e-5f
#define WSTR 180224   // per-layer bf16 weight stride: 3*16384 + 2*65536

typedef __attribute__((ext_vector_type(4))) float f32x4;
typedef __attribute__((ext_vector_type(4))) short s16x4;
typedef __attribute__((ext_vector_type(8))) short s16x8;

#if defined(__has_builtin)
#if __has_builtin(__builtin_amdgcn_mfma_f32_16x16x16bf16_1k)
#define HAVE_MFMA16 1
#endif
#if __has_builtin(__builtin_amdgcn_mfma_f32_16x16x32_bf16)
#define HAVE_MFMA32 1
#endif
#endif

#ifdef HAVE_MFMA16
#define MFMA16(a, b, c) __builtin_amdgcn_mfma_f32_16x16x16bf16_1k((a), (b), (c), 0, 0, 0)
#else
static __device__ __forceinline__ f32x4 mfma16_asm(s16x4 a, s16x4 b, f32x4 c) {
    asm volatile("v_mfma_f32_16x16x16_bf16 %0, %1, %2, %0\n\ts_nop 7\n\ts_nop 7"
                 : "+v"(c) : "v"(a), "v"(b));
    return c;
}
#define MFMA16(a, b, c) mfma16_asm((a), (b), (c))
#endif

#ifdef HAVE_MFMA32
#define MFMA32(a, b, c) __builtin_amdgcn_mfma_f32_16x16x32_bf16((a), (b), (c), 0, 0, 0)
#else
static __device__ __forceinline__ f32x4 mfma32_asm(s16x8 a, s16x8 b, f32x4 c) {
    asm volatile("v_mfma_f32_16x16x32_bf16 %0, %1, %2, %0\n\ts_nop 7\n\ts_nop 7"
                 : "+v"(c) : "v"(a), "v"(b));
    return c;
}
#define MFMA32(a, b, c) mfma32_asm((a), (b), (c))
#endif

__device__ __forceinline__ float n2n(float v) {
    if (v != v) return 0.f;
    if (isinf(v)) return v > 0.f ? FLT_MAX : -FLT_MAX;
    return v;
}

__device__ __forceinline__ unsigned short f2bf(float x) {
    unsigned u = __float_as_uint(x);
    return (unsigned short)((u + 0x7fffu + ((u >> 16) & 1u)) >> 16);
}

__device__ __forceinline__ float bf2f(unsigned short v) {
    return __uint_as_float(((unsigned)v) << 16);
}

// ---------------- one-time: weights -> bf16 ----------------
// layout per layer (stride WSTR): Wq 0, Wk 16384, Wv 32768, W1 49152, W2 114688
__global__ __launch_bounds__(256) void k_wprep(
        const float* __restrict__ Wq, const float* __restrict__ Wk,
        const float* __restrict__ Wv, const float* __restrict__ W1,
        const float* __restrict__ W2, unsigned short* __restrict__ wbf) {
    int bx = blockIdx.x, l = blockIdx.y;
    const float* src; int doff, off;
    if (bx < 8)       { src = Wq + (size_t)l * 16384; doff = 0;      off = bx * 2048; }
    else if (bx < 16) { src = Wk + (size_t)l * 16384; doff = 16384;  off = (bx - 8) * 2048; }
    else if (bx < 24) { src = Wv + (size_t)l * 16384; doff = 32768;  off = (bx - 16) * 2048; }
    else if (bx < 56) { src = W1 + (size_t)l * 65536; doff = 49152;  off = (bx - 24) * 2048; }
    else              { src = W2 + (size_t)l * 65536; doff = 114688; off = (bx - 56) * 2048; }
    int i = off + threadIdx.x * 8;
    float4 a4 = *(const float4*)(src + i);
    float4 b4 = *(const float4*)(src + i + 4);
    s16x8 p = {(short)f2bf(a4.x), (short)f2bf(a4.y), (short)f2bf(a4.z), (short)f2bf(a4.w),
               (short)f2bf(b4.x), (short)f2bf(b4.y), (short)f2bf(b4.z), (short)f2bf(b4.w)};
    *(s16x8*)(wbf + (size_t)l * WSTR + doff + i) = p;
}

// ---------------- one-time prep: dist -> bf16 padded ----------------
__global__ __launch_bounds__(256) void k_prep(
        const float* __restrict__ dist, unsigned short* __restrict__ nd) {
    int row = blockIdx.x;
    int col = threadIdx.x * 4;
    unsigned short* op = nd + (size_t)row * 1024 + col;
    if (col < 1000) {
        float4 v = *(const float4*)(dist + (size_t)row * 1000 + col);
        s16x4 p = {(short)f2bf(v.x), (short)f2bf(v.y), (short)f2bf(v.z), (short)f2bf(v.w)};
        *(s16x4*)op = p;
    } else {
        s16x4 z = {0, 0, 0, 0};
        *(s16x4*)op = z;
    }
}

__global__ __launch_bounds__(128) void k_embed(
        const float* __restrict__ depot, const float* __restrict__ node,
        const float* __restrict__ Wd, const float* __restrict__ bd,
        const float* __restrict__ Wn, const float* __restrict__ bn,
        float* __restrict__ x) {
    int row = blockIdx.x;
    int b = row / S, s = row % S;
    int d = threadIdx.x;
    float o;
    if (s == 0) {
        float x0 = depot[b * 2 + 0], x1 = depot[b * 2 + 1];
        o = Wd[d * 2 + 0] * x0 + Wd[d * 2 + 1] * x1 + bd[d];
    } else {
        const float* p = node + ((size_t)b * NN + (s - 1)) * 3;
        o = Wn[d * 3 + 0] * p[0] + Wn[d * 3 + 1] * p[1] + Wn[d * 3 + 2] * p[2] + bn[d];
    }
    x[(size_t)row * D + d] = o;
}

__global__ __launch_bounds__(128) void k_rowxform(
        float* __restrict__ x, const float* __restrict__ W,
        const float* __restrict__ bias, const int* __restrict__ flag, int mode) {
    int b = blockIdx.x;
    int d = threadIdx.x;
    __shared__ float row[D];
    int r = (mode == 0) ? 1 : (1 - flag[b]) * NN;
    float* xr = x + ((size_t)b * S + r) * D;
    row[d] = xr[d];
    __syncthreads();
    float acc = bias[d];
    for (int e = 0; e < D; e += 4) {
        const float4 w = *(const float4*)(W + (size_t)d * D + e);
        acc += w.x * row[e] + w.y * row[e + 1] + w.z * row[e + 2] + w.w * row[e + 3];
    }
    xr[d] = acc;
}

// ---------------- qkv: norm-fused input, LDS-staged bf16 weights, coalesced swizzled mT ----------------
__global__ __launch_bounds__(256) void k_qkv(
        const float* __restrict__ yprev, const float* __restrict__ part2, int hasnorm,
        const float* __restrict__ gp, const float* __restrict__ bp,
        const unsigned short* __restrict__ wl,
        unsigned short* __restrict__ sqb, unsigned short* __restrict__ mT) {
    int blk = blockIdx.x;
    int b = blk >> 4, rb = blk & 15;
    int s0 = rb * 64;
    int tid = threadIdx.x, lane = tid & 63, wid = tid >> 6;
    __shared__ __align__(16) unsigned short lds[18432];  // xs[64*40]+wt[3][128*40]; reused tile[256*72]
    __shared__ float nsc[128], nsh[128];
    __shared__ float accv[256];
    unsigned short* xs = lds;
    unsigned short* wt0 = lds + 2560;

    if (hasnorm) {
        int st = tid >> 7, d = tid & 127;
        float s = 0.f;
#pragma unroll
        for (int c = 0; c < 16; c++) s += part2[(size_t)(b * 32 + c * 2 + st) * 128 + d];
        accv[tid] = s;
    }
    __syncthreads();
    if (tid < 128) {
        float scv = 1.f, shv = 0.f;
        if (hasnorm) {
            float mu = accv[tid] * (1.f / S);
            float var = accv[128 + tid] * (1.f / S) - mu * mu;
            float rs = rsqrtf(var + EPSN);
            scv = rs * gp[tid];
            shv = bp[tid] - mu * scv;
        }
        nsc[tid] = scv; nsh[tid] = shv;
    }
    __syncthreads();

    f32x4 acc[3][8];
#pragma unroll
    for (int mm = 0; mm < 3; mm++)
#pragma unroll
        for (int cf = 0; cf < 8; cf++) acc[mm][cf] = {0.f, 0.f, 0.f, 0.f};

    for (int k0 = 0; k0 < D; k0 += 32) {
        {
            int i = tid >> 2, kq = (tid & 3) * 8;
            int s = s0 + i;
            int gs = s < S ? s : S - 1;
            const float* gpx = yprev + ((size_t)b * S + gs) * D + k0 + kq;
            float4 a4 = *(const float4*)gpx;
            float4 b4 = *(const float4*)(gpx + 4);
            const float* scp = &nsc[k0 + kq];
            const float* shp = &nsh[k0 + kq];
            s16x4 p0 = {(short)f2bf(a4.x * scp[0] + shp[0]), (short)f2bf(a4.y * scp[1] + shp[1]),
                        (short)f2bf(a4.z * scp[2] + shp[2]), (short)f2bf(a4.w * scp[3] + shp[3])};
            s16x4 p1 = {(short)f2bf(b4.x * scp[4] + shp[4]), (short)f2bf(b4.y * scp[5] + shp[5]),
                        (short)f2bf(b4.z * scp[6] + shp[6]), (short)f2bf(b4.w * scp[7] + shp[7])};
            *(s16x4*)&xs[i * 40 + kq] = p0;
            *(s16x4*)&xs[i * 40 + kq + 4] = p1;
        }
#pragma unroll
        for (int u0 = 0; u0 < 6; u0++) {
            int u = tid + u0 * 256;
            int mm = u >> 9;
            int v = u & 511;
            int c = v >> 2, kq = (v & 3) * 8;
            s16x8 w = *(const s16x8*)(wl + (size_t)mm * 16384 + (size_t)c * D + k0 + kq);
            *(s16x8*)&wt0[mm * 5120 + c * 40 + kq] = w;
        }
        __syncthreads();
#pragma unroll
        for (int ks = 0; ks < 2; ks++) {
            int ko = ks * 16 + (lane >> 4) * 4;
            s16x4 a = *(const s16x4*)&xs[(wid * 16 + (lane & 15)) * 40 + ko];
#pragma unroll
            for (int mm = 0; mm < 3; mm++)
#pragma unroll
                for (int cf = 0; cf < 8; cf++) {
                    s16x4 bf = *(const s16x4*)&wt0[mm * 5120 + (cf * 16 + (lane & 15)) * 40 + ko];
                    acc[mm][cf] = MFMA16(a, bf, acc[mm][cf]);
                }
        }
        __syncthreads();
    }

    // epilogue phase 1: acc -> tile[256 d][72]  (stride 72 shorts = 144 B, 16B-aligned rows)
    unsigned short* tile = lds;               // 256*72 = 18432
    int sl0 = wid * 16 + (lane >> 4) * 4;     // local k
#pragma unroll
    for (int cf = 0; cf < 8; cf++) {
        int d = cf * 16 + (lane & 15);
        s16x4 p0, p1;
#pragma unroll
        for (int r = 0; r < 4; r++) {
            int s = s0 + sl0 + r;
            if (s < S) {
                float qv = acc[0][cf][r], kv = acc[1][cf][r], vv = acc[2][cf][r];
                float ek = __expf(kv);
                sqb[((size_t)b * S + s) * D + d] = f2bf(1.f / (1.f + __expf(-qv)));
                p0[r] = (short)f2bf(ek * vv);
                p1[r] = (short)f2bf(ek);
            } else { p0[r] = 0; p1[r] = 0; }
        }
        *(s16x4*)&tile[d * 72 + sl0] = p0;
        *(s16x4*)&tile[(d + 128) * 72 + sl0] = p1;
    }
    __syncthreads();
    // epilogue phase 2: permuted read, fully coalesced 32KB store
    {
        unsigned short* base = mT + (((size_t)b * 16 + rb) * 256) * 64;
#pragma unroll
        for (int j = 0; j < 8; j++) {
            int u = j * 256 + tid;
            int d = u >> 3, sp = u & 7;
            int o = sp ^ (d & 7);
            s16x8 v = *(const s16x8*)&tile[d * 72 + o * 8];
            *(s16x8*)(base + (size_t)u * 8) = v;
        }
    }
}

// ---------------- attention: 128 rows/block, rf=2 per wave, num/den wave split ----------------
__global__ __launch_bounds__(512, 2) void k_attn(
        const float* __restrict__ yprev, const float* __restrict__ part2, int hasnorm,
        const float* __restrict__ gp, const float* __restrict__ bp,
        const unsigned short* __restrict__ sqb,
        const unsigned short* __restrict__ mT, const unsigned short* __restrict__ nd,
        const float* __restrict__ log_scale, const float* __restrict__ alpha, int l,
        float* __restrict__ y, float* __restrict__ part) {
    int blk0 = blockIdx.x;
    int blk = (blk0 & 7) * 32 + (blk0 >> 3);  // XCD-bijective swizzle (256 % 8 == 0)
    int b = blk >> 3, ib = blk & 7;
    int i0 = ib * 128;
    int tid = threadIdx.x, lane = tid & 63, wid = tid >> 6;
    int wr = wid & 3, wh = wid >> 2;          // row group (32 rows), cf half (0=num, 1=den)
    __shared__ __align__(16) unsigned short esL[128 * 64];  // 16 KB swizzled
    __shared__ __align__(16) unsigned short mtL[256 * 64];  // 32 KB; reused f32[64][128] per rf-half
    __shared__ float accvA[256];
    float sc = log_scale[0] * alpha[l];

    if (hasnorm && tid < 256) {
        int st = tid >> 7, d = tid & 127;
        float s = 0.f;
#pragma unroll
        for (int c = 0; c < 16; c++) s += part2[(size_t)(b * 32 + c * 2 + st) * 128 + d];
        accvA[tid] = s;
    }
    __syncthreads();

    float rsc[8], rsh[8];
#pragma unroll
    for (int cf = 0; cf < 8; cf++) {
        int d = cf * 16 + (lane & 15);
        float scv = 1.f, shv = 0.f;
        if (hasnorm) {
            float mu = accvA[d] * (1.f / S);
            float var = accvA[128 + d] * (1.f / S) - mu * mu;
            float rs = rsqrtf(var + EPSN);
            scv = rs * gp[d];
            shv = bp[d] - mu * scv;
        }
        rsc[cf] = scv; rsh[cf] = shv;
    }

    f32x4 acc[2][8];
#pragma unroll
    for (int rf = 0; rf < 2; rf++)
#pragma unroll
        for (int cf = 0; cf < 8; cf++) acc[rf][cf] = {0.f, 0.f, 0.f, 0.f};

    // es staging: row = tid>>2 (128 rows), 2 octets/thread
    int erow = tid >> 2;
    int gi = i0 + erow; if (gi > 999) gi = 999;
    const unsigned short* ndr = nd + (size_t)b * 1000 * 1024 + (size_t)gi * 1024 + (tid & 3) * 16;
    const unsigned short* mtb = mT + (size_t)b * 16 * 16384;
    int eg = (tid & 3) * 2;
    unsigned short* esw0 = &esL[erow * 64 + ((eg ^ (erow & 7)) * 8)];
    unsigned short* esw1 = &esL[erow * 64 + (((eg + 1) ^ (erow & 7)) * 8)];

    s16x8 cnA = *(const s16x8*)(ndr);
    s16x8 cnB = *(const s16x8*)(ndr + 8);
    s16x8 cm[4];
#pragma unroll
    for (int j = 0; j < 4; j++)
        cm[j] = *(const s16x8*)(mtb + (size_t)(j * 512 + tid) * 8);

    for (int kc = 0; kc < 16; kc++) {
        s16x8 o0, o1;
#pragma unroll
        for (int j = 0; j < 8; j++) {
            o0[j] = (short)f2bf(__expf(-sc * bf2f((unsigned short)cnA[j])));
            o1[j] = (short)f2bf(__expf(-sc * bf2f((unsigned short)cnB[j])));
        }
        int kn = kc < 15 ? kc + 1 : 15;
        cnA = *(const s16x8*)(ndr + kn * 64);
        cnB = *(const s16x8*)(ndr + kn * 64 + 8);
        __syncthreads();
        *(s16x8*)esw0 = o0;
        *(s16x8*)esw1 = o1;
#pragma unroll
        for (int j = 0; j < 4; j++)
            *(s16x8*)&mtL[(j * 512 + tid) * 8] = cm[j];
#pragma unroll
        for (int j = 0; j < 4; j++)
            cm[j] = *(const s16x8*)(mtb + (size_t)kn * 16384 + (size_t)(j * 512 + tid) * 8);
        __syncthreads();
#pragma unroll
        for (int ks = 0; ks < 2; ks++) {
            int ag = ks * 4 + (lane >> 4);
            int arow0 = wr * 32 + (lane & 15);
            int arow1 = arow0 + 16;
            s16x8 a0 = *(const s16x8*)&esL[arow0 * 64 + ((ag ^ (arow0 & 7)) * 8)];
            s16x8 a1 = *(const s16x8*)&esL[arow1 * 64 + ((ag ^ (arow1 & 7)) * 8)];
            __builtin_amdgcn_s_setprio(1);
#pragma unroll
            for (int cf = 0; cf < 8; cf++) {
                int c = cf * 16 + wh * 128 + (lane & 15);
                s16x8 bf = *(const s16x8*)&mtL[c * 64 + ((ag ^ (c & 7)) * 8)];
                acc[0][cf] = MFMA32(a0, bf, acc[0][cf]);
                acc[1][cf] = MFMA32(a1, bf, acc[1][cf]);
            }
            __builtin_amdgcn_s_setprio(0);
        }
    }

    // epilogue: two rf-halves; den waves publish via LDS, num waves finish + stats
    float sacc[8], s2acc[8];
#pragma unroll
    for (int cf = 0; cf < 8; cf++) { sacc[cf] = 0.f; s2acc[cf] = 0.f; }
    float* pw = (float*)mtL;                  // [64 local rows][128 d] f32 = 32 KB
#pragma unroll
    for (int rf = 0; rf < 2; rf++) {
        __syncthreads();
        if (wh == 1) {
#pragma unroll
            for (int cf = 0; cf < 8; cf++) {
                int c = cf * 16 + (lane & 15);
#pragma unroll
                for (int r = 0; r < 4; r++) {
                    int lrow = wr * 16 + (lane >> 4) * 4 + r;
                    pw[lrow * 128 + c] = acc[rf][cf][r];
                }
            }
        }
        __syncthreads();
        if (wh == 0) {
#pragma unroll
            for (int cf = 0; cf < 8; cf++) {
                int d = cf * 16 + (lane & 15);
#pragma unroll
                for (int r = 0; r < 4; r++) {
                    int lrow = wr * 16 + (lane >> 4) * 4 + r;
                    int i = i0 + wr * 32 + rf * 16 + (lane >> 4) * 4 + r;
                    if (i < S) {
                        size_t off = ((size_t)b * S + i) * D + d;
                        float w = n2n(acc[rf][cf][r]) / n2n(pw[lrow * 128 + d]);
                        float xv = yprev[off] * rsc[cf] + rsh[cf];
                        float yv = xv + bf2f(sqb[off]) * w;
                        y[off] = yv;
                        sacc[cf] += yv;
                        s2acc[cf] = fmaf(yv, yv, s2acc[cf]);
                    }
                }
            }
        }
    }
    __syncthreads();
    float* sw = (float*)esL;                  // stats partials [8][128] = 4 KB
    if (wh == 0) {
#pragma unroll
        for (int cf = 0; cf < 8; cf++) {
            int d = cf * 16 + (lane & 15);
            float s = sacc[cf], s2 = s2acc[cf];
            s += __shfl_xor(s, 16); s += __shfl_xor(s, 32);
            s2 += __shfl_xor(s2, 16); s2 += __shfl_xor(s2, 32);
            if (lane < 16) {
                sw[(wr * 2 + 0) * 128 + d] = s;
                sw[(wr * 2 + 1) * 128 + d] = s2;
            }
        }
    }
    __syncthreads();
    if (tid < 256) {
        int st = tid >> 7, d = tid & 127;
        float v = sw[(0 * 2 + st) * 128 + d] + sw[(1 * 2 + st) * 128 + d] +
                  sw[(2 * 2 + st) * 128 + d] + sw[(3 * 2 + st) * 128 + d];
        part[((size_t)(b * 8 + ib) * 2 + st) * 128 + d] = v;
    }
}

// ---------------- fused FFN: norm(part1,8chunks) -> relu(h@W1^T+b) in LDS -> @W2^T + residual ----------------
__global__ __launch_bounds__(256) void k_ffn(
        const float* __restrict__ ya, const float* __restrict__ part1,
        const float* __restrict__ gp, const float* __restrict__ bp,
        const unsigned short* __restrict__ w1b, const unsigned short* __restrict__ w2b,
        const float* __restrict__ bW1, const float* __restrict__ bW2,
        float* __restrict__ yb, float* __restrict__ part) {
    int blk = blockIdx.x;
    int b = blk >> 4, rb = blk & 15;
    int r0 = rb * 64;
    int tid = threadIdx.x, lane = tid & 63, wid = tid >> 6;
    __shared__ __align__(16) unsigned short hs[64 * 128];    // normed h bf16, octet-swizzled
    __shared__ __align__(16) unsigned short w1c[64 * 128];   // W1 chunk [64 f][128 k], swizzled
    __shared__ __align__(16) unsigned short tc[64 * 72];     // t chunk [64 row][64 f], stride 144B
    __shared__ __align__(16) unsigned short w2c[128 * 64];   // W2 chunk [128 d][64 f], swizzled
    __shared__ float nsc[128], nsh[128];
    __shared__ float accv[256];

    {
        int st = tid >> 7, d = tid & 127;
        float s = 0.f;
#pragma unroll
        for (int c = 0; c < 8; c++) s += part1[(size_t)(b * 8 + c) * 256 + st * 128 + d];
        accv[tid] = s;
    }
    __syncthreads();
    if (tid < 128) {
        float mu = accv[tid] * (1.f / S);
        float var = accv[128 + tid] * (1.f / S) - mu * mu;
        float rs = rsqrtf(var + EPSN);
        float scv = rs * gp[tid];
        nsc[tid] = scv;
        nsh[tid] = bp[tid] - mu * scv;
    }
    __syncthreads();

    // stage normed h (64 rows x 128 k), octet-swizzled
    {
        int i = tid >> 2;
        int gs = r0 + i; if (gs >= S) gs = S - 1;
        const float* gpx = ya + ((size_t)b * S + gs) * D;
#pragma unroll
        for (int q = 0; q < 4; q++) {
            int col = (tid & 3) * 32 + q * 8;
            int g = col >> 3;
            float4 a4 = *(const float4*)(gpx + col);
            float4 b4 = *(const float4*)(gpx + col + 4);
            const float* scp = &nsc[col];
            const float* shp = &nsh[col];
            s16x4 p0 = {(short)f2bf(a4.x * scp[0] + shp[0]), (short)f2bf(a4.y * scp[1] + shp[1]),
                        (short)f2bf(a4.z * scp[2] + shp[2]), (short)f2bf(a4.w * scp[3] + shp[3])};
            s16x4 p1 = {(short)f2bf(b4.x * scp[4] + shp[4]), (short)f2bf(b4.y * scp[5] + shp[5]),
                        (short)f2bf(b4.z * scp[6] + shp[6]), (short)f2bf(b4.w * scp[7] + shp[7])};
            int base = i * 128 + ((g ^ (i & 7)) * 8);
            *(s16x4*)&hs[base] = p0;
            *(s16x4*)&hs[base + 4] = p1;
        }
    }

    f32x4 yacc[8];
#pragma unroll
    for (int cf = 0; cf < 8; cf++) yacc[cf] = {0.f, 0.f, 0.f, 0.f};

    for (int fc = 0; fc < 8; fc++) {
        int c0 = fc * 64;
        // stage W1 chunk [64 f][128 k], swizzled
        {
            int f = tid >> 2;
#pragma unroll
            for (int q = 0; q < 4; q++) {
                int col = (tid & 3) * 32 + q * 8;
                int g = col >> 3;
                s16x8 w = *(const s16x8*)(w1b + (size_t)(c0 + f) * D + col);
                *(s16x8*)&w1c[f * 128 + ((g ^ (f & 7)) * 8)] = w;
            }
        }
        // stage W2 chunk [128 d][64 f], swizzled
        {
            int d2 = tid >> 1;
#pragma unroll
            for (int q = 0; q < 4; q++) {
                int g = (tid & 1) * 4 + q;
                s16x8 w = *(const s16x8*)(w2b + (size_t)d2 * F + c0 + g * 8);
                *(s16x8*)&w2c[d2 * 64 + ((g ^ (d2 & 7)) * 8)] = w;
            }
        }
        __syncthreads();
        // GEMM1: t = relu(h @ W1c^T + bW1)
        f32x4 tacc[4];
#pragma unroll
        for (int c4 = 0; c4 < 4; c4++) tacc[c4] = {0.f, 0.f, 0.f, 0.f};
#pragma unroll
        for (int ks = 0; ks < 4; ks++) {
            int g = ks * 4 + (lane >> 4);
            int arow = wid * 16 + (lane & 15);
            s16x8 a = *(const s16x8*)&hs[arow * 128 + ((g ^ (arow & 7)) * 8)];
#pragma unroll
            for (int c4 = 0; c4 < 4; c4++) {
                int brow = c4 * 16 + (lane & 15);
                s16x8 bf = *(const s16x8*)&w1c[brow * 128 + ((g ^ (brow & 7)) * 8)];
                tacc[c4] = MFMA32(a, bf, tacc[c4]);
            }
        }
#pragma unroll
        for (int c4 = 0; c4 < 4; c4++) {
            int col = c4 * 16 + (lane & 15);
            float bias = bW1[c0 + col];
#pragma unroll
            for (int r = 0; r < 4; r++) {
                int rl = wid * 16 + (lane >> 4) * 4 + r;
                tc[rl * 72 + col] = f2bf(fmaxf(tacc[c4][r] + bias, 0.f));
            }
        }
        __syncthreads();
        // GEMM2: yacc += t @ W2c^T
#pragma unroll
        for (int ks = 0; ks < 2; ks++) {
            int ko = ks * 32 + (lane >> 4) * 8;
            int g = ks * 4 + (lane >> 4);
            s16x8 a = *(const s16x8*)&tc[(wid * 16 + (lane & 15)) * 72 + ko];
#pragma unroll
            for (int cf = 0; cf < 8; cf++) {
                int brow = cf * 16 + (lane & 15);
                s16x8 bf = *(const s16x8*)&w2c[brow * 64 + ((g ^ (brow & 7)) * 8)];
                yacc[cf] = MFMA32(a, bf, yacc[cf]);
            }
        }
        __syncthreads();
    }

    // epilogue: yb = h + ff + bias, stats
    float* pw = (float*)w1c;
#pragma unroll
    for (int cf = 0; cf < 8; cf++) {
        int d = cf * 16 + (lane & 15);
        float bias = bW2[d];
        float s = 0.f, s2 = 0.f;
#pragma unroll
        for (int r = 0; r < 4; r++) {
            int rl = wid * 16 + (lane >> 4) * 4 + r;
            int row = r0 + rl;
            if (row < S) {
                float hval = bf2f(hs[rl * 128 + (((d >> 3) ^ (rl & 7)) * 8) + (d & 7)]);
                float yv = hval + yacc[cf][r] + bias;
                yb[((size_t)b * S + row) * D + d] = yv;
                s += yv;
                s2 = fmaf(yv, yv, s2);
            }
        }
        s += __shfl_xor(s, 16); s += __shfl_xor(s, 32);
        s2 += __shfl_xor(s2, 16); s2 += __shfl_xor(s2, 32);
        if (lane < 16) {
            pw[(wid * 2 + 0) * 128 + d] = s;
            pw[(wid * 2 + 1) * 128 + d] = s2;
        }
    }
    __syncthreads();
    {
        int st = tid >> 7, d = tid & 127;
        float v = pw[(0 * 2 + st) * 128 + d] + pw[(1 * 2 + st) * 128 + d] +
                  pw[(2 * 2 + st) * 128 + d] + pw[(3 * 2 + st) * 128 + d];
        part[((size_t)(b * 16 + rb) * 2 + st) * 128 + d] = v;
    }
}

// ---------------- final reduce + norm ----------------
__global__ __launch_bounds__(256) void k_finalize(
        const float* __restrict__ part, float* __restrict__ acc) {
    int i = blockIdx.x * 256 + threadIdx.x;
    int b = i >> 8, k = i & 255;
    float s = 0.f;
#pragma unroll
    for (int c = 0; c < 16; c++) s += part[(size_t)(b * 16 + c) * 256 + k];
    acc[i] = s;
}

__global__ __launch_bounds__(256) void k_norm(
        const float* __restrict__ y, const float* __restrict__ acc,
        const float* __restrict__ g, const float* __restrict__ bb,
        float* __restrict__ out) {
    size_t i = (size_t)blockIdx.x * 256 + threadIdx.x;
    int d = (int)(i % D);
    int b = (int)(i / ((size_t)S * D));
    float mu = acc[b * 256 + d] * (1.f / S);
    float var = acc[b * 256 + 128 + d] * (1.f / S) - mu * mu;
    float v = (y[i] - mu) * rsqrtf(var + EPSN);
    out[i] = v * g[d] + bb[d];
}

extern "C" void kernel_launch(void* const* d_in, const int* in_sizes, int n_in,
                              void* d_out, int out_size, void* d_ws, size_t ws_size,
                              hipStream_t stream) {
    const float* depot = (const float*)d_in[0];
    const float* node  = (const float*)d_in[1];
    const float* dist  = (const float*)d_in[2];
    const float* log_scale = (const float*)d_in[3];
    const int*   flag  = (const int*)d_in[4];
    const float* Wd   = (const float*)d_in[5];
    const float* bd   = (const float*)d_in[6];
    const float* Wn   = (const float*)d_in[7];
    const float* bn   = (const float*)d_in[8];
    const float* Win  = (const float*)d_in[9];
    const float* bin_ = (const float*)d_in[10];
    const float* Wout = (const float*)d_in[11];
    const float* bout = (const float*)d_in[12];
    const float* Wq   = (const float*)d_in[13];
    const float* Wk   = (const float*)d_in[14];
    const float* Wv   = (const float*)d_in[15];
    const float* alpha= (const float*)d_in[16];
    const float* g1   = (const float*)d_in[17];
    const float* b1   = (const float*)d_in[18];
    const float* W1   = (const float*)d_in[19];
    const float* bW1  = (const float*)d_in[20];
    const float* W2   = (const float*)d_in[21];
    const float* bW2  = (const float*)d_in[22];
    const float* g2   = (const float*)d_in[23];
    const float* b2   = (const float*)d_in[24];

    float* ws = (float*)d_ws;
    size_t nxd = (size_t)B * S * D;                       // 4,096,000
    float* ya    = ws;
    float* yb    = ws + nxd;
    float* part1 = ws + 2 * nxd;                          // B*8*256 (alloc 131072)
    float* part2 = part1 + 131072;                        // B*16*256
    float* accb2 = part2 + 131072;                        // B*256
    unsigned short* sqb = (unsigned short*)(accb2 + 8192);          // B*S*D bf16
    unsigned short* mT  = sqb + nxd;                                // B*16*256*64
    unsigned short* wbf = mT + (size_t)B * 16 * 256 * 64;           // L*WSTR
    unsigned short* nd  = wbf + (size_t)L * WSTR;                   // B*1000*1024

    k_wprep<<<dim3(88, 6), 256, 0, stream>>>(Wq, Wk, Wv, W1, W2, wbf);
    k_prep<<<B * S, 256, 0, stream>>>(dist, nd);
    k_embed<<<B * S, 128, 0, stream>>>(depot, node, Wd, bd, Wn, bn, yb);
    k_rowxform<<<B, 128, 0, stream>>>(yb, Win, bin_, flag, 0);
    k_rowxform<<<B, 128, 0, stream>>>(yb, Wout, bout, flag, 1);

    for (int l = 0; l < L; l++) {
        int hasnorm = (l > 0) ? 1 : 0;
        const float* gpn = g2 + (l > 0 ? (l - 1) : 0) * D;
        const float* bpn = b2 + (l > 0 ? (l - 1) : 0) * D;
        const unsigned short* wl = wbf + (size_t)l * WSTR;
        k_qkv<<<B * 16, 256, 0, stream>>>(yb, part2, hasnorm, gpn, bpn, wl, sqb, mT);
        k_attn<<<B * 8, 512, 0, stream>>>(yb, part2, hasnorm, gpn, bpn,
                                          sqb, mT, nd, log_scale, alpha, l, ya, part1);
        k_ffn<<<B * 16, 256, 0, stream>>>(ya, part1, g1 + l * D, b1 + l * D,
                                          wl + 49152, wl + 114688,
                                          bW1 + (size_t)l * F, bW2 + (size_t)l * D, yb, part2);
    }
    k_finalize<<<32, 256, 0, stream>>>(part2, accb2);
    k_norm<<<B * S * D / 256, 256, 0, stream>>>(yb, accb2, g2 + 5 * D, b2 + 5 * D, (float*)d_out);
}

// Round 11
// 645.532 us; speedup vs baseline: 1.0829x; 1.0829x over previous
//
#include <hip/hip_runtime.h>
#include <hip/hip_bf16.h>
#include <float.h>
#include <math.h>

#define B 32
#define NN 999
#define S 1000
#define D 128
#define F 512
#define L 6
#define EPSN 1e-5f
#define WSTR 180224   // per-layer bf16 weight stride: 3*16384 + 2*65536

typedef __attribute__((ext_vector_type(4))) float f32x4;
typedef __attribute__((ext_vector_type(4))) short s16x4;
typedef __attribute__((ext_vector_type(8))) short s16x8;

#if defined(__has_builtin)
#if __has_builtin(__builtin_amdgcn_mfma_f32_16x16x16bf16_1k)
#define HAVE_MFMA16 1
#endif
#if __has_builtin(__builtin_amdgcn_mfma_f32_16x16x32_bf16)
#define HAVE_MFMA32 1
#endif
#endif

#ifdef HAVE_MFMA16
#define MFMA16(a, b, c) __builtin_amdgcn_mfma_f32_16x16x16bf16_1k((a), (b), (c), 0, 0, 0)
#else
static __device__ __forceinline__ f32x4 mfma16_asm(s16x4 a, s16x4 b, f32x4 c) {
    asm volatile("v_mfma_f32_16x16x16_bf16 %0, %1, %2, %0\n\ts_nop 7\n\ts_nop 7"
                 : "+v"(c) : "v"(a), "v"(b));
    return c;
}
#define MFMA16(a, b, c) mfma16_asm((a), (b), (c))
#endif

#ifdef HAVE_MFMA32
#define MFMA32(a, b, c) __builtin_amdgcn_mfma_f32_16x16x32_bf16((a), (b), (c), 0, 0, 0)
#else
static __device__ __forceinline__ f32x4 mfma32_asm(s16x8 a, s16x8 b, f32x4 c) {
    asm volatile("v_mfma_f32_16x16x32_bf16 %0, %1, %2, %0\n\ts_nop 7\n\ts_nop 7"
                 : "+v"(c) : "v"(a), "v"(b));
    return c;
}
#define MFMA32(a, b, c) mfma32_asm((a), (b), (c))
#endif

__device__ __forceinline__ float n2n(float v) {
    if (v != v) return 0.f;
    if (isinf(v)) return v > 0.f ? FLT_MAX : -FLT_MAX;
    return v;
}

__device__ __forceinline__ unsigned short f2bf(float x) {
    unsigned u = __float_as_uint(x);
    return (unsigned short)((u + 0x7fffu + ((u >> 16) & 1u)) >> 16);
}

__device__ __forceinline__ float bf2f(unsigned short v) {
    return __uint_as_float(((unsigned)v) << 16);
}

// ---------------- one-time: weights -> bf16 ----------------
// layout per layer (stride WSTR): Wq 0, Wk 16384, Wv 32768, W1 49152, W2 114688
__global__ __launch_bounds__(256) void k_wprep(
        const float* __restrict__ Wq, const float* __restrict__ Wk,
        const float* __restrict__ Wv, const float* __restrict__ W1,
        const float* __restrict__ W2, unsigned short* __restrict__ wbf) {
    int bx = blockIdx.x, l = blockIdx.y;
    const float* src; int doff, off;
    if (bx < 8)       { src = Wq + (size_t)l * 16384; doff = 0;      off = bx * 2048; }
    else if (bx < 16) { src = Wk + (size_t)l * 16384; doff = 16384;  off = (bx - 8) * 2048; }
    else if (bx < 24) { src = Wv + (size_t)l * 16384; doff = 32768;  off = (bx - 16) * 2048; }
    else if (bx < 56) { src = W1 + (size_t)l * 65536; doff = 49152;  off = (bx - 24) * 2048; }
    else              { src = W2 + (size_t)l * 65536; doff = 114688; off = (bx - 56) * 2048; }
    int i = off + threadIdx.x * 8;
    float4 a4 = *(const float4*)(src + i);
    float4 b4 = *(const float4*)(src + i + 4);
    s16x8 p = {(short)f2bf(a4.x), (short)f2bf(a4.y), (short)f2bf(a4.z), (short)f2bf(a4.w),
               (short)f2bf(b4.x), (short)f2bf(b4.y), (short)f2bf(b4.z), (short)f2bf(b4.w)};
    *(s16x8*)(wbf + (size_t)l * WSTR + doff + i) = p;
}

// ---------------- one-time prep: dist -> bf16 padded ----------------
__global__ __launch_bounds__(256) void k_prep(
        const float* __restrict__ dist, unsigned short* __restrict__ nd) {
    int row = blockIdx.x;
    int col = threadIdx.x * 4;
    unsigned short* op = nd + (size_t)row * 1024 + col;
    if (col < 1000) {
        float4 v = *(const float4*)(dist + (size_t)row * 1000 + col);
        s16x4 p = {(short)f2bf(v.x), (short)f2bf(v.y), (short)f2bf(v.z), (short)f2bf(v.w)};
        *(s16x4*)op = p;
    } else {
        s16x4 z = {0, 0, 0, 0};
        *(s16x4*)op = z;
    }
}

__global__ __launch_bounds__(128) void k_embed(
        const float* __restrict__ depot, const float* __restrict__ node,
        const float* __restrict__ Wd, const float* __restrict__ bd,
        const float* __restrict__ Wn, const float* __restrict__ bn,
        float* __restrict__ x) {
    int row = blockIdx.x;
    int b = row / S, s = row % S;
    int d = threadIdx.x;
    float o;
    if (s == 0) {
        float x0 = depot[b * 2 + 0], x1 = depot[b * 2 + 1];
        o = Wd[d * 2 + 0] * x0 + Wd[d * 2 + 1] * x1 + bd[d];
    } else {
        const float* p = node + ((size_t)b * NN + (s - 1)) * 3;
        o = Wn[d * 3 + 0] * p[0] + Wn[d * 3 + 1] * p[1] + Wn[d * 3 + 2] * p[2] + bn[d];
    }
    x[(size_t)row * D + d] = o;
}

__global__ __launch_bounds__(128) void k_rowxform(
        float* __restrict__ x, const float* __restrict__ W,
        const float* __restrict__ bias, const int* __restrict__ flag, int mode) {
    int b = blockIdx.x;
    int d = threadIdx.x;
    __shared__ float row[D];
    int r = (mode == 0) ? 1 : (1 - flag[b]) * NN;
    float* xr = x + ((size_t)b * S + r) * D;
    row[d] = xr[d];
    __syncthreads();
    float acc = bias[d];
    for (int e = 0; e < D; e += 4) {
        const float4 w = *(const float4*)(W + (size_t)d * D + e);
        acc += w.x * row[e] + w.y * row[e + 1] + w.z * row[e + 2] + w.w * row[e + 3];
    }
    xr[d] = acc;
}

// ---------------- qkv: norm-fused input, LDS-staged bf16 weights, coalesced swizzled mT ----------------
__global__ __launch_bounds__(256) void k_qkv(
        const float* __restrict__ yprev, const float* __restrict__ part2, int hasnorm,
        const float* __restrict__ gp, const float* __restrict__ bp,
        const unsigned short* __restrict__ wl,
        unsigned short* __restrict__ sqb, unsigned short* __restrict__ mT) {
    int blk = blockIdx.x;
    int b = blk >> 4, rb = blk & 15;
    int s0 = rb * 64;
    int tid = threadIdx.x, lane = tid & 63, wid = tid >> 6;
    __shared__ __align__(16) unsigned short lds[18432];  // xs[64*40]+wt[3][128*40]; reused tile[256*72]
    __shared__ float nsc[128], nsh[128];
    __shared__ float accv[256];
    unsigned short* xs = lds;
    unsigned short* wt0 = lds + 2560;

    if (hasnorm) {
        int st = tid >> 7, d = tid & 127;
        float s = 0.f;
#pragma unroll
        for (int c = 0; c < 16; c++) s += part2[(size_t)(b * 32 + c * 2 + st) * 128 + d];
        accv[tid] = s;
    }
    __syncthreads();
    if (tid < 128) {
        float scv = 1.f, shv = 0.f;
        if (hasnorm) {
            float mu = accv[tid] * (1.f / S);
            float var = accv[128 + tid] * (1.f / S) - mu * mu;
            float rs = rsqrtf(var + EPSN);
            scv = rs * gp[tid];
            shv = bp[tid] - mu * scv;
        }
        nsc[tid] = scv; nsh[tid] = shv;
    }
    __syncthreads();

    f32x4 acc[3][8];
#pragma unroll
    for (int mm = 0; mm < 3; mm++)
#pragma unroll
        for (int cf = 0; cf < 8; cf++) acc[mm][cf] = {0.f, 0.f, 0.f, 0.f};

    for (int k0 = 0; k0 < D; k0 += 32) {
        {
            int i = tid >> 2, kq = (tid & 3) * 8;
            int s = s0 + i;
            int gs = s < S ? s : S - 1;
            const float* gpx = yprev + ((size_t)b * S + gs) * D + k0 + kq;
            float4 a4 = *(const float4*)gpx;
            float4 b4 = *(const float4*)(gpx + 4);
            const float* scp = &nsc[k0 + kq];
            const float* shp = &nsh[k0 + kq];
            s16x4 p0 = {(short)f2bf(a4.x * scp[0] + shp[0]), (short)f2bf(a4.y * scp[1] + shp[1]),
                        (short)f2bf(a4.z * scp[2] + shp[2]), (short)f2bf(a4.w * scp[3] + shp[3])};
            s16x4 p1 = {(short)f2bf(b4.x * scp[4] + shp[4]), (short)f2bf(b4.y * scp[5] + shp[5]),
                        (short)f2bf(b4.z * scp[6] + shp[6]), (short)f2bf(b4.w * scp[7] + shp[7])};
            *(s16x4*)&xs[i * 40 + kq] = p0;
            *(s16x4*)&xs[i * 40 + kq + 4] = p1;
        }
#pragma unroll
        for (int u0 = 0; u0 < 6; u0++) {
            int u = tid + u0 * 256;
            int mm = u >> 9;
            int v = u & 511;
            int c = v >> 2, kq = (v & 3) * 8;
            s16x8 w = *(const s16x8*)(wl + (size_t)mm * 16384 + (size_t)c * D + k0 + kq);
            *(s16x8*)&wt0[mm * 5120 + c * 40 + kq] = w;
        }
        __syncthreads();
#pragma unroll
        for (int ks = 0; ks < 2; ks++) {
            int ko = ks * 16 + (lane >> 4) * 4;
            s16x4 a = *(const s16x4*)&xs[(wid * 16 + (lane & 15)) * 40 + ko];
#pragma unroll
            for (int mm = 0; mm < 3; mm++)
#pragma unroll
                for (int cf = 0; cf < 8; cf++) {
                    s16x4 bf = *(const s16x4*)&wt0[mm * 5120 + (cf * 16 + (lane & 15)) * 40 + ko];
                    acc[mm][cf] = MFMA16(a, bf, acc[mm][cf]);
                }
        }
        __syncthreads();
    }

    // epilogue phase 1: acc -> tile[256 d][72]  (stride 72 shorts = 144 B, 16B-aligned rows)
    unsigned short* tile = lds;               // 256*72 = 18432
    int sl0 = wid * 16 + (lane >> 4) * 4;     // local k
#pragma unroll
    for (int cf = 0; cf < 8; cf++) {
        int d = cf * 16 + (lane & 15);
        s16x4 p0, p1;
#pragma unroll
        for (int r = 0; r < 4; r++) {
            int s = s0 + sl0 + r;
            if (s < S) {
                float qv = acc[0][cf][r], kv = acc[1][cf][r], vv = acc[2][cf][r];
                float ek = __expf(kv);
                sqb[((size_t)b * S + s) * D + d] = f2bf(1.f / (1.f + __expf(-qv)));
                p0[r] = (short)f2bf(ek * vv);
                p1[r] = (short)f2bf(ek);
            } else { p0[r] = 0; p1[r] = 0; }
        }
        *(s16x4*)&tile[d * 72 + sl0] = p0;
        *(s16x4*)&tile[(d + 128) * 72 + sl0] = p1;
    }
    __syncthreads();
    // epilogue phase 2: permuted read, fully coalesced 32KB store
    {
        unsigned short* base = mT + (((size_t)b * 16 + rb) * 256) * 64;
#pragma unroll
        for (int j = 0; j < 8; j++) {
            int u = j * 256 + tid;
            int d = u >> 3, sp = u & 7;
            int o = sp ^ (d & 7);
            s16x8 v = *(const s16x8*)&tile[d * 72 + o * 8];
            *(s16x8*)(base + (size_t)u * 8) = v;
        }
    }
}

// ---------------- attention: 8 waves num/den split, double-buffered LDS, 1 barrier/chunk ----------------
__global__ __launch_bounds__(512, 2) void k_attn(
        const float* __restrict__ yprev, const float* __restrict__ part2, int hasnorm,
        const float* __restrict__ gp, const float* __restrict__ bp,
        const unsigned short* __restrict__ sqb,
        const unsigned short* __restrict__ mT, const unsigned short* __restrict__ nd,
        const float* __restrict__ log_scale, const float* __restrict__ alpha, int l,
        float* __restrict__ y, float* __restrict__ part) {
    int blk0 = blockIdx.x;
    int blk = (blk0 & 7) * 64 + (blk0 >> 3);  // XCD-bijective swizzle (512 % 8 == 0)
    int b = blk >> 4, ib = blk & 15;
    int i0 = ib * 64;
    int tid = threadIdx.x, lane = tid & 63, wid = tid >> 6;
    int wr = wid & 3, wh = wid >> 2;          // row group, cf half (0=num, 1=den)
    __shared__ __align__(16) unsigned short esL[2][64 * 64];   // 16 KB dbuf, swizzled
    __shared__ __align__(16) unsigned short mtL[2][256 * 64];  // 64 KB dbuf
    float sc = log_scale[0] * alpha[l];

    // norm coefficients (accv scratch lives in esL before main loop)
    float* accvA = (float*)esL;
    if (hasnorm && tid < 256) {
        int st = tid >> 7, d = tid & 127;
        float s = 0.f;
#pragma unroll
        for (int c = 0; c < 16; c++) s += part2[(size_t)(b * 32 + c * 2 + st) * 128 + d];
        accvA[tid] = s;
    }
    __syncthreads();

    float rsc[8], rsh[8];
#pragma unroll
    for (int cf = 0; cf < 8; cf++) {
        int d = cf * 16 + (lane & 15);
        float scv = 1.f, shv = 0.f;
        if (hasnorm) {
            float mu = accvA[d] * (1.f / S);
            float var = accvA[128 + d] * (1.f / S) - mu * mu;
            float rs = rsqrtf(var + EPSN);
            scv = rs * gp[d];
            shv = bp[d] - mu * scv;
        }
        rsc[cf] = scv; rsh[cf] = shv;
    }
    __syncthreads();   // done with accvA scratch before esL[0] is written

    f32x4 acc[8];
#pragma unroll
    for (int cf = 0; cf < 8; cf++) acc[cf] = {0.f, 0.f, 0.f, 0.f};

    // es staging: 1 octet/thread (row = tid>>3, octet og = tid&7)
    int erow = tid >> 3, og = tid & 7;
    int gi = i0 + erow; if (gi > 999) gi = 999;
    const unsigned short* ndr = nd + (size_t)b * 1000 * 1024 + (size_t)gi * 1024 + og * 8;
    const unsigned short* mtb = mT + (size_t)b * 16 * 16384;
    int esoff = erow * 64 + ((og ^ (erow & 7)) * 8);

    // prologue: stage chunk 0 into buf0, issue chunk-1 loads
    s16x8 cn = *(const s16x8*)(ndr);
    s16x8 cm[4];
#pragma unroll
    for (int j = 0; j < 4; j++)
        cm[j] = *(const s16x8*)(mtb + (size_t)(j * 512 + tid) * 8);
    {
        s16x8 o0;
#pragma unroll
        for (int j = 0; j < 8; j++)
            o0[j] = (short)f2bf(__expf(-sc * bf2f((unsigned short)cn[j])));
        *(s16x8*)&esL[0][esoff] = o0;
#pragma unroll
        for (int j = 0; j < 4; j++)
            *(s16x8*)&mtL[0][(j * 512 + tid) * 8] = cm[j];
    }
    cn = *(const s16x8*)(ndr + 64);
#pragma unroll
    for (int j = 0; j < 4; j++)
        cm[j] = *(const s16x8*)(mtb + (size_t)16384 + (size_t)(j * 512 + tid) * 8);
    __syncthreads();

    int cur = 0;
    for (int kc = 0; kc < 16; kc++) {
        if (kc < 15) {
            // write buf[cur^1] with chunk kc+1 (from regs), overlapped with MFMA on buf[cur]
            s16x8 o0;
#pragma unroll
            for (int j = 0; j < 8; j++)
                o0[j] = (short)f2bf(__expf(-sc * bf2f((unsigned short)cn[j])));
            *(s16x8*)&esL[cur ^ 1][esoff] = o0;
#pragma unroll
            for (int j = 0; j < 4; j++)
                *(s16x8*)&mtL[cur ^ 1][(j * 512 + tid) * 8] = cm[j];
            // issue chunk kc+2 loads; in flight across MFMA + barrier + next write phase
            int kn = (kc + 2 <= 15) ? kc + 2 : 15;
            cn = *(const s16x8*)(ndr + kn * 64);
#pragma unroll
            for (int j = 0; j < 4; j++)
                cm[j] = *(const s16x8*)(mtb + (size_t)kn * 16384 + (size_t)(j * 512 + tid) * 8);
        }
#pragma unroll
        for (int ks = 0; ks < 2; ks++) {
            int arow = wr * 16 + (lane & 15);
            int ag = ks * 4 + (lane >> 4);
            s16x8 a = *(const s16x8*)&esL[cur][arow * 64 + ((ag ^ (arow & 7)) * 8)];
            __builtin_amdgcn_s_setprio(1);
#pragma unroll
            for (int cf = 0; cf < 8; cf++) {
                int c = cf * 16 + wh * 128 + (lane & 15);
                s16x8 bf = *(const s16x8*)&mtL[cur][c * 64 + ((ag ^ (c & 7)) * 8)];
                acc[cf] = MFMA32(a, bf, acc[cf]);
            }
            __builtin_amdgcn_s_setprio(0);
        }
        __syncthreads();   // buf[cur^1] ready for next iter; buf[cur] free for rewrite after next iter
        cur ^= 1;
    }

    // epilogue: exchange den via LDS, then num waves finish
    float* pw = (float*)mtL[0];               // [64 rows][128 d] f32 = 32 KB
    if (wh == 1) {
#pragma unroll
        for (int cf = 0; cf < 8; cf++) {
            int c = cf * 16 + (lane & 15);
#pragma unroll
            for (int r = 0; r < 4; r++) {
                int rl = wr * 16 + (lane >> 4) * 4 + r;
                pw[rl * 128 + c] = acc[cf][r];
            }
        }
    }
    __syncthreads();
    float* sw = (float*)esL;                  // stats partials [8][128]
    if (wh == 0) {
#pragma unroll
        for (int cf = 0; cf < 8; cf++) {
            int d = cf * 16 + (lane & 15);
            float s = 0.f, s2 = 0.f;
#pragma unroll
            for (int r = 0; r < 4; r++) {
                int rl = wr * 16 + (lane >> 4) * 4 + r;
                int i = i0 + rl;
                if (i < S) {
                    size_t off = ((size_t)b * S + i) * D + d;
                    float w = n2n(acc[cf][r]) / n2n(pw[rl * 128 + d]);
                    float xv = yprev[off] * rsc[cf] + rsh[cf];
                    float yv = xv + bf2f(sqb[off]) * w;
                    y[off] = yv;
                    s += yv;
                    s2 = fmaf(yv, yv, s2);
                }
            }
            s += __shfl_xor(s, 16); s += __shfl_xor(s, 32);
            s2 += __shfl_xor(s2, 16); s2 += __shfl_xor(s2, 32);
            if (lane < 16) {
                sw[(wr * 2 + 0) * 128 + d] = s;
                sw[(wr * 2 + 1) * 128 + d] = s2;
            }
        }
    }
    __syncthreads();
    if (tid < 256) {
        int st = tid >> 7, d = tid & 127;
        float v = sw[(0 * 2 + st) * 128 + d] + sw[(1 * 2 + st) * 128 + d] +
                  sw[(2 * 2 + st) * 128 + d] + sw[(3 * 2 + st) * 128 + d];
        part[((size_t)(b * 16 + ib) * 2 + st) * 128 + d] = v;
    }
}

// ---------------- fused FFN: norm(part1) -> relu(h@W1^T+b) in LDS -> @W2^T + residual ----------------
__global__ __launch_bounds__(256) void k_ffn(
        const float* __restrict__ ya, const float* __restrict__ part1,
        const float* __restrict__ gp, const float* __restrict__ bp,
        const unsigned short* __restrict__ w1b, const unsigned short* __restrict__ w2b,
        const float* __restrict__ bW1, const float* __restrict__ bW2,
        float* __restrict__ yb, float* __restrict__ part) {
    int blk = blockIdx.x;
    int b = blk >> 4, rb = blk & 15;
    int r0 = rb * 64;
    int tid = threadIdx.x, lane = tid & 63, wid = tid >> 6;
    __shared__ __align__(16) unsigned short hs[64 * 128];    // normed h bf16, octet-swizzled
    __shared__ __align__(16) unsigned short w1c[64 * 128];   // W1 chunk [64 f][128 k], swizzled
    __shared__ __align__(16) unsigned short tc[64 * 72];     // t chunk [64 row][64 f], stride 144B
    __shared__ __align__(16) unsigned short w2c[128 * 64];   // W2 chunk [128 d][64 f], swizzled
    __shared__ float nsc[128], nsh[128];
    __shared__ float accv[256];

    {
        int st = tid >> 7, d = tid & 127;
        float s = 0.f;
#pragma unroll
        for (int c = 0; c < 16; c++) s += part1[(size_t)(b * 32 + c * 2 + st) * 128 + d];
        accv[tid] = s;
    }
    __syncthreads();
    if (tid < 128) {
        float mu = accv[tid] * (1.f / S);
        float var = accv[128 + tid] * (1.f / S) - mu * mu;
        float rs = rsqrtf(var + EPSN);
        float scv = rs * gp[tid];
        nsc[tid] = scv;
        nsh[tid] = bp[tid] - mu * scv;
    }
    __syncthreads();

    // stage normed h (64 rows x 128 k), octet-swizzled
    {
        int i = tid >> 2;
        int gs = r0 + i; if (gs >= S) gs = S - 1;
        const float* gpx = ya + ((size_t)b * S + gs) * D;
#pragma unroll
        for (int q = 0; q < 4; q++) {
            int col = (tid & 3) * 32 + q * 8;
            int g = col >> 3;
            float4 a4 = *(const float4*)(gpx + col);
            float4 b4 = *(const float4*)(gpx + col + 4);
            const float* scp = &nsc[col];
            const float* shp = &nsh[col];
            s16x4 p0 = {(short)f2bf(a4.x * scp[0] + shp[0]), (short)f2bf(a4.y * scp[1] + shp[1]),
                        (short)f2bf(a4.z * scp[2] + shp[2]), (short)f2bf(a4.w * scp[3] + shp[3])};
            s16x4 p1 = {(short)f2bf(b4.x * scp[4] + shp[4]), (short)f2bf(b4.y * scp[5] + shp[5]),
                        (short)f2bf(b4.z * scp[6] + shp[6]), (short)f2bf(b4.w * scp[7] + shp[7])};
            int base = i * 128 + ((g ^ (i & 7)) * 8);
            *(s16x4*)&hs[base] = p0;
            *(s16x4*)&hs[base + 4] = p1;
        }
    }

    f32x4 yacc[8];
#pragma unroll
    for (int cf = 0; cf < 8; cf++) yacc[cf] = {0.f, 0.f, 0.f, 0.f};

    for (int fc = 0; fc < 8; fc++) {
        int c0 = fc * 64;
        // stage W1 chunk [64 f][128 k], swizzled
        {
            int f = tid >> 2;
#pragma unroll
            for (int q = 0; q < 4; q++) {
                int col = (tid & 3) * 32 + q * 8;
                int g = col >> 3;
                s16x8 w = *(const s16x8*)(w1b + (size_t)(c0 + f) * D + col);
                *(s16x8*)&w1c[f * 128 + ((g ^ (f & 7)) * 8)] = w;
            }
        }
        // stage W2 chunk [128 d][64 f], swizzled
        {
            int d2 = tid >> 1;
#pragma unroll
            for (int q = 0; q < 4; q++) {
                int g = (tid & 1) * 4 + q;
                s16x8 w = *(const s16x8*)(w2b + (size_t)d2 * F + c0 + g * 8);
                *(s16x8*)&w2c[d2 * 64 + ((g ^ (d2 & 7)) * 8)] = w;
            }
        }
        __syncthreads();
        // GEMM1: t = relu(h @ W1c^T + bW1)
        f32x4 tacc[4];
#pragma unroll
        for (int c4 = 0; c4 < 4; c4++) tacc[c4] = {0.f, 0.f, 0.f, 0.f};
#pragma unroll
        for (int ks = 0; ks < 4; ks++) {
            int g = ks * 4 + (lane >> 4);
            int arow = wid * 16 + (lane & 15);
            s16x8 a = *(const s16x8*)&hs[arow * 128 + ((g ^ (arow & 7)) * 8)];
#pragma unroll
            for (int c4 = 0; c4 < 4; c4++) {
                int brow = c4 * 16 + (lane & 15);
                s16x8 bf = *(const s16x8*)&w1c[brow * 128 + ((g ^ (brow & 7)) * 8)];
                tacc[c4] = MFMA32(a, bf, tacc[c4]);
            }
        }
#pragma unroll
        for (int c4 = 0; c4 < 4; c4++) {
            int col = c4 * 16 + (lane & 15);
            float bias = bW1[c0 + col];
#pragma unroll
            for (int r = 0; r < 4; r++) {
                int rl = wid * 16 + (lane >> 4) * 4 + r;
                tc[rl * 72 + col] = f2bf(fmaxf(tacc[c4][r] + bias, 0.f));
            }
        }
        __syncthreads();
        // GEMM2: yacc += t @ W2c^T
#pragma unroll
        for (int ks = 0; ks < 2; ks++) {
            int ko = ks * 32 + (lane >> 4) * 8;
            int g = ks * 4 + (lane >> 4);
            s16x8 a = *(const s16x8*)&tc[(wid * 16 + (lane & 15)) * 72 + ko];
#pragma unroll
            for (int cf = 0; cf < 8; cf++) {
                int brow = cf * 16 + (lane & 15);
                s16x8 bf = *(const s16x8*)&w2c[brow * 64 + ((g ^ (brow & 7)) * 8)];
                yacc[cf] = MFMA32(a, bf, yacc[cf]);
            }
        }
        __syncthreads();
    }

    // epilogue: yb = h + ff + bias, stats
    float* pw = (float*)w1c;
#pragma unroll
    for (int cf = 0; cf < 8; cf++) {
        int d = cf * 16 + (lane & 15);
        float bias = bW2[d];
        float s = 0.f, s2 = 0.f;
#pragma unroll
        for (int r = 0; r < 4; r++) {
            int rl = wid * 16 + (lane >> 4) * 4 + r;
            int row = r0 + rl;
            if (row < S) {
                float hval = bf2f(hs[rl * 128 + (((d >> 3) ^ (rl & 7)) * 8) + (d & 7)]);
                float yv = hval + yacc[cf][r] + bias;
                yb[((size_t)b * S + row) * D + d] = yv;
                s += yv;
                s2 = fmaf(yv, yv, s2);
            }
        }
        s += __shfl_xor(s, 16); s += __shfl_xor(s, 32);
        s2 += __shfl_xor(s2, 16); s2 += __shfl_xor(s2, 32);
        if (lane < 16) {
            pw[(wid * 2 + 0) * 128 + d] = s;
            pw[(wid * 2 + 1) * 128 + d] = s2;
        }
    }
    __syncthreads();
    {
        int st = tid >> 7, d = tid & 127;
        float v = pw[(0 * 2 + st) * 128 + d] + pw[(1 * 2 + st) * 128 + d] +
                  pw[(2 * 2 + st) * 128 + d] + pw[(3 * 2 + st) * 128 + d];
        part[((size_t)(b * 16 + rb) * 2 + st) * 128 + d] = v;
    }
}

// ---------------- final reduce + norm ----------------
__global__ __launch_bounds__(256) void k_finalize(
        const float* __restrict__ part, float* __restrict__ acc) {
    int i = blockIdx.x * 256 + threadIdx.x;
    int b = i >> 8, k = i & 255;
    float s = 0.f;
#pragma unroll
    for (int c = 0; c < 16; c++) s += part[(size_t)(b * 16 + c) * 256 + k];
    acc[i] = s;
}

__global__ __launch_bounds__(256) void k_norm(
        const float* __restrict__ y, const float* __restrict__ acc,
        const float* __restrict__ g, const float* __restrict__ bb,
        float* __restrict__ out) {
    size_t i = (size_t)blockIdx.x * 256 + threadIdx.x;
    int d = (int)(i % D);
    int b = (int)(i / ((size_t)S * D));
    float mu = acc[b * 256 + d] * (1.f / S);
    float var = acc[b * 256 + 128 + d] * (1.f / S) - mu * mu;
    float v = (y[i] - mu) * rsqrtf(var + EPSN);
    out[i] = v * g[d] + bb[d];
}

extern "C" void kernel_launch(void* const* d_in, const int* in_sizes, int n_in,
                              void* d_out, int out_size, void* d_ws, size_t ws_size,
                              hipStream_t stream) {
    const float* depot = (const float*)d_in[0];
    const float* node  = (const float*)d_in[1];
    const float* dist  = (const float*)d_in[2];
    const float* log_scale = (const float*)d_in[3];
    const int*   flag  = (const int*)d_in[4];
    const float* Wd   = (const float*)d_in[5];
    const float* bd   = (const float*)d_in[6];
    const float* Wn   = (const float*)d_in[7];
    const float* bn   = (const float*)d_in[8];
    const float* Win  = (const float*)d_in[9];
    const float* bin_ = (const float*)d_in[10];
    const float* Wout = (const float*)d_in[11];
    const float* bout = (const float*)d_in[12];
    const float* Wq   = (const float*)d_in[13];
    const float* Wk   = (const float*)d_in[14];
    const float* Wv   = (const float*)d_in[15];
    const float* alpha= (const float*)d_in[16];
    const float* g1   = (const float*)d_in[17];
    const float* b1   = (const float*)d_in[18];
    const float* W1   = (const float*)d_in[19];
    const float* bW1  = (const float*)d_in[20];
    const float* W2   = (const float*)d_in[21];
    const float* bW2  = (const float*)d_in[22];
    const float* g2   = (const float*)d_in[23];
    const float* b2   = (const float*)d_in[24];

    float* ws = (float*)d_ws;
    size_t nxd = (size_t)B * S * D;                       // 4,096,000
    float* ya    = ws;
    float* yb    = ws + nxd;
    float* part1 = ws + 2 * nxd;                          // B*16*256 = 131072
    float* part2 = part1 + 131072;
    float* accb2 = part2 + 131072;                        // B*256
    unsigned short* sqb = (unsigned short*)(accb2 + 8192);          // B*S*D bf16
    unsigned short* mT  = sqb + nxd;                                // B*16*256*64
    unsigned short* wbf = mT + (size_t)B * 16 * 256 * 64;           // L*WSTR
    unsigned short* nd  = wbf + (size_t)L * WSTR;                   // B*1000*1024

    k_wprep<<<dim3(88, 6), 256, 0, stream>>>(Wq, Wk, Wv, W1, W2, wbf);
    k_prep<<<B * S, 256, 0, stream>>>(dist, nd);
    k_embed<<<B * S, 128, 0, stream>>>(depot, node, Wd, bd, Wn, bn, yb);
    k_rowxform<<<B, 128, 0, stream>>>(yb, Win, bin_, flag, 0);
    k_rowxform<<<B, 128, 0, stream>>>(yb, Wout, bout, flag, 1);

    for (int l = 0; l < L; l++) {
        int hasnorm = (l > 0) ? 1 : 0;
        const float* gpn = g2 + (l > 0 ? (l - 1) : 0) * D;
        const float* bpn = b2 + (l > 0 ? (l - 1) : 0) * D;
        const unsigned short* wl = wbf + (size_t)l * WSTR;
        k_qkv<<<B * 16, 256, 0, stream>>>(yb, part2, hasnorm, gpn, bpn, wl, sqb, mT);
        k_attn<<<B * 16, 512, 0, stream>>>(yb, part2, hasnorm, gpn, bpn,
                                           sqb, mT, nd, log_scale, alpha, l, ya, part1);
        k_ffn<<<B * 16, 256, 0, stream>>>(ya, part1, g1 + l * D, b1 + l * D,
                                          wl + 49152, wl + 114688,
                                          bW1 + (size_t)l * F, bW2 + (size_t)l * D, yb, part2);
    }
    k_finalize<<<32, 256, 0, stream>>>(part2, accb2);
    k_norm<<<B * S * D / 256, 256, 0, stream>>>(yb, accb2, g2 + 5 * D, b2 + 5 * D, (float*)d_out);
}

// Round 13
// 629.333 us; speedup vs baseline: 1.1108x; 1.0257x over previous
//
#include <hip/hip_runtime.h>
#include <hip/hip_bf16.h>
#include <float.h>
#include <math.h>

#define B 32
#define NN 999
#define S 1000
#define D 128
#define F 512
#define L 6
#define EPSN 1e-5f
#define WSTR 180224   // per-layer bf16 weight stride: 3*16384 + 2*65536

typedef __attribute__((ext_vector_type(4))) float f32x4;
typedef __attribute__((ext_vector_type(4))) short s16x4;
typedef __attribute__((ext_vector_type(8))) short s16x8;

#if defined(__has_builtin)
#if __has_builtin(__builtin_amdgcn_mfma_f32_16x16x16bf16_1k)
#define HAVE_MFMA16 1
#endif
#if __has_builtin(__builtin_amdgcn_mfma_f32_16x16x32_bf16)
#define HAVE_MFMA32 1
#endif
#endif

#ifdef HAVE_MFMA16
#define MFMA16(a, b, c) __builtin_amdgcn_mfma_f32_16x16x16bf16_1k((a), (b), (c), 0, 0, 0)
#else
static __device__ __forceinline__ f32x4 mfma16_asm(s16x4 a, s16x4 b, f32x4 c) {
    asm volatile("v_mfma_f32_16x16x16_bf16 %0, %1, %2, %0\n\ts_nop 7\n\ts_nop 7"
                 : "+v"(c) : "v"(a), "v"(b));
    return c;
}
#define MFMA16(a, b, c) mfma16_asm((a), (b), (c))
#endif

#ifdef HAVE_MFMA32
#define MFMA32(a, b, c) __builtin_amdgcn_mfma_f32_16x16x32_bf16((a), (b), (c), 0, 0, 0)
#else
static __device__ __forceinline__ f32x4 mfma32_asm(s16x8 a, s16x8 b, f32x4 c) {
    asm volatile("v_mfma_f32_16x16x32_bf16 %0, %1, %2, %0\n\ts_nop 7\n\ts_nop 7"
                 : "+v"(c) : "v"(a), "v"(b));
    return c;
}
#define MFMA32(a, b, c) mfma32_asm((a), (b), (c))
#endif

__device__ __forceinline__ float n2n(float v) {
    if (v != v) return 0.f;
    if (isinf(v)) return v > 0.f ? FLT_MAX : -FLT_MAX;
    return v;
}

__device__ __forceinline__ unsigned short f2bf(float x) {
    unsigned u = __float_as_uint(x);
    return (unsigned short)((u + 0x7fffu + ((u >> 16) & 1u)) >> 16);
}

__device__ __forceinline__ float bf2f(unsigned short v) {
    return __uint_as_float(((unsigned)v) << 16);
}

// ---------------- one-time: weights -> bf16 ----------------
// layout per layer (stride WSTR): Wq 0, Wk 16384, Wv 32768, W1 49152, W2 114688
__global__ __launch_bounds__(256) void k_wprep(
        const float* __restrict__ Wq, const float* __restrict__ Wk,
        const float* __restrict__ Wv, const float* __restrict__ W1,
        const float* __restrict__ W2, unsigned short* __restrict__ wbf) {
    int bx = blockIdx.x, l = blockIdx.y;
    const float* src; int doff, off;
    if (bx < 8)       { src = Wq + (size_t)l * 16384; doff = 0;      off = bx * 2048; }
    else if (bx < 16) { src = Wk + (size_t)l * 16384; doff = 16384;  off = (bx - 8) * 2048; }
    else if (bx < 24) { src = Wv + (size_t)l * 16384; doff = 32768;  off = (bx - 16) * 2048; }
    else if (bx < 56) { src = W1 + (size_t)l * 65536; doff = 49152;  off = (bx - 24) * 2048; }
    else              { src = W2 + (size_t)l * 65536; doff = 114688; off = (bx - 56) * 2048; }
    int i = off + threadIdx.x * 8;
    float4 a4 = *(const float4*)(src + i);
    float4 b4 = *(const float4*)(src + i + 4);
    s16x8 p = {(short)f2bf(a4.x), (short)f2bf(a4.y), (short)f2bf(a4.z), (short)f2bf(a4.w),
               (short)f2bf(b4.x), (short)f2bf(b4.y), (short)f2bf(b4.z), (short)f2bf(b4.w)};
    *(s16x8*)(wbf + (size_t)l * WSTR + doff + i) = p;
}

// ---------------- one-time prep: dist -> bf16 padded ----------------
__global__ __launch_bounds__(256) void k_prep(
        const float* __restrict__ dist, unsigned short* __restrict__ nd) {
    int row = blockIdx.x;
    int col = threadIdx.x * 4;
    unsigned short* op = nd + (size_t)row * 1024 + col;
    if (col < 1000) {
        float4 v = *(const float4*)(dist + (size_t)row * 1000 + col);
        s16x4 p = {(short)f2bf(v.x), (short)f2bf(v.y), (short)f2bf(v.z), (short)f2bf(v.w)};
        *(s16x4*)op = p;
    } else {
        s16x4 z = {0, 0, 0, 0};
        *(s16x4*)op = z;
    }
}

__global__ __launch_bounds__(128) void k_embed(
        const float* __restrict__ depot, const float* __restrict__ node,
        const float* __restrict__ Wd, const float* __restrict__ bd,
        const float* __restrict__ Wn, const float* __restrict__ bn,
        float* __restrict__ x) {
    int row = blockIdx.x;
    int b = row / S, s = row % S;
    int d = threadIdx.x;
    float o;
    if (s == 0) {
        float x0 = depot[b * 2 + 0], x1 = depot[b * 2 + 1];
        o = Wd[d * 2 + 0] * x0 + Wd[d * 2 + 1] * x1 + bd[d];
    } else {
        const float* p = node + ((size_t)b * NN + (s - 1)) * 3;
        o = Wn[d * 3 + 0] * p[0] + Wn[d * 3 + 1] * p[1] + Wn[d * 3 + 2] * p[2] + bn[d];
    }
    x[(size_t)row * D + d] = o;
}

__global__ __launch_bounds__(128) void k_rowxform(
        float* __restrict__ x, const float* __restrict__ W,
        const float* __restrict__ bias, const int* __restrict__ flag, int mode) {
    int b = blockIdx.x;
    int d = threadIdx.x;
    __shared__ float row[D];
    int r = (mode == 0) ? 1 : (1 - flag[b]) * NN;
    float* xr = x + ((size_t)b * S + r) * D;
    row[d] = xr[d];
    __syncthreads();
    float acc = bias[d];
    for (int e = 0; e < D; e += 4) {
        const float4 w = *(const float4*)(W + (size_t)d * D + e);
        acc += w.x * row[e] + w.y * row[e + 1] + w.z * row[e + 2] + w.w * row[e + 3];
    }
    xr[d] = acc;
}

// ---------------- qkv: norm-fused input, LDS-staged bf16 weights, coalesced swizzled mT ----------------
__global__ __launch_bounds__(256) void k_qkv(
        const float* __restrict__ yprev, const float* __restrict__ part2, int hasnorm,
        const float* __restrict__ gp, const float* __restrict__ bp,
        const unsigned short* __restrict__ wl,
        unsigned short* __restrict__ sqb, unsigned short* __restrict__ mT) {
    int blk = blockIdx.x;
    int b = blk >> 4, rb = blk & 15;
    int s0 = rb * 64;
    int tid = threadIdx.x, lane = tid & 63, wid = tid >> 6;
    __shared__ __align__(16) unsigned short lds[18432];  // xs[64*40]+wt[3][128*40]; reused tile[256*72]
    __shared__ float nsc[128], nsh[128];
    __shared__ float accv[256];
    unsigned short* xs = lds;
    unsigned short* wt0 = lds + 2560;

    if (hasnorm) {
        int st = tid >> 7, d = tid & 127;
        float s = 0.f;
#pragma unroll
        for (int c = 0; c < 16; c++) s += part2[(size_t)(b * 32 + c * 2 + st) * 128 + d];
        accv[tid] = s;
    }
    __syncthreads();
    if (tid < 128) {
        float scv = 1.f, shv = 0.f;
        if (hasnorm) {
            float mu = accv[tid] * (1.f / S);
            float var = accv[128 + tid] * (1.f / S) - mu * mu;
            float rs = rsqrtf(var + EPSN);
            scv = rs * gp[tid];
            shv = bp[tid] - mu * scv;
        }
        nsc[tid] = scv; nsh[tid] = shv;
    }
    __syncthreads();

    f32x4 acc[3][8];
#pragma unroll
    for (int mm = 0; mm < 3; mm++)
#pragma unroll
        for (int cf = 0; cf < 8; cf++) acc[mm][cf] = {0.f, 0.f, 0.f, 0.f};

    for (int k0 = 0; k0 < D; k0 += 32) {
        {
            int i = tid >> 2, kq = (tid & 3) * 8;
            int s = s0 + i;
            int gs = s < S ? s : S - 1;
            const float* gpx = yprev + ((size_t)b * S + gs) * D + k0 + kq;
            float4 a4 = *(const float4*)gpx;
            float4 b4 = *(const float4*)(gpx + 4);
            const float* scp = &nsc[k0 + kq];
            const float* shp = &nsh[k0 + kq];
            s16x4 p0 = {(short)f2bf(a4.x * scp[0] + shp[0]), (short)f2bf(a4.y * scp[1] + shp[1]),
                        (short)f2bf(a4.z * scp[2] + shp[2]), (short)f2bf(a4.w * scp[3] + shp[3])};
            s16x4 p1 = {(short)f2bf(b4.x * scp[4] + shp[4]), (short)f2bf(b4.y * scp[5] + shp[5]),
                        (short)f2bf(b4.z * scp[6] + shp[6]), (short)f2bf(b4.w * scp[7] + shp[7])};
            *(s16x4*)&xs[i * 40 + kq] = p0;
            *(s16x4*)&xs[i * 40 + kq + 4] = p1;
        }
#pragma unroll
        for (int u0 = 0; u0 < 6; u0++) {
            int u = tid + u0 * 256;
            int mm = u >> 9;
            int v = u & 511;
            int c = v >> 2, kq = (v & 3) * 8;
            s16x8 w = *(const s16x8*)(wl + (size_t)mm * 16384 + (size_t)c * D + k0 + kq);
            *(s16x8*)&wt0[mm * 5120 + c * 40 + kq] = w;
        }
        __syncthreads();
#pragma unroll
        for (int ks = 0; ks < 2; ks++) {
            int ko = ks * 16 + (lane >> 4) * 4;
            s16x4 a = *(const s16x4*)&xs[(wid * 16 + (lane & 15)) * 40 + ko];
#pragma unroll
            for (int mm = 0; mm < 3; mm++)
#pragma unroll
                for (int cf = 0; cf < 8; cf++) {
                    s16x4 bf = *(const s16x4*)&wt0[mm * 5120 + (cf * 16 + (lane & 15)) * 40 + ko];
                    acc[mm][cf] = MFMA16(a, bf, acc[mm][cf]);
                }
        }
        __syncthreads();
    }

    // epilogue phase 1: acc -> tile[256 d][72]  (stride 72 shorts = 144 B, 16B-aligned rows)
    unsigned short* tile = lds;               // 256*72 = 18432
    int sl0 = wid * 16 + (lane >> 4) * 4;     // local k
#pragma unroll
    for (int cf = 0; cf < 8; cf++) {
        int d = cf * 16 + (lane & 15);
        s16x4 p0, p1;
#pragma unroll
        for (int r = 0; r < 4; r++) {
            int s = s0 + sl0 + r;
            if (s < S) {
                float qv = acc[0][cf][r], kv = acc[1][cf][r], vv = acc[2][cf][r];
                float ek = __expf(kv);
                sqb[((size_t)b * S + s) * D + d] = f2bf(1.f / (1.f + __expf(-qv)));
                p0[r] = (short)f2bf(ek * vv);
                p1[r] = (short)f2bf(ek);
            } else { p0[r] = 0; p1[r] = 0; }
        }
        *(s16x4*)&tile[d * 72 + sl0] = p0;
        *(s16x4*)&tile[(d + 128) * 72 + sl0] = p1;
    }
    __syncthreads();
    // epilogue phase 2: permuted read, fully coalesced 32KB store
    {
        unsigned short* base = mT + (((size_t)b * 16 + rb) * 256) * 64;
#pragma unroll
        for (int j = 0; j < 8; j++) {
            int u = j * 256 + tid;
            int d = u >> 3, sp = u & 7;
            int o = sp ^ (d & 7);
            s16x8 v = *(const s16x8*)&tile[d * 72 + o * 8];
            *(s16x8*)(base + (size_t)u * 8) = v;
        }
    }
}

// ---------------- attention: 8 waves (2 row-halves x 4 col-quarters), dbuf LDS ----------------
__global__ __launch_bounds__(512, 2) void k_attn(
        const float* __restrict__ yprev, const float* __restrict__ part2, int hasnorm,
        const float* __restrict__ gp, const float* __restrict__ bp,
        const unsigned short* __restrict__ sqb,
        const unsigned short* __restrict__ mT, const unsigned short* __restrict__ nd,
        const float* __restrict__ log_scale, const float* __restrict__ alpha, int l,
        float* __restrict__ y, float* __restrict__ part) {
    int blk0 = blockIdx.x;
    int blk = (blk0 & 7) * 64 + (blk0 >> 3);  // XCD-bijective swizzle (512 % 8 == 0)
    int b = blk >> 4, ib = blk & 15;
    int i0 = ib * 64;
    int tid = threadIdx.x, lane = tid & 63, wid = tid >> 6;
    int wr = wid & 1, wc = wid >> 1;          // row half (32 rows), col quarter (cols wc*64..+64)
    __shared__ __align__(16) unsigned short esL[2][64 * 64];   // 16 KB dbuf, swizzled
    __shared__ __align__(16) unsigned short mtL[2][256 * 64];  // 64 KB dbuf
    float sc = log_scale[0] * alpha[l];

    // norm coefficients (accv scratch lives in esL before main loop)
    float* accvA = (float*)esL;
    if (hasnorm && tid < 256) {
        int st = tid >> 7, d = tid & 127;
        float s = 0.f;
#pragma unroll
        for (int c = 0; c < 16; c++) s += part2[(size_t)(b * 32 + c * 2 + st) * 128 + d];
        accvA[tid] = s;
    }
    __syncthreads();

    int wcm = wc & 1;                          // d-quarter within 0..127 for this wave
    float rsc[4], rsh[4];
#pragma unroll
    for (int cf = 0; cf < 4; cf++) {
        int d = wcm * 64 + cf * 16 + (lane & 15);
        float scv = 1.f, shv = 0.f;
        if (hasnorm) {
            float mu = accvA[d] * (1.f / S);
            float var = accvA[128 + d] * (1.f / S) - mu * mu;
            float rs = rsqrtf(var + EPSN);
            scv = rs * gp[d];
            shv = bp[d] - mu * scv;
        }
        rsc[cf] = scv; rsh[cf] = shv;
    }
    __syncthreads();   // done with accvA scratch before esL[0] is written

    f32x4 acc[2][4];
#pragma unroll
    for (int rf = 0; rf < 2; rf++)
#pragma unroll
        for (int cf = 0; cf < 4; cf++) acc[rf][cf] = {0.f, 0.f, 0.f, 0.f};

    // es staging: 1 octet/thread (row = tid>>3, octet og = tid&7)
    int erow = tid >> 3, og = tid & 7;
    int gi = i0 + erow; if (gi > 999) gi = 999;
    const unsigned short* ndr = nd + (size_t)b * 1000 * 1024 + (size_t)gi * 1024 + og * 8;
    const unsigned short* mtb = mT + (size_t)b * 16 * 16384;
    int esoff = erow * 64 + ((og ^ (erow & 7)) * 8);

    // prologue: stage chunk 0 into buf0, issue chunk-1 loads
    s16x8 cn = *(const s16x8*)(ndr);
    s16x8 cm[4];
#pragma unroll
    for (int j = 0; j < 4; j++)
        cm[j] = *(const s16x8*)(mtb + (size_t)(j * 512 + tid) * 8);
    {
        s16x8 o0;
#pragma unroll
        for (int j = 0; j < 8; j++)
            o0[j] = (short)f2bf(__expf(-sc * bf2f((unsigned short)cn[j])));
        *(s16x8*)&esL[0][esoff] = o0;
#pragma unroll
        for (int j = 0; j < 4; j++)
            *(s16x8*)&mtL[0][(j * 512 + tid) * 8] = cm[j];
    }
    cn = *(const s16x8*)(ndr + 64);
#pragma unroll
    for (int j = 0; j < 4; j++)
        cm[j] = *(const s16x8*)(mtb + (size_t)16384 + (size_t)(j * 512 + tid) * 8);
    __syncthreads();

    int cur = 0;
    for (int kc = 0; kc < 16; kc++) {
        if (kc < 15) {
            // write buf[cur^1] with chunk kc+1 (from regs), overlapped with MFMA on buf[cur]
            s16x8 o0;
#pragma unroll
            for (int j = 0; j < 8; j++)
                o0[j] = (short)f2bf(__expf(-sc * bf2f((unsigned short)cn[j])));
            *(s16x8*)&esL[cur ^ 1][esoff] = o0;
#pragma unroll
            for (int j = 0; j < 4; j++)
                *(s16x8*)&mtL[cur ^ 1][(j * 512 + tid) * 8] = cm[j];
            // issue chunk kc+2 loads; in flight across MFMA + barrier + next write phase
            int kn = (kc + 2 <= 15) ? kc + 2 : 15;
            cn = *(const s16x8*)(ndr + kn * 64);
#pragma unroll
            for (int j = 0; j < 4; j++)
                cm[j] = *(const s16x8*)(mtb + (size_t)kn * 16384 + (size_t)(j * 512 + tid) * 8);
        }
#pragma unroll
        for (int ks = 0; ks < 2; ks++) {
            int ag = ks * 4 + (lane >> 4);
            int arow0 = wr * 32 + (lane & 15);
            int arow1 = arow0 + 16;
            s16x8 a0 = *(const s16x8*)&esL[cur][arow0 * 64 + ((ag ^ (arow0 & 7)) * 8)];
            s16x8 a1 = *(const s16x8*)&esL[cur][arow1 * 64 + ((ag ^ (arow1 & 7)) * 8)];
            __builtin_amdgcn_s_setprio(1);
#pragma unroll
            for (int cf = 0; cf < 4; cf++) {
                int c = wc * 64 + cf * 16 + (lane & 15);
                s16x8 bf = *(const s16x8*)&mtL[cur][c * 64 + ((ag ^ (c & 7)) * 8)];
                acc[0][cf] = MFMA32(a0, bf, acc[0][cf]);
                acc[1][cf] = MFMA32(a1, bf, acc[1][cf]);
            }
            __builtin_amdgcn_s_setprio(0);
        }
        __syncthreads();   // buf[cur^1] ready for next iter; buf[cur] free for rewrite after next iter
        cur ^= 1;
    }

    // epilogue: den waves (wc>=2) publish via LDS, num waves (wc<2) finish + stats
    float* pw = (float*)mtL[0];               // [64 rows][128 d] f32 = 32 KB
    if (wc >= 2) {
#pragma unroll
        for (int cf = 0; cf < 4; cf++) {
            int dcol = (wc - 2) * 64 + cf * 16 + (lane & 15);
#pragma unroll
            for (int rf = 0; rf < 2; rf++)
#pragma unroll
                for (int r = 0; r < 4; r++) {
                    int lrow = wr * 32 + rf * 16 + (lane >> 4) * 4 + r;
                    pw[lrow * 128 + dcol] = acc[rf][cf][r];
                }
        }
    }
    __syncthreads();
    float* sw = (float*)esL;                  // stats partials [2 row-halves][2 stat][128]
    if (wc < 2) {
#pragma unroll
        for (int cf = 0; cf < 4; cf++) {
            int d = wc * 64 + cf * 16 + (lane & 15);
            float s = 0.f, s2 = 0.f;
#pragma unroll
            for (int rf = 0; rf < 2; rf++)
#pragma unroll
                for (int r = 0; r < 4; r++) {
                    int lrow = wr * 32 + rf * 16 + (lane >> 4) * 4 + r;
                    int i = i0 + lrow;
                    if (i < S) {
                        size_t off = ((size_t)b * S + i) * D + d;
                        float w = n2n(acc[rf][cf][r]) / n2n(pw[lrow * 128 + d]);
                        float xv = yprev[off] * rsc[cf] + rsh[cf];
                        float yv = xv + bf2f(sqb[off]) * w;
                        y[off] = yv;
                        s += yv;
                        s2 = fmaf(yv, yv, s2);
                    }
                }
            s += __shfl_xor(s, 16); s += __shfl_xor(s, 32);
            s2 += __shfl_xor(s2, 16); s2 += __shfl_xor(s2, 32);
            if (lane < 16) {
                sw[(wr * 2 + 0) * 128 + d] = s;
                sw[(wr * 2 + 1) * 128 + d] = s2;
            }
        }
    }
    __syncthreads();
    if (tid < 256) {
        int st = tid >> 7, d = tid & 127;
        float v = sw[(0 * 2 + st) * 128 + d] + sw[(1 * 2 + st) * 128 + d];
        part[((size_t)(b * 16 + ib) * 2 + st) * 128 + d] = v;
    }
}

// ---------------- fused FFN: norm(part1) -> relu(h@W1^T+b) in LDS -> @W2^T + residual ----------------
__global__ __launch_bounds__(256) void k_ffn(
        const float* __restrict__ ya, const float* __restrict__ part1,
        const float* __restrict__ gp, const float* __restrict__ bp,
        const unsigned short* __restrict__ w1b, const unsigned short* __restrict__ w2b,
        const float* __restrict__ bW1, const float* __restrict__ bW2,
        float* __restrict__ yb, float* __restrict__ part) {
    int blk = blockIdx.x;
    int b = blk >> 4, rb = blk & 15;
    int r0 = rb * 64;
    int tid = threadIdx.x, lane = tid & 63, wid = tid >> 6;
    __shared__ __align__(16) unsigned short hs[64 * 128];    // normed h bf16, octet-swizzled
    __shared__ __align__(16) unsigned short w1c[64 * 128];   // W1 chunk [64 f][128 k], swizzled
    __shared__ __align__(16) unsigned short tc[64 * 72];     // t chunk [64 row][64 f], stride 144B
    __shared__ __align__(16) unsigned short w2c[128 * 64];   // W2 chunk [128 d][64 f], swizzled
    __shared__ float nsc[128], nsh[128];
    __shared__ float accv[256];

    {
        int st = tid >> 7, d = tid & 127;
        float s = 0.f;
#pragma unroll
        for (int c = 0; c < 16; c++) s += part1[(size_t)(b * 32 + c * 2 + st) * 128 + d];
        accv[tid] = s;
    }
    __syncthreads();
    if (tid < 128) {
        float mu = accv[tid] * (1.f / S);
        float var = accv[128 + tid] * (1.f / S) - mu * mu;
        float rs = rsqrtf(var + EPSN);
        float scv = rs * gp[tid];
        nsc[tid] = scv;
        nsh[tid] = bp[tid] - mu * scv;
    }
    __syncthreads();

    // stage normed h (64 rows x 128 k), octet-swizzled
    {
        int i = tid >> 2;
        int gs = r0 + i; if (gs >= S) gs = S - 1;
        const float* gpx = ya + ((size_t)b * S + gs) * D;
#pragma unroll
        for (int q = 0; q < 4; q++) {
            int col = (tid & 3) * 32 + q * 8;
            int g = col >> 3;
            float4 a4 = *(const float4*)(gpx + col);
            float4 b4 = *(const float4*)(gpx + col + 4);
            const float* scp = &nsc[col];
            const float* shp = &nsh[col];
            s16x4 p0 = {(short)f2bf(a4.x * scp[0] + shp[0]), (short)f2bf(a4.y * scp[1] + shp[1]),
                        (short)f2bf(a4.z * scp[2] + shp[2]), (short)f2bf(a4.w * scp[3] + shp[3])};
            s16x4 p1 = {(short)f2bf(b4.x * scp[4] + shp[4]), (short)f2bf(b4.y * scp[5] + shp[5]),
                        (short)f2bf(b4.z * scp[6] + shp[6]), (short)f2bf(b4.w * scp[7] + shp[7])};
            int base = i * 128 + ((g ^ (i & 7)) * 8);
            *(s16x4*)&hs[base] = p0;
            *(s16x4*)&hs[base + 4] = p1;
        }
    }

    f32x4 yacc[8];
#pragma unroll
    for (int cf = 0; cf < 8; cf++) yacc[cf] = {0.f, 0.f, 0.f, 0.f};

    for (int fc = 0; fc < 8; fc++) {
        int c0 = fc * 64;
        // stage W1 chunk [64 f][128 k], swizzled
        {
            int f = tid >> 2;
#pragma unroll
            for (int q = 0; q < 4; q++) {
                int col = (tid & 3) * 32 + q * 8;
                int g = col >> 3;
                s16x8 w = *(const s16x8*)(w1b + (size_t)(c0 + f) * D + col);
                *(s16x8*)&w1c[f * 128 + ((g ^ (f & 7)) * 8)] = w;
            }
        }
        // stage W2 chunk [128 d][64 f], swizzled
        {
            int d2 = tid >> 1;
#pragma unroll
            for (int q = 0; q < 4; q++) {
                int g = (tid & 1) * 4 + q;
                s16x8 w = *(const s16x8*)(w2b + (size_t)d2 * F + c0 + g * 8);
                *(s16x8*)&w2c[d2 * 64 + ((g ^ (d2 & 7)) * 8)] = w;
            }
        }
        __syncthreads();
        // GEMM1: t = relu(h @ W1c^T + bW1)
        f32x4 tacc[4];
#pragma unroll
        for (int c4 = 0; c4 < 4; c4++) tacc[c4] = {0.f, 0.f, 0.f, 0.f};
#pragma unroll
        for (int ks = 0; ks < 4; ks++) {
            int g = ks * 4 + (lane >> 4);
            int arow = wid * 16 + (lane & 15);
            s16x8 a = *(const s16x8*)&hs[arow * 128 + ((g ^ (arow & 7)) * 8)];
#pragma unroll
            for (int c4 = 0; c4 < 4; c4++) {
                int brow = c4 * 16 + (lane & 15);
                s16x8 bf = *(const s16x8*)&w1c[brow * 128 + ((g ^ (brow & 7)) * 8)];
                tacc[c4] = MFMA32(a, bf, tacc[c4]);
            }
        }
#pragma unroll
        for (int c4 = 0; c4 < 4; c4++) {
            int col = c4 * 16 + (lane & 15);
            float bias = bW1[c0 + col];
#pragma unroll
            for (int r = 0; r < 4; r++) {
                int rl = wid * 16 + (lane >> 4) * 4 + r;
                tc[rl * 72 + col] = f2bf(fmaxf(tacc[c4][r] + bias, 0.f));
            }
        }
        __syncthreads();
        // GEMM2: yacc += t @ W2c^T
#pragma unroll
        for (int ks = 0; ks < 2; ks++) {
            int ko = ks * 32 + (lane >> 4) * 8;
            int g = ks * 4 + (lane >> 4);
            s16x8 a = *(const s16x8*)&tc[(wid * 16 + (lane & 15)) * 72 + ko];
#pragma unroll
            for (int cf = 0; cf < 8; cf++) {
                int brow = cf * 16 + (lane & 15);
                s16x8 bf = *(const s16x8*)&w2c[brow * 64 + ((g ^ (brow & 7)) * 8)];
                yacc[cf] = MFMA32(a, bf, yacc[cf]);
            }
        }
        __syncthreads();
    }

    // epilogue: yb = h + ff + bias, stats
    float* pw = (float*)w1c;
#pragma unroll
    for (int cf = 0; cf < 8; cf++) {
        int d = cf * 16 + (lane & 15);
        float bias = bW2[d];
        float s = 0.f, s2 = 0.f;
#pragma unroll
        for (int r = 0; r < 4; r++) {
            int rl = wid * 16 + (lane >> 4) * 4 + r;
            int row = r0 + rl;
            if (row < S) {
                float hval = bf2f(hs[rl * 128 + (((d >> 3) ^ (rl & 7)) * 8) + (d & 7)]);
                float yv = hval + yacc[cf][r] + bias;
                yb[((size_t)b * S + row) * D + d] = yv;
                s += yv;
                s2 = fmaf(yv, yv, s2);
            }
        }
        s += __shfl_xor(s, 16); s += __shfl_xor(s, 32);
        s2 += __shfl_xor(s2, 16); s2 += __shfl_xor(s2, 32);
        if (lane < 16) {
            pw[(wid * 2 + 0) * 128 + d] = s;
            pw[(wid * 2 + 1) * 128 + d] = s2;
        }
    }
    __syncthreads();
    {
        int st = tid >> 7, d = tid & 127;
        float v = pw[(0 * 2 + st) * 128 + d] + pw[(1 * 2 + st) * 128 + d] +
                  pw[(2 * 2 + st) * 128 + d] + pw[(3 * 2 + st) * 128 + d];
        part[((size_t)(b * 16 + rb) * 2 + st) * 128 + d] = v;
    }
}

// ---------------- final reduce + norm ----------------
__global__ __launch_bounds__(256) void k_finalize(
        const float* __restrict__ part, float* __restrict__ acc) {
    int i = blockIdx.x * 256 + threadIdx.x;
    int b = i >> 8, k = i & 255;
    float s = 0.f;
#pragma unroll
    for (int c = 0; c < 16; c++) s += part[(size_t)(b * 16 + c) * 256 + k];
    acc[i] = s;
}

__global__ __launch_bounds__(256) void k_norm(
        const float* __restrict__ y, const float* __restrict__ acc,
        const float* __restrict__ g, const float* __restrict__ bb,
        float* __restrict__ out) {
    size_t i = (size_t)blockIdx.x * 256 + threadIdx.x;
    int d = (int)(i % D);
    int b = (int)(i / ((size_t)S * D));
    float mu = acc[b * 256 + d] * (1.f / S);
    float var = acc[b * 256 + 128 + d] * (1.f / S) - mu * mu;
    float v = (y[i] - mu) * rsqrtf(var + EPSN);
    out[i] = v * g[d] + bb[d];
}

extern "C" void kernel_launch(void* const* d_in, const int* in_sizes, int n_in,
                              void* d_out, int out_size, void* d_ws, size_t ws_size,
                              hipStream_t stream) {
    const float* depot = (const float*)d_in[0];
    const float* node  = (const float*)d_in[1];
    const float* dist  = (const float*)d_in[2];
    const float* log_scale = (const float*)d_in[3];
    const int*   flag  = (const int*)d_in[4];
    const float* Wd   = (const float*)d_in[5];
    const float* bd   = (const float*)d_in[6];
    const float* Wn   = (const float*)d_in[7];
    const float* bn   = (const float*)d_in[8];
    const float* Win  = (const float*)d_in[9];
    const float* bin_ = (const float*)d_in[10];
    const float* Wout = (const float*)d_in[11];
    const float* bout = (const float*)d_in[12];
    const float* Wq   = (const float*)d_in[13];
    const float* Wk   = (const float*)d_in[14];
    const float* Wv   = (const float*)d_in[15];
    const float* alpha= (const float*)d_in[16];
    const float* g1   = (const float*)d_in[17];
    const float* b1   = (const float*)d_in[18];
    const float* W1   = (const float*)d_in[19];
    const float* bW1  = (const float*)d_in[20];
    const float* W2   = (const float*)d_in[21];
    const float* bW2  = (const float*)d_in[22];
    const float* g2   = (const float*)d_in[23];
    const float* b2   = (const float*)d_in[24];

    float* ws = (float*)d_ws;
    size_t nxd = (size_t)B * S * D;                       // 4,096,000
    float* ya    = ws;
    float* yb    = ws + nxd;
    float* part1 = ws + 2 * nxd;                          // B*16*256 = 131072
    float* part2 = part1 + 131072;
    float* accb2 = part2 + 131072;                        // B*256
    unsigned short* sqb = (unsigned short*)(accb2 + 8192);          // B*S*D bf16
    unsigned short* mT  = sqb + nxd;                                // B*16*256*64
    unsigned short* wbf = mT + (size_t)B * 16 * 256 * 64;           // L*WSTR
    unsigned short* nd  = wbf + (size_t)L * WSTR;                   // B*1000*1024

    k_wprep<<<dim3(88, 6), 256, 0, stream>>>(Wq, Wk, Wv, W1, W2, wbf);
    k_prep<<<B * S, 256, 0, stream>>>(dist, nd);
    k_embed<<<B * S, 128, 0, stream>>>(depot, node, Wd, bd, Wn, bn, yb);
    k_rowxform<<<B, 128, 0, stream>>>(yb, Win, bin_, flag, 0);
    k_rowxform<<<B, 128, 0, stream>>>(yb, Wout, bout, flag, 1);

    for (int l = 0; l < L; l++) {
        int hasnorm = (l > 0) ? 1 : 0;
        const float* gpn = g2 + (l > 0 ? (l - 1) : 0) * D;
        const float* bpn = b2 + (l > 0 ? (l - 1) : 0) * D;
        const unsigned short* wl = wbf + (size_t)l * WSTR;
        k_qkv<<<B * 16, 256, 0, stream>>>(yb, part2, hasnorm, gpn, bpn, wl, sqb, mT);
        k_attn<<<B * 16, 512, 0, stream>>>(yb, part2, hasnorm, gpn, bpn,
                                           sqb, mT, nd, log_scale, alpha, l, ya, part1);
        k_ffn<<<B * 16, 256, 0, stream>>>(ya, part1, g1 + l * D, b1 + l * D,
                                          wl + 49152, wl + 114688,
                                          bW1 + (size_t)l * F, bW2 + (size_t)l * D, yb, part2);
    }
    k_finalize<<<32, 256, 0, stream>>>(part2, accb2);
    k_norm<<<B * S * D / 256, 256, 0, stream>>>(yb, accb2, g2 + 5 * D, b2 + 5 * D, (float*)d_out);
}

// Round 14
// 591.740 us; speedup vs baseline: 1.1813x; 1.0635x over previous
//
#include <hip/hip_runtime.h>
#include <hip/hip_bf16.h>
#include <float.h>
#include <math.h>

#define B 32
#define NN 999
#define S 1000
#define D 128
#define F 512
#define L 6
#define EPSN 1e-5f
#define WSTR 180224   // per-layer bf16 weight stride: 3*16384 + 2*65536

typedef __attribute__((ext_vector_type(4))) float f32x4;
typedef __attribute__((ext_vector_type(4))) short s16x4;
typedef __attribute__((ext_vector_type(8))) short s16x8;

#if defined(__has_builtin)
#if __has_builtin(__builtin_amdgcn_mfma_f32_16x16x32_bf16)
#define HAVE_MFMA32 1
#endif
#endif

#ifdef HAVE_MFMA32
#define MFMA32(a, b, c) __builtin_amdgcn_mfma_f32_16x16x32_bf16((a), (b), (c), 0, 0, 0)
#else
static __device__ __forceinline__ f32x4 mfma32_asm(s16x8 a, s16x8 b, f32x4 c) {
    asm volatile("v_mfma_f32_16x16x32_bf16 %0, %1, %2, %0\n\ts_nop 7\n\ts_nop 7"
                 : "+v"(c) : "v"(a), "v"(b));
    return c;
}
#define MFMA32(a, b, c) mfma32_asm((a), (b), (c))
#endif

__device__ __forceinline__ float n2n(float v) {
    if (v != v) return 0.f;
    if (isinf(v)) return v > 0.f ? FLT_MAX : -FLT_MAX;
    return v;
}

__device__ __forceinline__ unsigned short f2bf(float x) {
    unsigned u = __float_as_uint(x);
    return (unsigned short)((u + 0x7fffu + ((u >> 16) & 1u)) >> 16);
}

__device__ __forceinline__ float bf2f(unsigned short v) {
    return __uint_as_float(((unsigned)v) << 16);
}

// ---------------- one-time: weights -> bf16 ----------------
// layout per layer (stride WSTR): Wq 0, Wk 16384, Wv 32768, W1 49152, W2 114688
__global__ __launch_bounds__(256) void k_wprep(
        const float* __restrict__ Wq, const float* __restrict__ Wk,
        const float* __restrict__ Wv, const float* __restrict__ W1,
        const float* __restrict__ W2, unsigned short* __restrict__ wbf) {
    int bx = blockIdx.x, l = blockIdx.y;
    const float* src; int doff, off;
    if (bx < 8)       { src = Wq + (size_t)l * 16384; doff = 0;      off = bx * 2048; }
    else if (bx < 16) { src = Wk + (size_t)l * 16384; doff = 16384;  off = (bx - 8) * 2048; }
    else if (bx < 24) { src = Wv + (size_t)l * 16384; doff = 32768;  off = (bx - 16) * 2048; }
    else if (bx < 56) { src = W1 + (size_t)l * 65536; doff = 49152;  off = (bx - 24) * 2048; }
    else              { src = W2 + (size_t)l * 65536; doff = 114688; off = (bx - 56) * 2048; }
    int i = off + threadIdx.x * 8;
    float4 a4 = *(const float4*)(src + i);
    float4 b4 = *(const float4*)(src + i + 4);
    s16x8 p = {(short)f2bf(a4.x), (short)f2bf(a4.y), (short)f2bf(a4.z), (short)f2bf(a4.w),
               (short)f2bf(b4.x), (short)f2bf(b4.y), (short)f2bf(b4.z), (short)f2bf(b4.w)};
    *(s16x8*)(wbf + (size_t)l * WSTR + doff + i) = p;
}

// ---------------- one-time prep: dist -> bf16 padded ----------------
__global__ __launch_bounds__(256) void k_prep(
        const float* __restrict__ dist, unsigned short* __restrict__ nd) {
    int row = blockIdx.x;
    int col = threadIdx.x * 4;
    unsigned short* op = nd + (size_t)row * 1024 + col;
    if (col < 1000) {
        float4 v = *(const float4*)(dist + (size_t)row * 1000 + col);
        s16x4 p = {(short)f2bf(v.x), (short)f2bf(v.y), (short)f2bf(v.z), (short)f2bf(v.w)};
        *(s16x4*)op = p;
    } else {
        s16x4 z = {0, 0, 0, 0};
        *(s16x4*)op = z;
    }
}

__global__ __launch_bounds__(128) void k_embed(
        const float* __restrict__ depot, const float* __restrict__ node,
        const float* __restrict__ Wd, const float* __restrict__ bd,
        const float* __restrict__ Wn, const float* __restrict__ bn,
        float* __restrict__ x) {
    int row = blockIdx.x;
    int b = row / S, s = row % S;
    int d = threadIdx.x;
    float o;
    if (s == 0) {
        float x0 = depot[b * 2 + 0], x1 = depot[b * 2 + 1];
        o = Wd[d * 2 + 0] * x0 + Wd[d * 2 + 1] * x1 + bd[d];
    } else {
        const float* p = node + ((size_t)b * NN + (s - 1)) * 3;
        o = Wn[d * 3 + 0] * p[0] + Wn[d * 3 + 1] * p[1] + Wn[d * 3 + 2] * p[2] + bn[d];
    }
    x[(size_t)row * D + d] = o;
}

__global__ __launch_bounds__(128) void k_rowxform(
        float* __restrict__ x, const float* __restrict__ W,
        const float* __restrict__ bias, const int* __restrict__ flag, int mode) {
    int b = blockIdx.x;
    int d = threadIdx.x;
    __shared__ float row[D];
    int r = (mode == 0) ? 1 : (1 - flag[b]) * NN;
    float* xr = x + ((size_t)b * S + r) * D;
    row[d] = xr[d];
    __syncthreads();
    float acc = bias[d];
    for (int e = 0; e < D; e += 4) {
        const float4 w = *(const float4*)(W + (size_t)d * D + e);
        acc += w.x * row[e] + w.y * row[e + 1] + w.z * row[e + 2] + w.w * row[e + 3];
    }
    xr[d] = acc;
}

// ---------------- qkv: norm-fused input, LDS-staged bf16 weights, MFMA32, swizzled mT ----------------
__global__ __launch_bounds__(256) void k_qkv(
        const float* __restrict__ yprev, const float* __restrict__ part2, int hasnorm,
        const float* __restrict__ gp, const float* __restrict__ bp,
        const unsigned short* __restrict__ wl,
        unsigned short* __restrict__ sqb, unsigned short* __restrict__ mT) {
    int blk = blockIdx.x;
    int b = blk >> 4, rb = blk & 15;
    int s0 = rb * 64;
    int tid = threadIdx.x, lane = tid & 63, wid = tid >> 6;
    __shared__ __align__(16) unsigned short lds[18432];  // xs[64*40]+wt[3][128*40]; reused tile[256*72]
    __shared__ float nsc[128], nsh[128];
    __shared__ float accv[256];
    unsigned short* xs = lds;
    unsigned short* wt0 = lds + 2560;

    if (hasnorm) {
        int st = tid >> 7, d = tid & 127;
        float s = 0.f;
#pragma unroll
        for (int c = 0; c < 16; c++) s += part2[(size_t)(b * 32 + c * 2 + st) * 128 + d];
        accv[tid] = s;
    }
    __syncthreads();
    if (tid < 128) {
        float scv = 1.f, shv = 0.f;
        if (hasnorm) {
            float mu = accv[tid] * (1.f / S);
            float var = accv[128 + tid] * (1.f / S) - mu * mu;
            float rs = rsqrtf(var + EPSN);
            scv = rs * gp[tid];
            shv = bp[tid] - mu * scv;
        }
        nsc[tid] = scv; nsh[tid] = shv;
    }
    __syncthreads();

    f32x4 acc[3][8];
#pragma unroll
    for (int mm = 0; mm < 3; mm++)
#pragma unroll
        for (int cf = 0; cf < 8; cf++) acc[mm][cf] = {0.f, 0.f, 0.f, 0.f};

    for (int k0 = 0; k0 < D; k0 += 32) {
        {
            int i = tid >> 2, kq = (tid & 3) * 8;
            int s = s0 + i;
            int gs = s < S ? s : S - 1;
            const float* gpx = yprev + ((size_t)b * S + gs) * D + k0 + kq;
            float4 a4 = *(const float4*)gpx;
            float4 b4 = *(const float4*)(gpx + 4);
            const float* scp = &nsc[k0 + kq];
            const float* shp = &nsh[k0 + kq];
            s16x4 p0 = {(short)f2bf(a4.x * scp[0] + shp[0]), (short)f2bf(a4.y * scp[1] + shp[1]),
                        (short)f2bf(a4.z * scp[2] + shp[2]), (short)f2bf(a4.w * scp[3] + shp[3])};
            s16x4 p1 = {(short)f2bf(b4.x * scp[4] + shp[4]), (short)f2bf(b4.y * scp[5] + shp[5]),
                        (short)f2bf(b4.z * scp[6] + shp[6]), (short)f2bf(b4.w * scp[7] + shp[7])};
            *(s16x4*)&xs[i * 40 + kq] = p0;
            *(s16x4*)&xs[i * 40 + kq + 4] = p1;
        }
#pragma unroll
        for (int u0 = 0; u0 < 6; u0++) {
            int u = tid + u0 * 256;
            int mm = u >> 9;
            int v = u & 511;
            int c = v >> 2, kq = (v & 3) * 8;
            s16x8 w = *(const s16x8*)(wl + (size_t)mm * 16384 + (size_t)c * D + k0 + kq);
            *(s16x8*)&wt0[mm * 5120 + c * 40 + kq] = w;
        }
        __syncthreads();
        {
            int g8 = (lane >> 4) * 8;   // k-octet offset within the 32-k chunk
            s16x8 a = *(const s16x8*)&xs[(wid * 16 + (lane & 15)) * 40 + g8];
#pragma unroll
            for (int mm = 0; mm < 3; mm++)
#pragma unroll
                for (int cf = 0; cf < 8; cf++) {
                    s16x8 bf = *(const s16x8*)&wt0[mm * 5120 + (cf * 16 + (lane & 15)) * 40 + g8];
                    acc[mm][cf] = MFMA32(a, bf, acc[mm][cf]);
                }
        }
        __syncthreads();
    }

    // epilogue phase 1: acc -> tile[256 d][72]  (stride 72 shorts = 144 B, 16B-aligned rows)
    unsigned short* tile = lds;               // 256*72 = 18432
    int sl0 = wid * 16 + (lane >> 4) * 4;     // local k
#pragma unroll
    for (int cf = 0; cf < 8; cf++) {
        int d = cf * 16 + (lane & 15);
        s16x4 p0, p1;
#pragma unroll
        for (int r = 0; r < 4; r++) {
            int s = s0 + sl0 + r;
            if (s < S) {
                float qv = acc[0][cf][r], kv = acc[1][cf][r], vv = acc[2][cf][r];
                float ek = __expf(kv);
                sqb[((size_t)b * S + s) * D + d] = f2bf(1.f / (1.f + __expf(-qv)));
                p0[r] = (short)f2bf(ek * vv);
                p1[r] = (short)f2bf(ek);
            } else { p0[r] = 0; p1[r] = 0; }
        }
        *(s16x4*)&tile[d * 72 + sl0] = p0;
        *(s16x4*)&tile[(d + 128) * 72 + sl0] = p1;
    }
    __syncthreads();
    // epilogue phase 2: permuted read, fully coalesced 32KB store
    {
        unsigned short* base = mT + (((size_t)b * 16 + rb) * 256) * 64;
#pragma unroll
        for (int j = 0; j < 8; j++) {
            int u = j * 256 + tid;
            int d = u >> 3, sp = u & 7;
            int o = sp ^ (d & 7);
            s16x8 v = *(const s16x8*)&tile[d * 72 + o * 8];
            *(s16x8*)(base + (size_t)u * 8) = v;
        }
    }
}

// ---------------- attention: 8 waves (2 row-halves x 4 col-quarters), dbuf LDS ----------------
__global__ __launch_bounds__(512, 2) void k_attn(
        const float* __restrict__ yprev, const float* __restrict__ part2, int hasnorm,
        const float* __restrict__ gp, const float* __restrict__ bp,
        const unsigned short* __restrict__ sqb,
        const unsigned short* __restrict__ mT, const unsigned short* __restrict__ nd,
        const float* __restrict__ log_scale, const float* __restrict__ alpha, int l,
        float* __restrict__ y, float* __restrict__ part) {
    int blk0 = blockIdx.x;
    int blk = (blk0 & 7) * 64 + (blk0 >> 3);  // XCD-bijective swizzle (512 % 8 == 0)
    int b = blk >> 4, ib = blk & 15;
    int i0 = ib * 64;
    int tid = threadIdx.x, lane = tid & 63, wid = tid >> 6;
    int wr = wid & 1, wc = wid >> 1;          // row half (32 rows), col quarter (cols wc*64..+64)
    __shared__ __align__(16) unsigned short esL[2][64 * 64];   // 16 KB dbuf, swizzled
    __shared__ __align__(16) unsigned short mtL[2][256 * 64];  // 64 KB dbuf
    float sc = log_scale[0] * alpha[l];

    // norm coefficients (accv scratch lives in esL before main loop)
    float* accvA = (float*)esL;
    if (hasnorm && tid < 256) {
        int st = tid >> 7, d = tid & 127;
        float s = 0.f;
#pragma unroll
        for (int c = 0; c < 16; c++) s += part2[(size_t)(b * 32 + c * 2 + st) * 128 + d];
        accvA[tid] = s;
    }
    __syncthreads();

    int wcm = wc & 1;                          // d-quarter within 0..127 for this wave
    float rsc[4], rsh[4];
#pragma unroll
    for (int cf = 0; cf < 4; cf++) {
        int d = wcm * 64 + cf * 16 + (lane & 15);
        float scv = 1.f, shv = 0.f;
        if (hasnorm) {
            float mu = accvA[d] * (1.f / S);
            float var = accvA[128 + d] * (1.f / S) - mu * mu;
            float rs = rsqrtf(var + EPSN);
            scv = rs * gp[d];
            shv = bp[d] - mu * scv;
        }
        rsc[cf] = scv; rsh[cf] = shv;
    }
    __syncthreads();   // done with accvA scratch before esL[0] is written

    f32x4 acc[2][4];
#pragma unroll
    for (int rf = 0; rf < 2; rf++)
#pragma unroll
        for (int cf = 0; cf < 4; cf++) acc[rf][cf] = {0.f, 0.f, 0.f, 0.f};

    // es staging: 1 octet/thread (row = tid>>3, octet og = tid&7)
    int erow = tid >> 3, og = tid & 7;
    int gi = i0 + erow; if (gi > 999) gi = 999;
    const unsigned short* ndr = nd + (size_t)b * 1000 * 1024 + (size_t)gi * 1024 + og * 8;
    const unsigned short* mtb = mT + (size_t)b * 16 * 16384;
    int esoff = erow * 64 + ((og ^ (erow & 7)) * 8);

    // prologue: stage chunk 0 into buf0, issue chunk-1 loads
    s16x8 cn = *(const s16x8*)(ndr);
    s16x8 cm[4];
#pragma unroll
    for (int j = 0; j < 4; j++)
        cm[j] = *(const s16x8*)(mtb + (size_t)(j * 512 + tid) * 8);
    {
        s16x8 o0;
#pragma unroll
        for (int j = 0; j < 8; j++)
            o0[j] = (short)f2bf(__expf(-sc * bf2f((unsigned short)cn[j])));
        *(s16x8*)&esL[0][esoff] = o0;
#pragma unroll
        for (int j = 0; j < 4; j++)
            *(s16x8*)&mtL[0][(j * 512 + tid) * 8] = cm[j];
    }
    cn = *(const s16x8*)(ndr + 64);
#pragma unroll
    for (int j = 0; j < 4; j++)
        cm[j] = *(const s16x8*)(mtb + (size_t)16384 + (size_t)(j * 512 + tid) * 8);
    __syncthreads();

    int cur = 0;
    for (int kc = 0; kc < 16; kc++) {
        if (kc < 15) {
            // write buf[cur^1] with chunk kc+1 (from regs), overlapped with MFMA on buf[cur]
            s16x8 o0;
#pragma unroll
            for (int j = 0; j < 8; j++)
                o0[j] = (short)f2bf(__expf(-sc * bf2f((unsigned short)cn[j])));
            *(s16x8*)&esL[cur ^ 1][esoff] = o0;
#pragma unroll
            for (int j = 0; j < 4; j++)
                *(s16x8*)&mtL[cur ^ 1][(j * 512 + tid) * 8] = cm[j];
            // issue chunk kc+2 loads; in flight across MFMA + barrier + next write phase
            int kn = (kc + 2 <= 15) ? kc + 2 : 15;
            cn = *(const s16x8*)(ndr + kn * 64);
#pragma unroll
            for (int j = 0; j < 4; j++)
                cm[j] = *(const s16x8*)(mtb + (size_t)kn * 16384 + (size_t)(j * 512 + tid) * 8);
        }
#pragma unroll
        for (int ks = 0; ks < 2; ks++) {
            int ag = ks * 4 + (lane >> 4);
            int arow0 = wr * 32 + (lane & 15);
            int arow1 = arow0 + 16;
            s16x8 a0 = *(const s16x8*)&esL[cur][arow0 * 64 + ((ag ^ (arow0 & 7)) * 8)];
            s16x8 a1 = *(const s16x8*)&esL[cur][arow1 * 64 + ((ag ^ (arow1 & 7)) * 8)];
            __builtin_amdgcn_s_setprio(1);
#pragma unroll
            for (int cf = 0; cf < 4; cf++) {
                int c = wc * 64 + cf * 16 + (lane & 15);
                s16x8 bf = *(const s16x8*)&mtL[cur][c * 64 + ((ag ^ (c & 7)) * 8)];
                acc[0][cf] = MFMA32(a0, bf, acc[0][cf]);
                acc[1][cf] = MFMA32(a1, bf, acc[1][cf]);
            }
            __builtin_amdgcn_s_setprio(0);
        }
        __syncthreads();   // buf[cur^1] ready for next iter; buf[cur] free for rewrite after next iter
        cur ^= 1;
    }

    // epilogue: den waves (wc>=2) publish via LDS, num waves (wc<2) finish + stats
    float* pw = (float*)mtL[0];               // [64 rows][128 d] f32 = 32 KB
    if (wc >= 2) {
#pragma unroll
        for (int cf = 0; cf < 4; cf++) {
            int dcol = (wc - 2) * 64 + cf * 16 + (lane & 15);
#pragma unroll
            for (int rf = 0; rf < 2; rf++)
#pragma unroll
                for (int r = 0; r < 4; r++) {
                    int lrow = wr * 32 + rf * 16 + (lane >> 4) * 4 + r;
                    pw[lrow * 128 + dcol] = acc[rf][cf][r];
                }
        }
    }
    __syncthreads();
    float* sw = (float*)esL;                  // stats partials [2 row-halves][2 stat][128]
    if (wc < 2) {
#pragma unroll
        for (int cf = 0; cf < 4; cf++) {
            int d = wc * 64 + cf * 16 + (lane & 15);
            float s = 0.f, s2 = 0.f;
#pragma unroll
            for (int rf = 0; rf < 2; rf++)
#pragma unroll
                for (int r = 0; r < 4; r++) {
                    int lrow = wr * 32 + rf * 16 + (lane >> 4) * 4 + r;
                    int i = i0 + lrow;
                    if (i < S) {
                        size_t off = ((size_t)b * S + i) * D + d;
                        float w = n2n(acc[rf][cf][r]) / n2n(pw[lrow * 128 + d]);
                        float xv = yprev[off] * rsc[cf] + rsh[cf];
                        float yv = xv + bf2f(sqb[off]) * w;
                        y[off] = yv;
                        s += yv;
                        s2 = fmaf(yv, yv, s2);
                    }
                }
            s += __shfl_xor(s, 16); s += __shfl_xor(s, 32);
            s2 += __shfl_xor(s2, 16); s2 += __shfl_xor(s2, 32);
            if (lane < 16) {
                sw[(wr * 2 + 0) * 128 + d] = s;
                sw[(wr * 2 + 1) * 128 + d] = s2;
            }
        }
    }
    __syncthreads();
    if (tid < 256) {
        int st = tid >> 7, d = tid & 127;
        float v = sw[(0 * 2 + st) * 128 + d] + sw[(1 * 2 + st) * 128 + d];
        part[((size_t)(b * 16 + ib) * 2 + st) * 128 + d] = v;
    }
}

// ---------------- fused FFN: norm(part1) -> relu(h@W1^T+b) in LDS -> @W2^T + residual ----------------
__global__ __launch_bounds__(256) void k_ffn(
        const float* __restrict__ ya, const float* __restrict__ part1,
        const float* __restrict__ gp, const float* __restrict__ bp,
        const unsigned short* __restrict__ w1b, const unsigned short* __restrict__ w2b,
        const float* __restrict__ bW1, const float* __restrict__ bW2,
        float* __restrict__ yb, float* __restrict__ part) {
    int blk = blockIdx.x;
    int b = blk >> 4, rb = blk & 15;
    int r0 = rb * 64;
    int tid = threadIdx.x, lane = tid & 63, wid = tid >> 6;
    __shared__ __align__(16) unsigned short hs[64 * 128];    // normed h bf16, octet-swizzled
    __shared__ __align__(16) unsigned short w1c[64 * 128];   // W1 chunk [64 f][128 k], swizzled
    __shared__ __align__(16) unsigned short tc[64 * 72];     // t chunk [64 row][64 f], stride 144B
    __shared__ __align__(16) unsigned short w2c[128 * 64];   // W2 chunk [128 d][64 f], swizzled
    __shared__ float nsc[128], nsh[128];
    __shared__ float accv[256];

    {
        int st = tid >> 7, d = tid & 127;
        float s = 0.f;
#pragma unroll
        for (int c = 0; c < 16; c++) s += part1[(size_t)(b * 32 + c * 2 + st) * 128 + d];
        accv[tid] = s;
    }
    __syncthreads();
    if (tid < 128) {
        float mu = accv[tid] * (1.f / S);
        float var = accv[128 + tid] * (1.f / S) - mu * mu;
        float rs = rsqrtf(var + EPSN);
        float scv = rs * gp[tid];
        nsc[tid] = scv;
        nsh[tid] = bp[tid] - mu * scv;
    }
    __syncthreads();

    // stage normed h (64 rows x 128 k), octet-swizzled
    {
        int i = tid >> 2;
        int gs = r0 + i; if (gs >= S) gs = S - 1;
        const float* gpx = ya + ((size_t)b * S + gs) * D;
#pragma unroll
        for (int q = 0; q < 4; q++) {
            int col = (tid & 3) * 32 + q * 8;
            int g = col >> 3;
            float4 a4 = *(const float4*)(gpx + col);
            float4 b4 = *(const float4*)(gpx + col + 4);
            const float* scp = &nsc[col];
            const float* shp = &nsh[col];
            s16x4 p0 = {(short)f2bf(a4.x * scp[0] + shp[0]), (short)f2bf(a4.y * scp[1] + shp[1]),
                        (short)f2bf(a4.z * scp[2] + shp[2]), (short)f2bf(a4.w * scp[3] + shp[3])};
            s16x4 p1 = {(short)f2bf(b4.x * scp[4] + shp[4]), (short)f2bf(b4.y * scp[5] + shp[5]),
                        (short)f2bf(b4.z * scp[6] + shp[6]), (short)f2bf(b4.w * scp[7] + shp[7])};
            int base = i * 128 + ((g ^ (i & 7)) * 8);
            *(s16x4*)&hs[base] = p0;
            *(s16x4*)&hs[base + 4] = p1;
        }
    }

    f32x4 yacc[8];
#pragma unroll
    for (int cf = 0; cf < 8; cf++) yacc[cf] = {0.f, 0.f, 0.f, 0.f};

    for (int fc = 0; fc < 8; fc++) {
        int c0 = fc * 64;
        // stage W1 chunk [64 f][128 k], swizzled
        {
            int f = tid >> 2;
#pragma unroll
            for (int q = 0; q < 4; q++) {
                int col = (tid & 3) * 32 + q * 8;
                int g = col >> 3;
                s16x8 w = *(const s16x8*)(w1b + (size_t)(c0 + f) * D + col);
                *(s16x8*)&w1c[f * 128 + ((g ^ (f & 7)) * 8)] = w;
            }
        }
        // stage W2 chunk [128 d][64 f], swizzled
        {
            int d2 = tid >> 1;
#pragma unroll
            for (int q = 0; q < 4; q++) {
                int g = (tid & 1) * 4 + q;
                s16x8 w = *(const s16x8*)(w2b + (size_t)d2 * F + c0 + g * 8);
                *(s16x8*)&w2c[d2 * 64 + ((g ^ (d2 & 7)) * 8)] = w;
            }
        }
        __syncthreads();
        // GEMM1: t = relu(h @ W1c^T + bW1)
        f32x4 tacc[4];
#pragma unroll
        for (int c4 = 0; c4 < 4; c4++) tacc[c4] = {0.f, 0.f, 0.f, 0.f};
#pragma unroll
        for (int ks = 0; ks < 4; ks++) {
            int g = ks * 4 + (lane >> 4);
            int arow = wid * 16 + (lane & 15);
            s16x8 a = *(const s16x8*)&hs[arow * 128 + ((g ^ (arow & 7)) * 8)];
#pragma unroll
            for (int c4 = 0; c4 < 4; c4++) {
                int brow = c4 * 16 + (lane & 15);
                s16x8 bf = *(const s16x8*)&w1c[brow * 128 + ((g ^ (brow & 7)) * 8)];
                tacc[c4] = MFMA32(a, bf, tacc[c4]);
            }
        }
#pragma unroll
        for (int c4 = 0; c4 < 4; c4++) {
            int col = c4 * 16 + (lane & 15);
            float bias = bW1[c0 + col];
#pragma unroll
            for (int r = 0; r < 4; r++) {
                int rl = wid * 16 + (lane >> 4) * 4 + r;
                tc[rl * 72 + col] = f2bf(fmaxf(tacc[c4][r] + bias, 0.f));
            }
        }
        __syncthreads();
        // GEMM2: yacc += t @ W2c^T
#pragma unroll
        for (int ks = 0; ks < 2; ks++) {
            int ko = ks * 32 + (lane >> 4) * 8;
            int g = ks * 4 + (lane >> 4);
            s16x8 a = *(const s16x8*)&tc[(wid * 16 + (lane & 15)) * 72 + ko];
#pragma unroll
            for (int cf = 0; cf < 8; cf++) {
                int brow = cf * 16 + (lane & 15);
                s16x8 bf = *(const s16x8*)&w2c[brow * 64 + ((g ^ (brow & 7)) * 8)];
                yacc[cf] = MFMA32(a, bf, yacc[cf]);
            }
        }
        __syncthreads();
    }

    // epilogue: yb = h + ff + bias, stats
    float* pw = (float*)w1c;
#pragma unroll
    for (int cf = 0; cf < 8; cf++) {
        int d = cf * 16 + (lane & 15);
        float bias = bW2[d];
        float s = 0.f, s2 = 0.f;
#pragma unroll
        for (int r = 0; r < 4; r++) {
            int rl = wid * 16 + (lane >> 4) * 4 + r;
            int row = r0 + rl;
            if (row < S) {
                float hval = bf2f(hs[rl * 128 + (((d >> 3) ^ (rl & 7)) * 8) + (d & 7)]);
                float yv = hval + yacc[cf][r] + bias;
                yb[((size_t)b * S + row) * D + d] = yv;
                s += yv;
                s2 = fmaf(yv, yv, s2);
            }
        }
        s += __shfl_xor(s, 16); s += __shfl_xor(s, 32);
        s2 += __shfl_xor(s2, 16); s2 += __shfl_xor(s2, 32);
        if (lane < 16) {
            pw[(wid * 2 + 0) * 128 + d] = s;
            pw[(wid * 2 + 1) * 128 + d] = s2;
        }
    }
    __syncthreads();
    {
        int st = tid >> 7, d = tid & 127;
        float v = pw[(0 * 2 + st) * 128 + d] + pw[(1 * 2 + st) * 128 + d] +
                  pw[(2 * 2 + st) * 128 + d] + pw[(3 * 2 + st) * 128 + d];
        part[((size_t)(b * 16 + rb) * 2 + st) * 128 + d] = v;
    }
}

// ---------------- final reduce + norm ----------------
__global__ __launch_bounds__(256) void k_finalize(
        const float* __restrict__ part, float* __restrict__ acc) {
    int i = blockIdx.x * 256 + threadIdx.x;
    int b = i >> 8, k = i & 255;
    float s = 0.f;
#pragma unroll
    for (int c = 0; c < 16; c++) s += part[(size_t)(b * 16 + c) * 256 + k];
    acc[i] = s;
}

__global__ __launch_bounds__(256) void k_norm(
        const float* __restrict__ y, const float* __restrict__ acc,
        const float* __restrict__ g, const float* __restrict__ bb,
        float* __restrict__ out) {
    size_t i = (size_t)blockIdx.x * 256 + threadIdx.x;
    int d = (int)(i % D);
    int b = (int)(i / ((size_t)S * D));
    float mu = acc[b * 256 + d] * (1.f / S);
    float var = acc[b * 256 + 128 + d] * (1.f / S) - mu * mu;
    float v = (y[i] - mu) * rsqrtf(var + EPSN);
    out[i] = v * g[d] + bb[d];
}

extern "C" void kernel_launch(void* const* d_in, const int* in_sizes, int n_in,
                              void* d_out, int out_size, void* d_ws, size_t ws_size,
                              hipStream_t stream) {
    const float* depot = (const float*)d_in[0];
    const float* node  = (const float*)d_in[1];
    const float* dist  = (const float*)d_in[2];
    const float* log_scale = (const float*)d_in[3];
    const int*   flag  = (const int*)d_in[4];
    const float* Wd   = (const float*)d_in[5];
    const float* bd   = (const float*)d_in[6];
    const float* Wn   = (const float*)d_in[7];
    const float* bn   = (const float*)d_in[8];
    const float* Win  = (const float*)d_in[9];
    const float* bin_ = (const float*)d_in[10];
    const float* Wout = (const float*)d_in[11];
    const float* bout = (const float*)d_in[12];
    const float* Wq   = (const float*)d_in[13];
    const float* Wk   = (const float*)d_in[14];
    const float* Wv   = (const float*)d_in[15];
    const float* alpha= (const float*)d_in[16];
    const float* g1   = (const float*)d_in[17];
    const float* b1   = (const float*)d_in[18];
    const float* W1   = (const float*)d_in[19];
    const float* bW1  = (const float*)d_in[20];
    const float* W2   = (const float*)d_in[21];
    const float* bW2  = (const float*)d_in[22];
    const float* g2   = (const float*)d_in[23];
    const float* b2   = (const float*)d_in[24];

    float* ws = (float*)d_ws;
    size_t nxd = (size_t)B * S * D;                       // 4,096,000
    float* ya    = ws;
    float* yb    = ws + nxd;
    float* part1 = ws + 2 * nxd;                          // B*16*256 = 131072
    float* part2 = part1 + 131072;
    float* accb2 = part2 + 131072;                        // B*256
    unsigned short* sqb = (unsigned short*)(accb2 + 8192);          // B*S*D bf16
    unsigned short* mT  = sqb + nxd;                                // B*16*256*64
    unsigned short* wbf = mT + (size_t)B * 16 * 256 * 64;           // L*WSTR
    unsigned short* nd  = wbf + (size_t)L * WSTR;                   // B*1000*1024

    k_wprep<<<dim3(88, 6), 256, 0, stream>>>(Wq, Wk, Wv, W1, W2, wbf);
    k_prep<<<B * S, 256, 0, stream>>>(dist, nd);
    k_embed<<<B * S, 128, 0, stream>>>(depot, node, Wd, bd, Wn, bn, yb);
    k_rowxform<<<B, 128, 0, stream>>>(yb, Win, bin_, flag, 0);
    k_rowxform<<<B, 128, 0, stream>>>(yb, Wout, bout, flag, 1);

    for (int l = 0; l < L; l++) {
        int hasnorm = (l > 0) ? 1 : 0;
        const float* gpn = g2 + (l > 0 ? (l - 1) : 0) * D;
        const float* bpn = b2 + (l > 0 ? (l - 1) : 0) * D;
        const unsigned short* wl = wbf + (size_t)l * WSTR;
        k_qkv<<<B * 16, 256, 0, stream>>>(yb, part2, hasnorm, gpn, bpn, wl, sqb, mT);
        k_attn<<<B * 16, 512, 0, stream>>>(yb, part2, hasnorm, gpn, bpn,
                                           sqb, mT, nd, log_scale, alpha, l, ya, part1);
        k_ffn<<<B * 16, 256, 0, stream>>>(ya, part1, g1 + l * D, b1 + l * D,
                                          wl + 49152, wl + 114688,
                                          bW1 + (size_t)l * F, bW2 + (size_t)l * D, yb, part2);
    }
    k_finalize<<<32, 256, 0, stream>>>(part2, accb2);
    k_norm<<<B * S * D / 256, 256, 0, stream>>>(yb, accb2, g2 + 5 * D, b2 + 5 * D, (float*)d_out);
}

// Round 15
// 577.207 us; speedup vs baseline: 1.2111x; 1.0252x over previous
//
#include <hip/hip_runtime.h>
#include <hip/hip_bf16.h>
#include <float.h>
#include <math.h>

#define B 32
#define NN 999
#define S 1000
#define D 128
#define F 512
#define L 6
#define EPSN 1e-5f
#define WSTR 180224   // per-layer bf16 weight stride: 3*16384 + 2*65536

typedef __attribute__((ext_vector_type(4))) float f32x4;
typedef __attribute__((ext_vector_type(4))) short s16x4;
typedef __attribute__((ext_vector_type(8))) short s16x8;

#if defined(__has_builtin)
#if __has_builtin(__builtin_amdgcn_mfma_f32_16x16x32_bf16)
#define HAVE_MFMA32 1
#endif
#endif

#ifdef HAVE_MFMA32
#define MFMA32(a, b, c) __builtin_amdgcn_mfma_f32_16x16x32_bf16((a), (b), (c), 0, 0, 0)
#else
static __device__ __forceinline__ f32x4 mfma32_asm(s16x8 a, s16x8 b, f32x4 c) {
    asm volatile("v_mfma_f32_16x16x32_bf16 %0, %1, %2, %0\n\ts_nop 7\n\ts_nop 7"
                 : "+v"(c) : "v"(a), "v"(b));
    return c;
}
#define MFMA32(a, b, c) mfma32_asm((a), (b), (c))
#endif

__device__ __forceinline__ float n2n(float v) {
    if (v != v) return 0.f;
    if (isinf(v)) return v > 0.f ? FLT_MAX : -FLT_MAX;
    return v;
}

__device__ __forceinline__ unsigned short f2bf(float x) {
    unsigned u = __float_as_uint(x);
    return (unsigned short)((u + 0x7fffu + ((u >> 16) & 1u)) >> 16);
}

__device__ __forceinline__ float bf2f(unsigned short v) {
    return __uint_as_float(((unsigned)v) << 16);
}

// ---------------- one-time: weights -> bf16 ----------------
// layout per layer (stride WSTR): Wq 0, Wk 16384, Wv 32768, W1 49152, W2 114688
__global__ __launch_bounds__(256) void k_wprep(
        const float* __restrict__ Wq, const float* __restrict__ Wk,
        const float* __restrict__ Wv, const float* __restrict__ W1,
        const float* __restrict__ W2, unsigned short* __restrict__ wbf) {
    int bx = blockIdx.x, l = blockIdx.y;
    const float* src; int doff, off;
    if (bx < 8)       { src = Wq + (size_t)l * 16384; doff = 0;      off = bx * 2048; }
    else if (bx < 16) { src = Wk + (size_t)l * 16384; doff = 16384;  off = (bx - 8) * 2048; }
    else if (bx < 24) { src = Wv + (size_t)l * 16384; doff = 32768;  off = (bx - 16) * 2048; }
    else if (bx < 56) { src = W1 + (size_t)l * 65536; doff = 49152;  off = (bx - 24) * 2048; }
    else              { src = W2 + (size_t)l * 65536; doff = 114688; off = (bx - 56) * 2048; }
    int i = off + threadIdx.x * 8;
    float4 a4 = *(const float4*)(src + i);
    float4 b4 = *(const float4*)(src + i + 4);
    s16x8 p = {(short)f2bf(a4.x), (short)f2bf(a4.y), (short)f2bf(a4.z), (short)f2bf(a4.w),
               (short)f2bf(b4.x), (short)f2bf(b4.y), (short)f2bf(b4.z), (short)f2bf(b4.w)};
    *(s16x8*)(wbf + (size_t)l * WSTR + doff + i) = p;
}

// ---------------- one-time prep: dist -> bf16 padded ----------------
__global__ __launch_bounds__(256) void k_prep(
        const float* __restrict__ dist, unsigned short* __restrict__ nd) {
    int row = blockIdx.x;
    int col = threadIdx.x * 4;
    unsigned short* op = nd + (size_t)row * 1024 + col;
    if (col < 1000) {
        float4 v = *(const float4*)(dist + (size_t)row * 1000 + col);
        s16x4 p = {(short)f2bf(v.x), (short)f2bf(v.y), (short)f2bf(v.z), (short)f2bf(v.w)};
        *(s16x4*)op = p;
    } else {
        s16x4 z = {0, 0, 0, 0};
        *(s16x4*)op = z;
    }
}

__global__ __launch_bounds__(128) void k_embed(
        const float* __restrict__ depot, const float* __restrict__ node,
        const float* __restrict__ Wd, const float* __restrict__ bd,
        const float* __restrict__ Wn, const float* __restrict__ bn,
        float* __restrict__ x) {
    int row = blockIdx.x;
    int b = row / S, s = row % S;
    int d = threadIdx.x;
    float o;
    if (s == 0) {
        float x0 = depot[b * 2 + 0], x1 = depot[b * 2 + 1];
        o = Wd[d * 2 + 0] * x0 + Wd[d * 2 + 1] * x1 + bd[d];
    } else {
        const float* p = node + ((size_t)b * NN + (s - 1)) * 3;
        o = Wn[d * 3 + 0] * p[0] + Wn[d * 3 + 1] * p[1] + Wn[d * 3 + 2] * p[2] + bn[d];
    }
    x[(size_t)row * D + d] = o;
}

__global__ __launch_bounds__(128) void k_rowxform(
        float* __restrict__ x, const float* __restrict__ W,
        const float* __restrict__ bias, const int* __restrict__ flag, int mode) {
    int b = blockIdx.x;
    int d = threadIdx.x;
    __shared__ float row[D];
    int r = (mode == 0) ? 1 : (1 - flag[b]) * NN;
    float* xr = x + ((size_t)b * S + r) * D;
    row[d] = xr[d];
    __syncthreads();
    float acc = bias[d];
    for (int e = 0; e < D; e += 4) {
        const float4 w = *(const float4*)(W + (size_t)d * D + e);
        acc += w.x * row[e] + w.y * row[e + 1] + w.z * row[e + 2] + w.w * row[e + 3];
    }
    xr[d] = acc;
}

// ---------------- qkv: MFMA32, 2-row x 2-dcol wave tiling, swizzled mT ----------------
__global__ __launch_bounds__(256) void k_qkv(
        const float* __restrict__ yprev, const float* __restrict__ part2, int hasnorm,
        const float* __restrict__ gp, const float* __restrict__ bp,
        const unsigned short* __restrict__ wl,
        unsigned short* __restrict__ sqb, unsigned short* __restrict__ mT) {
    int blk = blockIdx.x;
    int b = blk >> 4, rb = blk & 15;
    int s0 = rb * 64;
    int tid = threadIdx.x, lane = tid & 63, wid = tid >> 6;
    int wr2 = wid & 1, wc2 = wid >> 1;        // 32-row half, 64-d half
    __shared__ __align__(16) unsigned short lds[18432];  // xs[64*40]+wt[3][128*40]; reused tile[256*72]
    __shared__ float nsc[128], nsh[128];
    __shared__ float accv[256];
    unsigned short* xs = lds;
    unsigned short* wt0 = lds + 2560;

    if (hasnorm) {
        int st = tid >> 7, d = tid & 127;
        float s = 0.f;
#pragma unroll
        for (int c = 0; c < 16; c++) s += part2[(size_t)(b * 32 + c * 2 + st) * 128 + d];
        accv[tid] = s;
    }
    __syncthreads();
    if (tid < 128) {
        float scv = 1.f, shv = 0.f;
        if (hasnorm) {
            float mu = accv[tid] * (1.f / S);
            float var = accv[128 + tid] * (1.f / S) - mu * mu;
            float rs = rsqrtf(var + EPSN);
            scv = rs * gp[tid];
            shv = bp[tid] - mu * scv;
        }
        nsc[tid] = scv; nsh[tid] = shv;
    }
    __syncthreads();

    f32x4 acc[2][3][4];
#pragma unroll
    for (int rf = 0; rf < 2; rf++)
#pragma unroll
        for (int mm = 0; mm < 3; mm++)
#pragma unroll
            for (int cf = 0; cf < 4; cf++) acc[rf][mm][cf] = {0.f, 0.f, 0.f, 0.f};

    for (int k0 = 0; k0 < D; k0 += 32) {
        {
            int i = tid >> 2, kq = (tid & 3) * 8;
            int s = s0 + i;
            int gs = s < S ? s : S - 1;
            const float* gpx = yprev + ((size_t)b * S + gs) * D + k0 + kq;
            float4 a4 = *(const float4*)gpx;
            float4 b4 = *(const float4*)(gpx + 4);
            const float* scp = &nsc[k0 + kq];
            const float* shp = &nsh[k0 + kq];
            s16x4 p0 = {(short)f2bf(a4.x * scp[0] + shp[0]), (short)f2bf(a4.y * scp[1] + shp[1]),
                        (short)f2bf(a4.z * scp[2] + shp[2]), (short)f2bf(a4.w * scp[3] + shp[3])};
            s16x4 p1 = {(short)f2bf(b4.x * scp[4] + shp[4]), (short)f2bf(b4.y * scp[5] + shp[5]),
                        (short)f2bf(b4.z * scp[6] + shp[6]), (short)f2bf(b4.w * scp[7] + shp[7])};
            *(s16x4*)&xs[i * 40 + kq] = p0;
            *(s16x4*)&xs[i * 40 + kq + 4] = p1;
        }
#pragma unroll
        for (int u0 = 0; u0 < 6; u0++) {
            int u = tid + u0 * 256;
            int mm = u >> 9;
            int v = u & 511;
            int c = v >> 2, kq = (v & 3) * 8;
            s16x8 w = *(const s16x8*)(wl + (size_t)mm * 16384 + (size_t)c * D + k0 + kq);
            *(s16x8*)&wt0[mm * 5120 + c * 40 + kq] = w;
        }
        __syncthreads();
        {
            int g8 = (lane >> 4) * 8;   // k-octet offset within the 32-k chunk
            int arow0 = wr2 * 32 + (lane & 15);
            s16x8 a0 = *(const s16x8*)&xs[arow0 * 40 + g8];
            s16x8 a1 = *(const s16x8*)&xs[(arow0 + 16) * 40 + g8];
#pragma unroll
            for (int mm = 0; mm < 3; mm++)
#pragma unroll
                for (int cf = 0; cf < 4; cf++) {
                    int c = wc2 * 64 + cf * 16 + (lane & 15);
                    s16x8 bf = *(const s16x8*)&wt0[mm * 5120 + c * 40 + g8];
                    acc[0][mm][cf] = MFMA32(a0, bf, acc[0][mm][cf]);
                    acc[1][mm][cf] = MFMA32(a1, bf, acc[1][mm][cf]);
                }
        }
        __syncthreads();
    }

    // epilogue phase 1: acc -> tile[256 d][72]
    unsigned short* tile = lds;               // 256*72 = 18432
#pragma unroll
    for (int rf = 0; rf < 2; rf++) {
        int sl0 = wr2 * 32 + rf * 16 + (lane >> 4) * 4;
#pragma unroll
        for (int cf = 0; cf < 4; cf++) {
            int d = wc2 * 64 + cf * 16 + (lane & 15);
            s16x4 p0, p1;
#pragma unroll
            for (int r = 0; r < 4; r++) {
                int s = s0 + sl0 + r;
                if (s < S) {
                    float qv = acc[rf][0][cf][r], kv = acc[rf][1][cf][r], vv = acc[rf][2][cf][r];
                    float ek = __expf(kv);
                    sqb[((size_t)b * S + s) * D + d] = f2bf(1.f / (1.f + __expf(-qv)));
                    p0[r] = (short)f2bf(ek * vv);
                    p1[r] = (short)f2bf(ek);
                } else { p0[r] = 0; p1[r] = 0; }
            }
            *(s16x4*)&tile[d * 72 + sl0] = p0;
            *(s16x4*)&tile[(d + 128) * 72 + sl0] = p1;
        }
    }
    __syncthreads();
    // epilogue phase 2: permuted read, fully coalesced 32KB store
    {
        unsigned short* base = mT + (((size_t)b * 16 + rb) * 256) * 64;
#pragma unroll
        for (int j = 0; j < 8; j++) {
            int u = j * 256 + tid;
            int d = u >> 3, sp = u & 7;
            int o = sp ^ (d & 7);
            s16x8 v = *(const s16x8*)&tile[d * 72 + o * 8];
            *(s16x8*)(base + (size_t)u * 8) = v;
        }
    }
}

// ---------------- attention: 8 waves (2 row-halves x 4 col-quarters), dbuf LDS ----------------
__global__ __launch_bounds__(512, 2) void k_attn(
        const float* __restrict__ yprev, const float* __restrict__ part2, int hasnorm,
        const float* __restrict__ gp, const float* __restrict__ bp,
        const unsigned short* __restrict__ sqb,
        const unsigned short* __restrict__ mT, const unsigned short* __restrict__ nd,
        const float* __restrict__ log_scale, const float* __restrict__ alpha, int l,
        float* __restrict__ y, float* __restrict__ part) {
    int blk0 = blockIdx.x;
    int blk = (blk0 & 7) * 64 + (blk0 >> 3);  // XCD-bijective swizzle (512 % 8 == 0)
    int b = blk >> 4, ib = blk & 15;
    int i0 = ib * 64;
    int tid = threadIdx.x, lane = tid & 63, wid = tid >> 6;
    int wr = wid & 1, wc = wid >> 1;          // row half (32 rows), col quarter (cols wc*64..+64)
    __shared__ __align__(16) unsigned short esL[2][64 * 64];   // 16 KB dbuf, swizzled
    __shared__ __align__(16) unsigned short mtL[2][256 * 64];  // 64 KB dbuf
    float sc = log_scale[0] * alpha[l];

    // norm coefficients (accv scratch lives in esL before main loop)
    float* accvA = (float*)esL;
    if (hasnorm && tid < 256) {
        int st = tid >> 7, d = tid & 127;
        float s = 0.f;
#pragma unroll
        for (int c = 0; c < 16; c++) s += part2[(size_t)(b * 32 + c * 2 + st) * 128 + d];
        accvA[tid] = s;
    }
    __syncthreads();

    int wcm = wc & 1;                          // d-quarter within 0..127 for this wave
    float rsc[4], rsh[4];
#pragma unroll
    for (int cf = 0; cf < 4; cf++) {
        int d = wcm * 64 + cf * 16 + (lane & 15);
        float scv = 1.f, shv = 0.f;
        if (hasnorm) {
            float mu = accvA[d] * (1.f / S);
            float var = accvA[128 + d] * (1.f / S) - mu * mu;
            float rs = rsqrtf(var + EPSN);
            scv = rs * gp[d];
            shv = bp[d] - mu * scv;
        }
        rsc[cf] = scv; rsh[cf] = shv;
    }
    __syncthreads();   // done with accvA scratch before esL[0] is written

    f32x4 acc[2][4];
#pragma unroll
    for (int rf = 0; rf < 2; rf++)
#pragma unroll
        for (int cf = 0; cf < 4; cf++) acc[rf][cf] = {0.f, 0.f, 0.f, 0.f};

    // es staging: 1 octet/thread (row = tid>>3, octet og = tid&7)
    int erow = tid >> 3, og = tid & 7;
    int gi = i0 + erow; if (gi > 999) gi = 999;
    const unsigned short* ndr = nd + (size_t)b * 1000 * 1024 + (size_t)gi * 1024 + og * 8;
    const unsigned short* mtb = mT + (size_t)b * 16 * 16384;
    int esoff = erow * 64 + ((og ^ (erow & 7)) * 8);

    // prologue: stage chunk 0 into buf0, issue chunk-1 loads
    s16x8 cn = *(const s16x8*)(ndr);
    s16x8 cm[4];
#pragma unroll
    for (int j = 0; j < 4; j++)
        cm[j] = *(const s16x8*)(mtb + (size_t)(j * 512 + tid) * 8);
    {
        s16x8 o0;
#pragma unroll
        for (int j = 0; j < 8; j++)
            o0[j] = (short)f2bf(__expf(-sc * bf2f((unsigned short)cn[j])));
        *(s16x8*)&esL[0][esoff] = o0;
#pragma unroll
        for (int j = 0; j < 4; j++)
            *(s16x8*)&mtL[0][(j * 512 + tid) * 8] = cm[j];
    }
    cn = *(const s16x8*)(ndr + 64);
#pragma unroll
    for (int j = 0; j < 4; j++)
        cm[j] = *(const s16x8*)(mtb + (size_t)16384 + (size_t)(j * 512 + tid) * 8);
    __syncthreads();

    int cur = 0;
    for (int kc = 0; kc < 16; kc++) {
        if (kc < 15) {
            // write buf[cur^1] with chunk kc+1 (from regs), overlapped with MFMA on buf[cur]
            s16x8 o0;
#pragma unroll
            for (int j = 0; j < 8; j++)
                o0[j] = (short)f2bf(__expf(-sc * bf2f((unsigned short)cn[j])));
            *(s16x8*)&esL[cur ^ 1][esoff] = o0;
#pragma unroll
            for (int j = 0; j < 4; j++)
                *(s16x8*)&mtL[cur ^ 1][(j * 512 + tid) * 8] = cm[j];
            // issue chunk kc+2 loads; in flight across MFMA + barrier + next write phase
            int kn = (kc + 2 <= 15) ? kc + 2 : 15;
            cn = *(const s16x8*)(ndr + kn * 64);
#pragma unroll
            for (int j = 0; j < 4; j++)
                cm[j] = *(const s16x8*)(mtb + (size_t)kn * 16384 + (size_t)(j * 512 + tid) * 8);
        }
#pragma unroll
        for (int ks = 0; ks < 2; ks++) {
            int ag = ks * 4 + (lane >> 4);
            int arow0 = wr * 32 + (lane & 15);
            int arow1 = arow0 + 16;
            s16x8 a0 = *(const s16x8*)&esL[cur][arow0 * 64 + ((ag ^ (arow0 & 7)) * 8)];
            s16x8 a1 = *(const s16x8*)&esL[cur][arow1 * 64 + ((ag ^ (arow1 & 7)) * 8)];
            __builtin_amdgcn_s_setprio(1);
#pragma unroll
            for (int cf = 0; cf < 4; cf++) {
                int c = wc * 64 + cf * 16 + (lane & 15);
                s16x8 bf = *(const s16x8*)&mtL[cur][c * 64 + ((ag ^ (c & 7)) * 8)];
                acc[0][cf] = MFMA32(a0, bf, acc[0][cf]);
                acc[1][cf] = MFMA32(a1, bf, acc[1][cf]);
            }
            __builtin_amdgcn_s_setprio(0);
        }
        __syncthreads();   // buf[cur^1] ready for next iter; buf[cur] free for rewrite after next iter
        cur ^= 1;
    }

    // epilogue: den waves (wc>=2) publish via LDS, num waves (wc<2) finish + stats
    float* pw = (float*)mtL[0];               // [64 rows][128 d] f32 = 32 KB
    if (wc >= 2) {
#pragma unroll
        for (int cf = 0; cf < 4; cf++) {
            int dcol = (wc - 2) * 64 + cf * 16 + (lane & 15);
#pragma unroll
            for (int rf = 0; rf < 2; rf++)
#pragma unroll
                for (int r = 0; r < 4; r++) {
                    int lrow = wr * 32 + rf * 16 + (lane >> 4) * 4 + r;
                    pw[lrow * 128 + dcol] = acc[rf][cf][r];
                }
        }
    }
    __syncthreads();
    float* sw = (float*)esL;                  // stats partials [2 row-halves][2 stat][128]
    if (wc < 2) {
#pragma unroll
        for (int cf = 0; cf < 4; cf++) {
            int d = wc * 64 + cf * 16 + (lane & 15);
            float s = 0.f, s2 = 0.f;
#pragma unroll
            for (int rf = 0; rf < 2; rf++)
#pragma unroll
                for (int r = 0; r < 4; r++) {
                    int lrow = wr * 32 + rf * 16 + (lane >> 4) * 4 + r;
                    int i = i0 + lrow;
                    if (i < S) {
                        size_t off = ((size_t)b * S + i) * D + d;
                        float w = n2n(acc[rf][cf][r]) / n2n(pw[lrow * 128 + d]);
                        float xv = yprev[off] * rsc[cf] + rsh[cf];
                        float yv = xv + bf2f(sqb[off]) * w;
                        y[off] = yv;
                        s += yv;
                        s2 = fmaf(yv, yv, s2);
                    }
                }
            s += __shfl_xor(s, 16); s += __shfl_xor(s, 32);
            s2 += __shfl_xor(s2, 16); s2 += __shfl_xor(s2, 32);
            if (lane < 16) {
                sw[(wr * 2 + 0) * 128 + d] = s;
                sw[(wr * 2 + 1) * 128 + d] = s2;
            }
        }
    }
    __syncthreads();
    if (tid < 256) {
        int st = tid >> 7, d = tid & 127;
        float v = sw[(0 * 2 + st) * 128 + d] + sw[(1 * 2 + st) * 128 + d];
        part[((size_t)(b * 16 + ib) * 2 + st) * 128 + d] = v;
    }
}

// ---------------- fused FFN: 2x2 wave quadrants in both GEMMs ----------------
__global__ __launch_bounds__(256) void k_ffn(
        const float* __restrict__ ya, const float* __restrict__ part1,
        const float* __restrict__ gp, const float* __restrict__ bp,
        const unsigned short* __restrict__ w1b, const unsigned short* __restrict__ w2b,
        const float* __restrict__ bW1, const float* __restrict__ bW2,
        float* __restrict__ yb, float* __restrict__ part) {
    int blk = blockIdx.x;
    int b = blk >> 4, rb = blk & 15;
    int r0 = rb * 64;
    int tid = threadIdx.x, lane = tid & 63, wid = tid >> 6;
    int wr2 = wid & 1, wc2 = wid >> 1;        // 32-row half, col half
    __shared__ __align__(16) unsigned short hs[64 * 128];    // normed h bf16, octet-swizzled
    __shared__ __align__(16) unsigned short w1c[64 * 128];   // W1 chunk [64 f][128 k], swizzled
    __shared__ __align__(16) unsigned short tc[64 * 72];     // t chunk [64 row][64 f], stride 144B
    __shared__ __align__(16) unsigned short w2c[128 * 64];   // W2 chunk [128 d][64 f], swizzled
    __shared__ float nsc[128], nsh[128];
    __shared__ float accv[256];

    {
        int st = tid >> 7, d = tid & 127;
        float s = 0.f;
#pragma unroll
        for (int c = 0; c < 16; c++) s += part1[(size_t)(b * 32 + c * 2 + st) * 128 + d];
        accv[tid] = s;
    }
    __syncthreads();
    if (tid < 128) {
        float mu = accv[tid] * (1.f / S);
        float var = accv[128 + tid] * (1.f / S) - mu * mu;
        float rs = rsqrtf(var + EPSN);
        float scv = rs * gp[tid];
        nsc[tid] = scv;
        nsh[tid] = bp[tid] - mu * scv;
    }
    __syncthreads();

    // stage normed h (64 rows x 128 k), octet-swizzled
    {
        int i = tid >> 2;
        int gs = r0 + i; if (gs >= S) gs = S - 1;
        const float* gpx = ya + ((size_t)b * S + gs) * D;
#pragma unroll
        for (int q = 0; q < 4; q++) {
            int col = (tid & 3) * 32 + q * 8;
            int g = col >> 3;
            float4 a4 = *(const float4*)(gpx + col);
            float4 b4 = *(const float4*)(gpx + col + 4);
            const float* scp = &nsc[col];
            const float* shp = &nsh[col];
            s16x4 p0 = {(short)f2bf(a4.x * scp[0] + shp[0]), (short)f2bf(a4.y * scp[1] + shp[1]),
                        (short)f2bf(a4.z * scp[2] + shp[2]), (short)f2bf(a4.w * scp[3] + shp[3])};
            s16x4 p1 = {(short)f2bf(b4.x * scp[4] + shp[4]), (short)f2bf(b4.y * scp[5] + shp[5]),
                        (short)f2bf(b4.z * scp[6] + shp[6]), (short)f2bf(b4.w * scp[7] + shp[7])};
            int base = i * 128 + ((g ^ (i & 7)) * 8);
            *(s16x4*)&hs[base] = p0;
            *(s16x4*)&hs[base + 4] = p1;
        }
    }

    f32x4 yacc[2][4];
#pragma unroll
    for (int rf = 0; rf < 2; rf++)
#pragma unroll
        for (int cf = 0; cf < 4; cf++) yacc[rf][cf] = {0.f, 0.f, 0.f, 0.f};

    for (int fc = 0; fc < 8; fc++) {
        int c0 = fc * 64;
        // stage W1 chunk [64 f][128 k], swizzled
        {
            int f = tid >> 2;
#pragma unroll
            for (int q = 0; q < 4; q++) {
                int col = (tid & 3) * 32 + q * 8;
                int g = col >> 3;
                s16x8 w = *(const s16x8*)(w1b + (size_t)(c0 + f) * D + col);
                *(s16x8*)&w1c[f * 128 + ((g ^ (f & 7)) * 8)] = w;
            }
        }
        // stage W2 chunk [128 d][64 f], swizzled
        {
            int d2 = tid >> 1;
#pragma unroll
            for (int q = 0; q < 4; q++) {
                int g = (tid & 1) * 4 + q;
                s16x8 w = *(const s16x8*)(w2b + (size_t)d2 * F + c0 + g * 8);
                *(s16x8*)&w2c[d2 * 64 + ((g ^ (d2 & 7)) * 8)] = w;
            }
        }
        __syncthreads();
        // GEMM1: t = relu(h @ W1c^T + bW1); wave quadrant 32 rows x 32 cols
        f32x4 tacc[2][2];
#pragma unroll
        for (int rf = 0; rf < 2; rf++)
#pragma unroll
            for (int cf = 0; cf < 2; cf++) tacc[rf][cf] = {0.f, 0.f, 0.f, 0.f};
#pragma unroll
        for (int ks = 0; ks < 4; ks++) {
            int g = ks * 4 + (lane >> 4);
            int arow0 = wr2 * 32 + (lane & 15);
            int arow1 = arow0 + 16;
            s16x8 a0 = *(const s16x8*)&hs[arow0 * 128 + ((g ^ (arow0 & 7)) * 8)];
            s16x8 a1 = *(const s16x8*)&hs[arow1 * 128 + ((g ^ (arow1 & 7)) * 8)];
#pragma unroll
            for (int cf = 0; cf < 2; cf++) {
                int brow = wc2 * 32 + cf * 16 + (lane & 15);
                s16x8 bf = *(const s16x8*)&w1c[brow * 128 + ((g ^ (brow & 7)) * 8)];
                tacc[0][cf] = MFMA32(a0, bf, tacc[0][cf]);
                tacc[1][cf] = MFMA32(a1, bf, tacc[1][cf]);
            }
        }
#pragma unroll
        for (int rf = 0; rf < 2; rf++)
#pragma unroll
            for (int cf = 0; cf < 2; cf++) {
                int col = wc2 * 32 + cf * 16 + (lane & 15);
                float bias = bW1[c0 + col];
#pragma unroll
                for (int r = 0; r < 4; r++) {
                    int rl = wr2 * 32 + rf * 16 + (lane >> 4) * 4 + r;
                    tc[rl * 72 + col] = f2bf(fmaxf(tacc[rf][cf][r] + bias, 0.f));
                }
            }
        __syncthreads();
        // GEMM2: yacc += t @ W2c^T; wave quadrant 32 rows x 64 d-cols
#pragma unroll
        for (int ks = 0; ks < 2; ks++) {
            int ko = ks * 32 + (lane >> 4) * 8;
            int g = ks * 4 + (lane >> 4);
            int arow0 = wr2 * 32 + (lane & 15);
            int arow1 = arow0 + 16;
            s16x8 a0 = *(const s16x8*)&tc[arow0 * 72 + ko];
            s16x8 a1 = *(const s16x8*)&tc[arow1 * 72 + ko];
#pragma unroll
            for (int cf = 0; cf < 4; cf++) {
                int brow = wc2 * 64 + cf * 16 + (lane & 15);
                s16x8 bf = *(const s16x8*)&w2c[brow * 64 + ((g ^ (brow & 7)) * 8)];
                yacc[0][cf] = MFMA32(a0, bf, yacc[0][cf]);
                yacc[1][cf] = MFMA32(a1, bf, yacc[1][cf]);
            }
        }
        __syncthreads();
    }

    // epilogue: yb = h + ff + bias, stats (wave covers rows wr2*32..+32, d wc2*64..+64)
    float* pw = (float*)w1c;                  // [2 row-halves][2 stat][128] f32
#pragma unroll
    for (int cf = 0; cf < 4; cf++) {
        int d = wc2 * 64 + cf * 16 + (lane & 15);
        float bias = bW2[d];
        float s = 0.f, s2 = 0.f;
#pragma unroll
        for (int rf = 0; rf < 2; rf++)
#pragma unroll
            for (int r = 0; r < 4; r++) {
                int rl = wr2 * 32 + rf * 16 + (lane >> 4) * 4 + r;
                int row = r0 + rl;
                if (row < S) {
                    float hval = bf2f(hs[rl * 128 + (((d >> 3) ^ (rl & 7)) * 8) + (d & 7)]);
                    float yv = hval + yacc[rf][cf][r] + bias;
                    yb[((size_t)b * S + row) * D + d] = yv;
                    s += yv;
                    s2 = fmaf(yv, yv, s2);
                }
            }
        s += __shfl_xor(s, 16); s += __shfl_xor(s, 32);
        s2 += __shfl_xor(s2, 16); s2 += __shfl_xor(s2, 32);
        if (lane < 16) {
            pw[(wr2 * 2 + 0) * 128 + d] = s;
            pw[(wr2 * 2 + 1) * 128 + d] = s2;
        }
    }
    __syncthreads();
    {
        int st = tid >> 7, d = tid & 127;
        float v = pw[(0 * 2 + st) * 128 + d] + pw[(1 * 2 + st) * 128 + d];
        part[((size_t)(b * 16 + rb) * 2 + st) * 128 + d] = v;
    }
}

// ---------------- final reduce + norm ----------------
__global__ __launch_bounds__(256) void k_finalize(
        const float* __restrict__ part, float* __restrict__ acc) {
    int i = blockIdx.x * 256 + threadIdx.x;
    int b = i >> 8, k = i & 255;
    float s = 0.f;
#pragma unroll
    for (int c = 0; c < 16; c++) s += part[(size_t)(b * 16 + c) * 256 + k];
    acc[i] = s;
}

__global__ __launch_bounds__(256) void k_norm(
        const float* __restrict__ y, const float* __restrict__ acc,
        const float* __restrict__ g, const float* __restrict__ bb,
        float* __restrict__ out) {
    size_t i = (size_t)blockIdx.x * 256 + threadIdx.x;
    int d = (int)(i % D);
    int b = (int)(i / ((size_t)S * D));
    float mu = acc[b * 256 + d] * (1.f / S);
    float var = acc[b * 256 + 128 + d] * (1.f / S) - mu * mu;
    float v = (y[i] - mu) * rsqrtf(var + EPSN);
    out[i] = v * g[d] + bb[d];
}

extern "C" void kernel_launch(void* const* d_in, const int* in_sizes, int n_in,
                              void* d_out, int out_size, void* d_ws, size_t ws_size,
                              hipStream_t stream) {
    const float* depot = (const float*)d_in[0];
    const float* node  = (const float*)d_in[1];
    const float* dist  = (const float*)d_in[2];
    const float* log_scale = (const float*)d_in[3];
    const int*   flag  = (const int*)d_in[4];
    const float* Wd   = (const float*)d_in[5];
    const float* bd   = (const float*)d_in[6];
    const float* Wn   = (const float*)d_in[7];
    const float* bn   = (const float*)d_in[8];
    const float* Win  = (const float*)d_in[9];
    const float* bin_ = (const float*)d_in[10];
    const float* Wout = (const float*)d_in[11];
    const float* bout = (const float*)d_in[12];
    const float* Wq   = (const float*)d_in[13];
    const float* Wk   = (const float*)d_in[14];
    const float* Wv   = (const float*)d_in[15];
    const float* alpha= (const float*)d_in[16];
    const float* g1   = (const float*)d_in[17];
    const float* b1   = (const float*)d_in[18];
    const float* W1   = (const float*)d_in[19];
    const float* bW1  = (const float*)d_in[20];
    const float* W2   = (const float*)d_in[21];
    const float* bW2  = (const float*)d_in[22];
    const float* g2   = (const float*)d_in[23];
    const float* b2   = (const float*)d_in[24];

    float* ws = (float*)d_ws;
    size_t nxd = (size_t)B * S * D;                       // 4,096,000
    float* ya    = ws;
    float* yb    = ws + nxd;
    float* part1 = ws + 2 * nxd;                          // B*16*256 = 131072
    float* part2 = part1 + 131072;
    float* accb2 = part2 + 131072;                        // B*256
    unsigned short* sqb = (unsigned short*)(accb2 + 8192);          // B*S*D bf16
    unsigned short* mT  = sqb + nxd;                                // B*16*256*64
    unsigned short* wbf = mT + (size_t)B * 16 * 256 * 64;           // L*WSTR
    unsigned short* nd  = wbf + (size_t)L * WSTR;                   // B*1000*1024

    k_wprep<<<dim3(88, 6), 256, 0, stream>>>(Wq, Wk, Wv, W1, W2, wbf);
    k_prep<<<B * S, 256, 0, stream>>>(dist, nd);
    k_embed<<<B * S, 128, 0, stream>>>(depot, node, Wd, bd, Wn, bn, yb);
    k_rowxform<<<B, 128, 0, stream>>>(yb, Win, bin_, flag, 0);
    k_rowxform<<<B, 128, 0, stream>>>(yb, Wout, bout, flag, 1);

    for (int l = 0; l < L; l++) {
        int hasnorm = (l > 0) ? 1 : 0;
        const float* gpn = g2 + (l > 0 ? (l - 1) : 0) * D;
        const float* bpn = b2 + (l > 0 ? (l - 1) : 0) * D;
        const unsigned short* wl = wbf + (size_t)l * WSTR;
        k_qkv<<<B * 16, 256, 0, stream>>>(yb, part2, hasnorm, gpn, bpn, wl, sqb, mT);
        k_attn<<<B * 16, 512, 0, stream>>>(yb, part2, hasnorm, gpn, bpn,
                                           sqb, mT, nd, log_scale, alpha, l, ya, part1);
        k_ffn<<<B * 16, 256, 0, stream>>>(ya, part1, g1 + l * D, b1 + l * D,
                                          wl + 49152, wl + 114688,
                                          bW1 + (size_t)l * F, bW2 + (size_t)l * D, yb, part2);
    }
    k_finalize<<<32, 256, 0, stream>>>(part2, accb2);
    k_norm<<<B * S * D / 256, 256, 0, stream>>>(yb, accb2, g2 + 5 * D, b2 + 5 * D, (float*)d_out);
}

// Round 18
// 553.420 us; speedup vs baseline: 1.2631x; 1.0430x over previous
//
#include <hip/hip_runtime.h>
#include <hip/hip_bf16.h>
#include <float.h>
#include <math.h>

#define B 32
#define NN 999
#define S 1000
#define D 128
#define F 512
#define L 6
#define EPSN 1e-5f
#define WSTR 180224   // per-layer bf16 weight stride: 3*16384 + 2*65536

typedef __attribute__((ext_vector_type(4))) float f32x4;
typedef __attribute__((ext_vector_type(4))) short s16x4;
typedef __attribute__((ext_vector_type(8))) short s16x8;

#if defined(__has_builtin)
#if __has_builtin(__builtin_amdgcn_mfma_f32_16x16x32_bf16)
#define HAVE_MFMA32 1
#endif
#endif

#ifdef HAVE_MFMA32
#define MFMA32(a, b, c) __builtin_amdgcn_mfma_f32_16x16x32_bf16((a), (b), (c), 0, 0, 0)
#else
static __device__ __forceinline__ f32x4 mfma32_asm(s16x8 a, s16x8 b, f32x4 c) {
    asm volatile("v_mfma_f32_16x16x32_bf16 %0, %1, %2, %0\n\ts_nop 7\n\ts_nop 7"
                 : "+v"(c) : "v"(a), "v"(b));
    return c;
}
#define MFMA32(a, b, c) mfma32_asm((a), (b), (c))
#endif

__device__ __forceinline__ float n2n(float v) {
    if (v != v) return 0.f;
    if (isinf(v)) return v > 0.f ? FLT_MAX : -FLT_MAX;
    return v;
}

__device__ __forceinline__ unsigned short f2bf(float x) {
    unsigned u = __float_as_uint(x);
    return (unsigned short)((u + 0x7fffu + ((u >> 16) & 1u)) >> 16);
}

__device__ __forceinline__ float bf2f(unsigned short v) {
    return __uint_as_float(((unsigned)v) << 16);
}

// ---------------- one-time: weights -> bf16 ----------------
// layout per layer (stride WSTR): Wq 0, Wk 16384, Wv 32768, W1 49152, W2 114688
__global__ __launch_bounds__(256) void k_wprep(
        const float* __restrict__ Wq, const float* __restrict__ Wk,
        const float* __restrict__ Wv, const float* __restrict__ W1,
        const float* __restrict__ W2, unsigned short* __restrict__ wbf) {
    int bx = blockIdx.x, l = blockIdx.y;
    const float* src; int doff, off;
    if (bx < 8)       { src = Wq + (size_t)l * 16384; doff = 0;      off = bx * 2048; }
    else if (bx < 16) { src = Wk + (size_t)l * 16384; doff = 16384;  off = (bx - 8) * 2048; }
    else if (bx < 24) { src = Wv + (size_t)l * 16384; doff = 32768;  off = (bx - 16) * 2048; }
    else if (bx < 56) { src = W1 + (size_t)l * 65536; doff = 49152;  off = (bx - 24) * 2048; }
    else              { src = W2 + (size_t)l * 65536; doff = 114688; off = (bx - 56) * 2048; }
    int i = off + threadIdx.x * 8;
    float4 a4 = *(const float4*)(src + i);
    float4 b4 = *(const float4*)(src + i + 4);
    s16x8 p = {(short)f2bf(a4.x), (short)f2bf(a4.y), (short)f2bf(a4.z), (short)f2bf(a4.w),
               (short)f2bf(b4.x), (short)f2bf(b4.y), (short)f2bf(b4.z), (short)f2bf(b4.w)};
    *(s16x8*)(wbf + (size_t)l * WSTR + doff + i) = p;
}

// ---------------- one-time prep: dist -> bf16 padded ----------------
__global__ __launch_bounds__(256) void k_prep(
        const float* __restrict__ dist, unsigned short* __restrict__ nd) {
    int row = blockIdx.x;
    int col = threadIdx.x * 4;
    unsigned short* op = nd + (size_t)row * 1024 + col;
    if (col < 1000) {
        float4 v = *(const float4*)(dist + (size_t)row * 1000 + col);
        s16x4 p = {(short)f2bf(v.x), (short)f2bf(v.y), (short)f2bf(v.z), (short)f2bf(v.w)};
        *(s16x4*)op = p;
    } else {
        s16x4 z = {0, 0, 0, 0};
        *(s16x4*)op = z;
    }
}

__global__ __launch_bounds__(128) void k_embed(
        const float* __restrict__ depot, const float* __restrict__ node,
        const float* __restrict__ Wd, const float* __restrict__ bd,
        const float* __restrict__ Wn, const float* __restrict__ bn,
        unsigned short* __restrict__ x) {
    int row = blockIdx.x;
    int b = row / S, s = row % S;
    int d = threadIdx.x;
    float o;
    if (s == 0) {
        float x0 = depot[b * 2 + 0], x1 = depot[b * 2 + 1];
        o = Wd[d * 2 + 0] * x0 + Wd[d * 2 + 1] * x1 + bd[d];
    } else {
        const float* p = node + ((size_t)b * NN + (s - 1)) * 3;
        o = Wn[d * 3 + 0] * p[0] + Wn[d * 3 + 1] * p[1] + Wn[d * 3 + 2] * p[2] + bn[d];
    }
    x[(size_t)row * D + d] = f2bf(o);
}

__global__ __launch_bounds__(128) void k_rowxform(
        unsigned short* __restrict__ x, const float* __restrict__ W,
        const float* __restrict__ bias, const int* __restrict__ flag, int mode) {
    int b = blockIdx.x;
    int d = threadIdx.x;
    __shared__ float row[D];
    int r = (mode == 0) ? 1 : (1 - flag[b]) * NN;
    unsigned short* xr = x + ((size_t)b * S + r) * D;
    row[d] = bf2f(xr[d]);
    __syncthreads();
    float acc = bias[d];
    for (int e = 0; e < D; e += 4) {
        const float4 w = *(const float4*)(W + (size_t)d * D + e);
        acc += w.x * row[e] + w.y * row[e + 1] + w.z * row[e + 2] + w.w * row[e + 3];
    }
    __syncthreads();
    xr[d] = f2bf(acc);
}

// ---------------- qkv: MFMA32, 2-row x 2-dcol wave tiling, swizzled mT (bf16 residual in) ----------------
__global__ __launch_bounds__(256) void k_qkv(
        const unsigned short* __restrict__ yprev, const float* __restrict__ part2, int hasnorm,
        const float* __restrict__ gp, const float* __restrict__ bp,
        const unsigned short* __restrict__ wl,
        unsigned short* __restrict__ sqb, unsigned short* __restrict__ mT) {
    int blk = blockIdx.x;
    int b = blk >> 4, rb = blk & 15;
    int s0 = rb * 64;
    int tid = threadIdx.x, lane = tid & 63, wid = tid >> 6;
    int wr2 = wid & 1, wc2 = wid >> 1;        // 32-row half, 64-d half
    __shared__ __align__(16) unsigned short lds[18432];  // xs[64*40]+wt[3][128*40]; reused tile[256*72]
    __shared__ float nsc[128], nsh[128];
    __shared__ float accv[256];
    unsigned short* xs = lds;
    unsigned short* wt0 = lds + 2560;

    if (hasnorm) {
        int st = tid >> 7, d = tid & 127;
        float s = 0.f;
#pragma unroll
        for (int c = 0; c < 16; c++) s += part2[(size_t)(b * 32 + c * 2 + st) * 128 + d];
        accv[tid] = s;
    }
    __syncthreads();
    if (tid < 128) {
        float scv = 1.f, shv = 0.f;
        if (hasnorm) {
            float mu = accv[tid] * (1.f / S);
            float var = accv[128 + tid] * (1.f / S) - mu * mu;
            float rs = rsqrtf(var + EPSN);
            scv = rs * gp[tid];
            shv = bp[tid] - mu * scv;
        }
        nsc[tid] = scv; nsh[tid] = shv;
    }
    __syncthreads();

    f32x4 acc[2][3][4];
#pragma unroll
    for (int rf = 0; rf < 2; rf++)
#pragma unroll
        for (int mm = 0; mm < 3; mm++)
#pragma unroll
            for (int cf = 0; cf < 4; cf++) acc[rf][mm][cf] = {0.f, 0.f, 0.f, 0.f};

    for (int k0 = 0; k0 < D; k0 += 32) {
        {
            int i = tid >> 2, kq = (tid & 3) * 8;
            int s = s0 + i;
            int gs = s < S ? s : S - 1;
            const unsigned short* gpx = yprev + ((size_t)b * S + gs) * D + k0 + kq;
            s16x8 v = *(const s16x8*)gpx;
            const float* scp = &nsc[k0 + kq];
            const float* shp = &nsh[k0 + kq];
            s16x8 p;
#pragma unroll
            for (int j = 0; j < 8; j++)
                p[j] = (short)f2bf(bf2f((unsigned short)v[j]) * scp[j] + shp[j]);
            *(s16x8*)&xs[i * 40 + kq] = p;
        }
#pragma unroll
        for (int u0 = 0; u0 < 6; u0++) {
            int u = tid + u0 * 256;
            int mm = u >> 9;
            int v = u & 511;
            int c = v >> 2, kq = (v & 3) * 8;
            s16x8 w = *(const s16x8*)(wl + (size_t)mm * 16384 + (size_t)c * D + k0 + kq);
            *(s16x8*)&wt0[mm * 5120 + c * 40 + kq] = w;
        }
        __syncthreads();
        {
            int g8 = (lane >> 4) * 8;   // k-octet offset within the 32-k chunk
            int arow0 = wr2 * 32 + (lane & 15);
            s16x8 a0 = *(const s16x8*)&xs[arow0 * 40 + g8];
            s16x8 a1 = *(const s16x8*)&xs[(arow0 + 16) * 40 + g8];
#pragma unroll
            for (int mm = 0; mm < 3; mm++)
#pragma unroll
                for (int cf = 0; cf < 4; cf++) {
                    int c = wc2 * 64 + cf * 16 + (lane & 15);
                    s16x8 bf = *(const s16x8*)&wt0[mm * 5120 + c * 40 + g8];
                    acc[0][mm][cf] = MFMA32(a0, bf, acc[0][mm][cf]);
                    acc[1][mm][cf] = MFMA32(a1, bf, acc[1][mm][cf]);
                }
        }
        __syncthreads();
    }

    // epilogue phase 1: acc -> tile[256 d][72]
    unsigned short* tile = lds;               // 256*72 = 18432
#pragma unroll
    for (int rf = 0; rf < 2; rf++) {
        int sl0 = wr2 * 32 + rf * 16 + (lane >> 4) * 4;
#pragma unroll
        for (int cf = 0; cf < 4; cf++) {
            int d = wc2 * 64 + cf * 16 + (lane & 15);
            s16x4 p0, p1;
#pragma unroll
            for (int r = 0; r < 4; r++) {
                int s = s0 + sl0 + r;
                if (s < S) {
                    float qv = acc[rf][0][cf][r], kv = acc[rf][1][cf][r], vv = acc[rf][2][cf][r];
                    float ek = __expf(kv);
                    sqb[((size_t)b * S + s) * D + d] = f2bf(1.f / (1.f + __expf(-qv)));
                    p0[r] = (short)f2bf(ek * vv);
                    p1[r] = (short)f2bf(ek);
                } else { p0[r] = 0; p1[r] = 0; }
            }
            *(s16x4*)&tile[d * 72 + sl0] = p0;
            *(s16x4*)&tile[(d + 128) * 72 + sl0] = p1;
        }
    }
    __syncthreads();
    // epilogue phase 2: permuted read, fully coalesced 32KB store
    {
        unsigned short* base = mT + (((size_t)b * 16 + rb) * 256) * 64;
#pragma unroll
        for (int j = 0; j < 8; j++) {
            int u = j * 256 + tid;
            int d = u >> 3, sp = u & 7;
            int o = sp ^ (d & 7);
            s16x8 v = *(const s16x8*)&tile[d * 72 + o * 8];
            *(s16x8*)(base + (size_t)u * 8) = v;
        }
    }
}

// ---------------- attention: 8 waves (2 row-halves x 4 col-quarters), dbuf LDS (bf16 residual) ----------------
__global__ __launch_bounds__(512, 2) void k_attn(
        const unsigned short* __restrict__ yprev, const float* __restrict__ part2, int hasnorm,
        const float* __restrict__ gp, const float* __restrict__ bp,
        const unsigned short* __restrict__ sqb,
        const unsigned short* __restrict__ mT, const unsigned short* __restrict__ nd,
        const float* __restrict__ log_scale, const float* __restrict__ alpha, int l,
        unsigned short* __restrict__ y, float* __restrict__ part) {
    int blk0 = blockIdx.x;
    int blk = (blk0 & 7) * 64 + (blk0 >> 3);  // XCD-bijective swizzle (512 % 8 == 0)
    int b = blk >> 4, ib = blk & 15;
    int i0 = ib * 64;
    int tid = threadIdx.x, lane = tid & 63, wid = tid >> 6;
    int wr = wid & 1, wc = wid >> 1;          // row half (32 rows), col quarter (cols wc*64..+64)
    __shared__ __align__(16) unsigned short esL[2][64 * 64];   // 16 KB dbuf, swizzled
    __shared__ __align__(16) unsigned short mtL[2][256 * 64];  // 64 KB dbuf
    float sc = log_scale[0] * alpha[l];

    // norm coefficients (accv scratch lives in esL before main loop)
    float* accvA = (float*)esL;
    if (hasnorm && tid < 256) {
        int st = tid >> 7, d = tid & 127;
        float s = 0.f;
#pragma unroll
        for (int c = 0; c < 16; c++) s += part2[(size_t)(b * 32 + c * 2 + st) * 128 + d];
        accvA[tid] = s;
    }
    __syncthreads();

    int wcm = wc & 1;                          // d-quarter within 0..127 for this wave
    float rsc[4], rsh[4];
#pragma unroll
    for (int cf = 0; cf < 4; cf++) {
        int d = wcm * 64 + cf * 16 + (lane & 15);
        float scv = 1.f, shv = 0.f;
        if (hasnorm) {
            float mu = accvA[d] * (1.f / S);
            float var = accvA[128 + d] * (1.f / S) - mu * mu;
            float rs = rsqrtf(var + EPSN);
            scv = rs * gp[d];
            shv = bp[d] - mu * scv;
        }
        rsc[cf] = scv; rsh[cf] = shv;
    }
    __syncthreads();   // done with accvA scratch before esL[0] is written

    f32x4 acc[2][4];
#pragma unroll
    for (int rf = 0; rf < 2; rf++)
#pragma unroll
        for (int cf = 0; cf < 4; cf++) acc[rf][cf] = {0.f, 0.f, 0.f, 0.f};

    // es staging: 1 octet/thread (row = tid>>3, octet og = tid&7)
    int erow = tid >> 3, og = tid & 7;
    int gi = i0 + erow; if (gi > 999) gi = 999;
    const unsigned short* ndr = nd + (size_t)b * 1000 * 1024 + (size_t)gi * 1024 + og * 8;
    const unsigned short* mtb = mT + (size_t)b * 16 * 16384;
    int esoff = erow * 64 + ((og ^ (erow & 7)) * 8);

    // prologue: stage chunk 0 into buf0, issue chunk-1 loads
    s16x8 cn = *(const s16x8*)(ndr);
    s16x8 cm[4];
#pragma unroll
    for (int j = 0; j < 4; j++)
        cm[j] = *(const s16x8*)(mtb + (size_t)(j * 512 + tid) * 8);
    {
        s16x8 o0;
#pragma unroll
        for (int j = 0; j < 8; j++)
            o0[j] = (short)f2bf(__expf(-sc * bf2f((unsigned short)cn[j])));
        *(s16x8*)&esL[0][esoff] = o0;
#pragma unroll
        for (int j = 0; j < 4; j++)
            *(s16x8*)&mtL[0][(j * 512 + tid) * 8] = cm[j];
    }
    cn = *(const s16x8*)(ndr + 64);
#pragma unroll
    for (int j = 0; j < 4; j++)
        cm[j] = *(const s16x8*)(mtb + (size_t)16384 + (size_t)(j * 512 + tid) * 8);
    __syncthreads();

    int cur = 0;
    for (int kc = 0; kc < 16; kc++) {
        if (kc < 15) {
            // write buf[cur^1] with chunk kc+1 (from regs), overlapped with MFMA on buf[cur]
            s16x8 o0;
#pragma unroll
            for (int j = 0; j < 8; j++)
                o0[j] = (short)f2bf(__expf(-sc * bf2f((unsigned short)cn[j])));
            *(s16x8*)&esL[cur ^ 1][esoff] = o0;
#pragma unroll
            for (int j = 0; j < 4; j++)
                *(s16x8*)&mtL[cur ^ 1][(j * 512 + tid) * 8] = cm[j];
            // issue chunk kc+2 loads; in flight across MFMA + barrier + next write phase
            int kn = (kc + 2 <= 15) ? kc + 2 : 15;
            cn = *(const s16x8*)(ndr + kn * 64);
#pragma unroll
            for (int j = 0; j < 4; j++)
                cm[j] = *(const s16x8*)(mtb + (size_t)kn * 16384 + (size_t)(j * 512 + tid) * 8);
        }
#pragma unroll
        for (int ks = 0; ks < 2; ks++) {
            int ag = ks * 4 + (lane >> 4);
            int arow0 = wr * 32 + (lane & 15);
            int arow1 = arow0 + 16;
            s16x8 a0 = *(const s16x8*)&esL[cur][arow0 * 64 + ((ag ^ (arow0 & 7)) * 8)];
            s16x8 a1 = *(const s16x8*)&esL[cur][arow1 * 64 + ((ag ^ (arow1 & 7)) * 8)];
            __builtin_amdgcn_s_setprio(1);
#pragma unroll
            for (int cf = 0; cf < 4; cf++) {
                int c = wc * 64 + cf * 16 + (lane & 15);
                s16x8 bf = *(const s16x8*)&mtL[cur][c * 64 + ((ag ^ (c & 7)) * 8)];
                acc[0][cf] = MFMA32(a0, bf, acc[0][cf]);
                acc[1][cf] = MFMA32(a1, bf, acc[1][cf]);
            }
            __builtin_amdgcn_s_setprio(0);
        }
        __syncthreads();   // buf[cur^1] ready for next iter; buf[cur] free for rewrite after next iter
        cur ^= 1;
    }

    // epilogue: den waves (wc>=2) publish via LDS, num waves (wc<2) finish + stats
    float* pw = (float*)mtL[0];               // [64 rows][128 d] f32 = 32 KB
    if (wc >= 2) {
#pragma unroll
        for (int cf = 0; cf < 4; cf++) {
            int dcol = (wc - 2) * 64 + cf * 16 + (lane & 15);
#pragma unroll
            for (int rf = 0; rf < 2; rf++)
#pragma unroll
                for (int r = 0; r < 4; r++) {
                    int lrow = wr * 32 + rf * 16 + (lane >> 4) * 4 + r;
                    pw[lrow * 128 + dcol] = acc[rf][cf][r];
                }
        }
    }
    __syncthreads();
    float* sw = (float*)esL;                  // stats partials [2 row-halves][2 stat][128]
    if (wc < 2) {
#pragma unroll
        for (int cf = 0; cf < 4; cf++) {
            int d = wc * 64 + cf * 16 + (lane & 15);
            float s = 0.f, s2 = 0.f;
#pragma unroll
            for (int rf = 0; rf < 2; rf++)
#pragma unroll
                for (int r = 0; r < 4; r++) {
                    int lrow = wr * 32 + rf * 16 + (lane >> 4) * 4 + r;
                    int i = i0 + lrow;
                    if (i < S) {
                        size_t off = ((size_t)b * S + i) * D + d;
                        float w = n2n(acc[rf][cf][r]) / n2n(pw[lrow * 128 + d]);
                        float xv = bf2f(yprev[off]) * rsc[cf] + rsh[cf];
                        float yv = xv + bf2f(sqb[off]) * w;
                        y[off] = f2bf(yv);
                        s += yv;
                        s2 = fmaf(yv, yv, s2);
                    }
                }
            s += __shfl_xor(s, 16); s += __shfl_xor(s, 32);
            s2 += __shfl_xor(s2, 16); s2 += __shfl_xor(s2, 32);
            if (lane < 16) {
                sw[(wr * 2 + 0) * 128 + d] = s;
                sw[(wr * 2 + 1) * 128 + d] = s2;
            }
        }
    }
    __syncthreads();
    if (tid < 256) {
        int st = tid >> 7, d = tid & 127;
        float v = sw[(0 * 2 + st) * 128 + d] + sw[(1 * 2 + st) * 128 + d];
        part[((size_t)(b * 16 + ib) * 2 + st) * 128 + d] = v;
    }
}

// ---------------- fused FFN: 2x2 wave quadrants in both GEMMs (bf16 residual) ----------------
__global__ __launch_bounds__(256) void k_ffn(
        const unsigned short* __restrict__ ya, const float* __restrict__ part1,
        const float* __restrict__ gp, const float* __restrict__ bp,
        const unsigned short* __restrict__ w1b, const unsigned short* __restrict__ w2b,
        const float* __restrict__ bW1, const float* __restrict__ bW2,
        unsigned short* __restrict__ yb, float* __restrict__ part) {
    int blk = blockIdx.x;
    int b = blk >> 4, rb = blk & 15;
    int r0 = rb * 64;
    int tid = threadIdx.x, lane = tid & 63, wid = tid >> 6;
    int wr2 = wid & 1, wc2 = wid >> 1;        // 32-row half, col half
    __shared__ __align__(16) unsigned short hs[64 * 128];    // normed h bf16, octet-swizzled
    __shared__ __align__(16) unsigned short w1c[64 * 128];   // W1 chunk [64 f][128 k], swizzled
    __shared__ __align__(16) unsigned short tc[64 * 72];     // t chunk [64 row][64 f], stride 144B
    __shared__ __align__(16) unsigned short w2c[128 * 64];   // W2 chunk [128 d][64 f], swizzled
    __shared__ float nsc[128], nsh[128];
    __shared__ float accv[256];

    {
        int st = tid >> 7, d = tid & 127;
        float s = 0.f;
#pragma unroll
        for (int c = 0; c < 16; c++) s += part1[(size_t)(b * 32 + c * 2 + st) * 128 + d];
        accv[tid] = s;
    }
    __syncthreads();
    if (tid < 128) {
        float mu = accv[tid] * (1.f / S);
        float var = accv[128 + tid] * (1.f / S) - mu * mu;
        float rs = rsqrtf(var + EPSN);
        float scv = rs * gp[tid];
        nsc[tid] = scv;
        nsh[tid] = bp[tid] - mu * scv;
    }
    __syncthreads();

    // stage normed h (64 rows x 128 k), octet-swizzled (bf16 source)
    {
        int i = tid >> 2;
        int gs = r0 + i; if (gs >= S) gs = S - 1;
        const unsigned short* gpx = ya + ((size_t)b * S + gs) * D;
#pragma unroll
        for (int q = 0; q < 4; q++) {
            int col = (tid & 3) * 32 + q * 8;
            int g = col >> 3;
            s16x8 v = *(const s16x8*)(gpx + col);
            const float* scp = &nsc[col];
            const float* shp = &nsh[col];
            s16x8 p;
#pragma unroll
            for (int j = 0; j < 8; j++)
                p[j] = (short)f2bf(bf2f((unsigned short)v[j]) * scp[j] + shp[j]);
            *(s16x8*)&hs[i * 128 + ((g ^ (i & 7)) * 8)] = p;
        }
    }

    f32x4 yacc[2][4];
#pragma unroll
    for (int rf = 0; rf < 2; rf++)
#pragma unroll
        for (int cf = 0; cf < 4; cf++) yacc[rf][cf] = {0.f, 0.f, 0.f, 0.f};

    for (int fc = 0; fc < 8; fc++) {
        int c0 = fc * 64;
        // stage W1 chunk [64 f][128 k], swizzled
        {
            int f = tid >> 2;
#pragma unroll
            for (int q = 0; q < 4; q++) {
                int col = (tid & 3) * 32 + q * 8;
                int g = col >> 3;
                s16x8 w = *(const s16x8*)(w1b + (size_t)(c0 + f) * D + col);
                *(s16x8*)&w1c[f * 128 + ((g ^ (f & 7)) * 8)] = w;
            }
        }
        // stage W2 chunk [128 d][64 f], swizzled
        {
            int d2 = tid >> 1;
#pragma unroll
            for (int q = 0; q < 4; q++) {
                int g = (tid & 1) * 4 + q;
                s16x8 w = *(const s16x8*)(w2b + (size_t)d2 * F + c0 + g * 8);
                *(s16x8*)&w2c[d2 * 64 + ((g ^ (d2 & 7)) * 8)] = w;
            }
        }
        __syncthreads();
        // GEMM1: t = relu(h @ W1c^T + bW1); wave quadrant 32 rows x 32 cols
        f32x4 tacc[2][2];
#pragma unroll
        for (int rf = 0; rf < 2; rf++)
#pragma unroll
            for (int cf = 0; cf < 2; cf++) tacc[rf][cf] = {0.f, 0.f, 0.f, 0.f};
#pragma unroll
        for (int ks = 0; ks < 4; ks++) {
            int g = ks * 4 + (lane >> 4);
            int arow0 = wr2 * 32 + (lane & 15);
            int arow1 = arow0 + 16;
            s16x8 a0 = *(const s16x8*)&hs[arow0 * 128 + ((g ^ (arow0 & 7)) * 8)];
            s16x8 a1 = *(const s16x8*)&hs[arow1 * 128 + ((g ^ (arow1 & 7)) * 8)];
#pragma unroll
            for (int cf = 0; cf < 2; cf++) {
                int brow = wc2 * 32 + cf * 16 + (lane & 15);
                s16x8 bf = *(const s16x8*)&w1c[brow * 128 + ((g ^ (brow & 7)) * 8)];
                tacc[0][cf] = MFMA32(a0, bf, tacc[0][cf]);
                tacc[1][cf] = MFMA32(a1, bf, tacc[1][cf]);
            }
        }
#pragma unroll
        for (int rf = 0; rf < 2; rf++)
#pragma unroll
            for (int cf = 0; cf < 2; cf++) {
                int col = wc2 * 32 + cf * 16 + (lane & 15);
                float bias = bW1[c0 + col];
#pragma unroll
                for (int r = 0; r < 4; r++) {
                    int rl = wr2 * 32 + rf * 16 + (lane >> 4) * 4 + r;
                    tc[rl * 72 + col] = f2bf(fmaxf(tacc[rf][cf][r] + bias, 0.f));
                }
            }
        __syncthreads();
        // GEMM2: yacc += t @ W2c^T; wave quadrant 32 rows x 64 d-cols
#pragma unroll
        for (int ks = 0; ks < 2; ks++) {
            int ko = ks * 32 + (lane >> 4) * 8;
            int g = ks * 4 + (lane >> 4);
            int arow0 = wr2 * 32 + (lane & 15);
            int arow1 = arow0 + 16;
            s16x8 a0 = *(const s16x8*)&tc[arow0 * 72 + ko];
            s16x8 a1 = *(const s16x8*)&tc[arow1 * 72 + ko];
#pragma unroll
            for (int cf = 0; cf < 4; cf++) {
                int brow = wc2 * 64 + cf * 16 + (lane & 15);
                s16x8 bf = *(const s16x8*)&w2c[brow * 64 + ((g ^ (brow & 7)) * 8)];
                yacc[0][cf] = MFMA32(a0, bf, yacc[0][cf]);
                yacc[1][cf] = MFMA32(a1, bf, yacc[1][cf]);
            }
        }
        __syncthreads();
    }

    // epilogue: yb = h + ff + bias, stats (wave covers rows wr2*32..+32, d wc2*64..+64)
    float* pw = (float*)w1c;                  // [2 row-halves][2 stat][128] f32
#pragma unroll
    for (int cf = 0; cf < 4; cf++) {
        int d = wc2 * 64 + cf * 16 + (lane & 15);
        float bias = bW2[d];
        float s = 0.f, s2 = 0.f;
#pragma unroll
        for (int rf = 0; rf < 2; rf++)
#pragma unroll
            for (int r = 0; r < 4; r++) {
                int rl = wr2 * 32 + rf * 16 + (lane >> 4) * 4 + r;
                int row = r0 + rl;
                if (row < S) {
                    float hval = bf2f(hs[rl * 128 + (((d >> 3) ^ (rl & 7)) * 8) + (d & 7)]);
                    float yv = hval + yacc[rf][cf][r] + bias;
                    yb[((size_t)b * S + row) * D + d] = f2bf(yv);
                    s += yv;
                    s2 = fmaf(yv, yv, s2);
                }
            }
        s += __shfl_xor(s, 16); s += __shfl_xor(s, 32);
        s2 += __shfl_xor(s2, 16); s2 += __shfl_xor(s2, 32);
        if (lane < 16) {
            pw[(wr2 * 2 + 0) * 128 + d] = s;
            pw[(wr2 * 2 + 1) * 128 + d] = s2;
        }
    }
    __syncthreads();
    {
        int st = tid >> 7, d = tid & 127;
        float v = pw[(0 * 2 + st) * 128 + d] + pw[(1 * 2 + st) * 128 + d];
        part[((size_t)(b * 16 + rb) * 2 + st) * 128 + d] = v;
    }
}

// ---------------- final reduce + norm ----------------
__global__ __launch_bounds__(256) void k_finalize(
        const float* __restrict__ part, float* __restrict__ acc) {
    int i = blockIdx.x * 256 + threadIdx.x;
    int b = i >> 8, k = i & 255;
    float s = 0.f;
#pragma unroll
    for (int c = 0; c < 16; c++) s += part[(size_t)(b * 16 + c) * 256 + k];
    acc[i] = s;
}

__global__ __launch_bounds__(256) void k_norm(
        const unsigned short* __restrict__ y, const float* __restrict__ acc,
        const float* __restrict__ g, const float* __restrict__ bb,
        float* __restrict__ out) {
    size_t i = (size_t)blockIdx.x * 256 + threadIdx.x;
    int d = (int)(i % D);
    int b = (int)(i / ((size_t)S * D));
    float mu = acc[b * 256 + d] * (1.f / S);
    float var = acc[b * 256 + 128 + d] * (1.f / S) - mu * mu;
    float v = (bf2f(y[i]) - mu) * rsqrtf(var + EPSN);
    out[i] = v * g[d] + bb[d];
}

extern "C" void kernel_launch(void* const* d_in, const int* in_sizes, int n_in,
                              void* d_out, int out_size, void* d_ws, size_t ws_size,
                              hipStream_t stream) {
    const float* depot = (const float*)d_in[0];
    const float* node  = (const float*)d_in[1];
    const float* dist  = (const float*)d_in[2];
    const float* log_scale = (const float*)d_in[3];
    const int*   flag  = (const int*)d_in[4];
    const float* Wd   = (const float*)d_in[5];
    const float* bd   = (const float*)d_in[6];
    const float* Wn   = (const float*)d_in[7];
    const float* bn   = (const float*)d_in[8];
    const float* Win  = (const float*)d_in[9];
    const float* bin_ = (const float*)d_in[10];
    const float* Wout = (const float*)d_in[11];
    const float* bout = (const float*)d_in[12];
    const float* Wq   = (const float*)d_in[13];
    const float* Wk   = (const float*)d_in[14];
    const float* Wv   = (const float*)d_in[15];
    const float* alpha= (const float*)d_in[16];
    const float* g1   = (const float*)d_in[17];
    const float* b1   = (const float*)d_in[18];
    const float* W1   = (const float*)d_in[19];
    const float* bW1  = (const float*)d_in[20];
    const float* W2   = (const float*)d_in[21];
    const float* bW2  = (const float*)d_in[22];
    const float* g2   = (const float*)d_in[23];
    const float* b2   = (const float*)d_in[24];

    float* ws = (float*)d_ws;
    size_t nxd = (size_t)B * S * D;                       // 4,096,000
    unsigned short* ya = (unsigned short*)ws;             // bf16 residual streams
    unsigned short* yb = ya + nxd;
    float* part1 = ws + nxd;                              // (2*nxd shorts == nxd floats)
    float* part2 = part1 + 131072;
    float* accb2 = part2 + 131072;                        // B*256
    unsigned short* sqb = (unsigned short*)(accb2 + 8192);          // B*S*D bf16
    unsigned short* mT  = sqb + nxd;                                // B*16*256*64
    unsigned short* wbf = mT + (size_t)B * 16 * 256 * 64;           // L*WSTR
    unsigned short* nd  = wbf + (size_t)L * WSTR;                   // B*1000*1024

    k_wprep<<<dim3(88, 6), 256, 0, stream>>>(Wq, Wk, Wv, W1, W2, wbf);
    k_prep<<<B * S, 256, 0, stream>>>(dist, nd);
    k_embed<<<B * S, 128, 0, stream>>>(depot, node, Wd, bd, Wn, bn, yb);
    k_rowxform<<<B, 128, 0, stream>>>(yb, Win, bin_, flag, 0);
    k_rowxform<<<B, 128, 0, stream>>>(yb, Wout, bout, flag, 1);

    for (int l = 0; l < L; l++) {
        int hasnorm = (l > 0) ? 1 : 0;
        const float* gpn = g2 + (l > 0 ? (l - 1) : 0) * D;
        const float* bpn = b2 + (l > 0 ? (l - 1) : 0) * D;
        const unsigned short* wl = wbf + (size_t)l * WSTR;
        k_qkv<<<B * 16, 256, 0, stream>>>(yb, part2, hasnorm, gpn, bpn, wl, sqb, mT);
        k_attn<<<B * 16, 512, 0, stream>>>(yb, part2, hasnorm, gpn, bpn,
                                           sqb, mT, nd, log_scale, alpha, l, ya, part1);
        k_ffn<<<B * 16, 256, 0, stream>>>(ya, part1, g1 + l * D, b1 + l * D,
                                          wl + 49152, wl + 114688,
                                          bW1 + (size_t)l * F, bW2 + (size_t)l * D, yb, part2);
    }
    k_finalize<<<32, 256, 0, stream>>>(part2, accb2);
    k_norm<<<B * S * D / 256, 256, 0, stream>>>(yb, accb2, g2 + 5 * D, b2 + 5 * D, (float*)d_out);
}

// Round 19
// 544.630 us; speedup vs baseline: 1.2835x; 1.0161x over previous
//
#include <hip/hip_runtime.h>
#include <hip/hip_bf16.h>
#include <float.h>
#include <math.h>

#define B 32
#define NN 999
#define S 1000
#define D 128
#define F 512
#define L 6
#define EPSN 1e-5f
#define WSTR 180224   // per-layer bf16 weight stride: 3*16384 + 2*65536

typedef __attribute__((ext_vector_type(4))) float f32x4;
typedef __attribute__((ext_vector_type(4))) short s16x4;
typedef __attribute__((ext_vector_type(8))) short s16x8;

#if defined(__has_builtin)
#if __has_builtin(__builtin_amdgcn_mfma_f32_16x16x32_bf16)
#define HAVE_MFMA32 1
#endif
#endif

#ifdef HAVE_MFMA32
#define MFMA32(a, b, c) __builtin_amdgcn_mfma_f32_16x16x32_bf16((a), (b), (c), 0, 0, 0)
#else
static __device__ __forceinline__ f32x4 mfma32_asm(s16x8 a, s16x8 b, f32x4 c) {
    asm volatile("v_mfma_f32_16x16x32_bf16 %0, %1, %2, %0\n\ts_nop 7\n\ts_nop 7"
                 : "+v"(c) : "v"(a), "v"(b));
    return c;
}
#define MFMA32(a, b, c) mfma32_asm((a), (b), (c))
#endif

__device__ __forceinline__ void gload_lds16(const void* g, void* l) {
    __builtin_amdgcn_global_load_lds(
        (const __attribute__((address_space(1))) void*)g,
        (__attribute__((address_space(3))) void*)l, 16, 0, 0);
}

__device__ __forceinline__ float n2n(float v) {
    if (v != v) return 0.f;
    if (isinf(v)) return v > 0.f ? FLT_MAX : -FLT_MAX;
    return v;
}

__device__ __forceinline__ unsigned short f2bf(float x) {
    unsigned u = __float_as_uint(x);
    return (unsigned short)((u + 0x7fffu + ((u >> 16) & 1u)) >> 16);
}

__device__ __forceinline__ float bf2f(unsigned short v) {
    return __uint_as_float(((unsigned)v) << 16);
}

// ---------------- one-time: weights -> bf16 ----------------
// layout per layer (stride WSTR): Wq 0, Wk 16384, Wv 32768, W1 49152, W2 114688
__global__ __launch_bounds__(256) void k_wprep(
        const float* __restrict__ Wq, const float* __restrict__ Wk,
        const float* __restrict__ Wv, const float* __restrict__ W1,
        const float* __restrict__ W2, unsigned short* __restrict__ wbf) {
    int bx = blockIdx.x, l = blockIdx.y;
    const float* src; int doff, off;
    if (bx < 8)       { src = Wq + (size_t)l * 16384; doff = 0;      off = bx * 2048; }
    else if (bx < 16) { src = Wk + (size_t)l * 16384; doff = 16384;  off = (bx - 8) * 2048; }
    else if (bx < 24) { src = Wv + (size_t)l * 16384; doff = 32768;  off = (bx - 16) * 2048; }
    else if (bx < 56) { src = W1 + (size_t)l * 65536; doff = 49152;  off = (bx - 24) * 2048; }
    else              { src = W2 + (size_t)l * 65536; doff = 114688; off = (bx - 56) * 2048; }
    int i = off + threadIdx.x * 8;
    float4 a4 = *(const float4*)(src + i);
    float4 b4 = *(const float4*)(src + i + 4);
    s16x8 p = {(short)f2bf(a4.x), (short)f2bf(a4.y), (short)f2bf(a4.z), (short)f2bf(a4.w),
               (short)f2bf(b4.x), (short)f2bf(b4.y), (short)f2bf(b4.z), (short)f2bf(b4.w)};
    *(s16x8*)(wbf + (size_t)l * WSTR + doff + i) = p;
}

// ---------------- one-time prep: dist -> bf16 padded ----------------
__global__ __launch_bounds__(256) void k_prep(
        const float* __restrict__ dist, unsigned short* __restrict__ nd) {
    int row = blockIdx.x;
    int col = threadIdx.x * 4;
    unsigned short* op = nd + (size_t)row * 1024 + col;
    if (col < 1000) {
        float4 v = *(const float4*)(dist + (size_t)row * 1000 + col);
        s16x4 p = {(short)f2bf(v.x), (short)f2bf(v.y), (short)f2bf(v.z), (short)f2bf(v.w)};
        *(s16x4*)op = p;
    } else {
        s16x4 z = {0, 0, 0, 0};
        *(s16x4*)op = z;
    }
}

__global__ __launch_bounds__(128) void k_embed(
        const float* __restrict__ depot, const float* __restrict__ node,
        const float* __restrict__ Wd, const float* __restrict__ bd,
        const float* __restrict__ Wn, const float* __restrict__ bn,
        unsigned short* __restrict__ x) {
    int row = blockIdx.x;
    int b = row / S, s = row % S;
    int d = threadIdx.x;
    float o;
    if (s == 0) {
        float x0 = depot[b * 2 + 0], x1 = depot[b * 2 + 1];
        o = Wd[d * 2 + 0] * x0 + Wd[d * 2 + 1] * x1 + bd[d];
    } else {
        const float* p = node + ((size_t)b * NN + (s - 1)) * 3;
        o = Wn[d * 3 + 0] * p[0] + Wn[d * 3 + 1] * p[1] + Wn[d * 3 + 2] * p[2] + bn[d];
    }
    x[(size_t)row * D + d] = f2bf(o);
}

__global__ __launch_bounds__(128) void k_rowxform(
        unsigned short* __restrict__ x, const float* __restrict__ W,
        const float* __restrict__ bias, const int* __restrict__ flag, int mode) {
    int b = blockIdx.x;
    int d = threadIdx.x;
    __shared__ float row[D];
    int r = (mode == 0) ? 1 : (1 - flag[b]) * NN;
    unsigned short* xr = x + ((size_t)b * S + r) * D;
    row[d] = bf2f(xr[d]);
    __syncthreads();
    float acc = bias[d];
    for (int e = 0; e < D; e += 4) {
        const float4 w = *(const float4*)(W + (size_t)d * D + e);
        acc += w.x * row[e] + w.y * row[e + 1] + w.z * row[e + 2] + w.w * row[e + 3];
    }
    __syncthreads();
    xr[d] = f2bf(acc);
}

// ---------------- qkv: MFMA32, 2-row x 2-dcol wave tiling, swizzled mT (bf16 residual in) ----------------
__global__ __launch_bounds__(256) void k_qkv(
        const unsigned short* __restrict__ yprev, const float* __restrict__ part2, int hasnorm,
        const float* __restrict__ gp, const float* __restrict__ bp,
        const unsigned short* __restrict__ wl,
        unsigned short* __restrict__ sqb, unsigned short* __restrict__ mT) {
    int blk = blockIdx.x;
    int b = blk >> 4, rb = blk & 15;
    int s0 = rb * 64;
    int tid = threadIdx.x, lane = tid & 63, wid = tid >> 6;
    int wr2 = wid & 1, wc2 = wid >> 1;        // 32-row half, 64-d half
    __shared__ __align__(16) unsigned short lds[18432];  // xs[64*40]+wt[3][128*40]; reused tile[256*72]
    __shared__ float nsc[128], nsh[128];
    __shared__ float accv[256];
    unsigned short* xs = lds;
    unsigned short* wt0 = lds + 2560;

    if (hasnorm) {
        int st = tid >> 7, d = tid & 127;
        float s = 0.f;
#pragma unroll
        for (int c = 0; c < 16; c++) s += part2[(size_t)(b * 32 + c * 2 + st) * 128 + d];
        accv[tid] = s;
    }
    __syncthreads();
    if (tid < 128) {
        float scv = 1.f, shv = 0.f;
        if (hasnorm) {
            float mu = accv[tid] * (1.f / S);
            float var = accv[128 + tid] * (1.f / S) - mu * mu;
            float rs = rsqrtf(var + EPSN);
            scv = rs * gp[tid];
            shv = bp[tid] - mu * scv;
        }
        nsc[tid] = scv; nsh[tid] = shv;
    }
    __syncthreads();

    f32x4 acc[2][3][4];
#pragma unroll
    for (int rf = 0; rf < 2; rf++)
#pragma unroll
        for (int mm = 0; mm < 3; mm++)
#pragma unroll
            for (int cf = 0; cf < 4; cf++) acc[rf][mm][cf] = {0.f, 0.f, 0.f, 0.f};

    for (int k0 = 0; k0 < D; k0 += 32) {
        {
            int i = tid >> 2, kq = (tid & 3) * 8;
            int s = s0 + i;
            int gs = s < S ? s : S - 1;
            const unsigned short* gpx = yprev + ((size_t)b * S + gs) * D + k0 + kq;
            s16x8 v = *(const s16x8*)gpx;
            const float* scp = &nsc[k0 + kq];
            const float* shp = &nsh[k0 + kq];
            s16x8 p;
#pragma unroll
            for (int j = 0; j < 8; j++)
                p[j] = (short)f2bf(bf2f((unsigned short)v[j]) * scp[j] + shp[j]);
            *(s16x8*)&xs[i * 40 + kq] = p;
        }
#pragma unroll
        for (int u0 = 0; u0 < 6; u0++) {
            int u = tid + u0 * 256;
            int mm = u >> 9;
            int v = u & 511;
            int c = v >> 2, kq = (v & 3) * 8;
            s16x8 w = *(const s16x8*)(wl + (size_t)mm * 16384 + (size_t)c * D + k0 + kq);
            *(s16x8*)&wt0[mm * 5120 + c * 40 + kq] = w;
        }
        __syncthreads();
        {
            int g8 = (lane >> 4) * 8;   // k-octet offset within the 32-k chunk
            int arow0 = wr2 * 32 + (lane & 15);
            s16x8 a0 = *(const s16x8*)&xs[arow0 * 40 + g8];
            s16x8 a1 = *(const s16x8*)&xs[(arow0 + 16) * 40 + g8];
#pragma unroll
            for (int mm = 0; mm < 3; mm++)
#pragma unroll
                for (int cf = 0; cf < 4; cf++) {
                    int c = wc2 * 64 + cf * 16 + (lane & 15);
                    s16x8 bf = *(const s16x8*)&wt0[mm * 5120 + c * 40 + g8];
                    acc[0][mm][cf] = MFMA32(a0, bf, acc[0][mm][cf]);
                    acc[1][mm][cf] = MFMA32(a1, bf, acc[1][mm][cf]);
                }
        }
        __syncthreads();
    }

    // epilogue phase 1: acc -> tile[256 d][72]
    unsigned short* tile = lds;               // 256*72 = 18432
#pragma unroll
    for (int rf = 0; rf < 2; rf++) {
        int sl0 = wr2 * 32 + rf * 16 + (lane >> 4) * 4;
#pragma unroll
        for (int cf = 0; cf < 4; cf++) {
            int d = wc2 * 64 + cf * 16 + (lane & 15);
            s16x4 p0, p1;
#pragma unroll
            for (int r = 0; r < 4; r++) {
                int s = s0 + sl0 + r;
                if (s < S) {
                    float qv = acc[rf][0][cf][r], kv = acc[rf][1][cf][r], vv = acc[rf][2][cf][r];
                    float ek = __expf(kv);
                    sqb[((size_t)b * S + s) * D + d] = f2bf(1.f / (1.f + __expf(-qv)));
                    p0[r] = (short)f2bf(ek * vv);
                    p1[r] = (short)f2bf(ek);
                } else { p0[r] = 0; p1[r] = 0; }
            }
            *(s16x4*)&tile[d * 72 + sl0] = p0;
            *(s16x4*)&tile[(d + 128) * 72 + sl0] = p1;
        }
    }
    __syncthreads();
    // epilogue phase 2: permuted read, fully coalesced 32KB store
    {
        unsigned short* base = mT + (((size_t)b * 16 + rb) * 256) * 64;
#pragma unroll
        for (int j = 0; j < 8; j++) {
            int u = j * 256 + tid;
            int d = u >> 3, sp = u & 7;
            int o = sp ^ (d & 7);
            s16x8 v = *(const s16x8*)&tile[d * 72 + o * 8];
            *(s16x8*)(base + (size_t)u * 8) = v;
        }
    }
}

// ---------------- attention: 8 waves (2 row-halves x 4 col-quarters), dbuf LDS, gload_lds mT ----------------
__global__ __launch_bounds__(512, 2) void k_attn(
        const unsigned short* __restrict__ yprev, const float* __restrict__ part2, int hasnorm,
        const float* __restrict__ gp, const float* __restrict__ bp,
        const unsigned short* __restrict__ sqb,
        const unsigned short* __restrict__ mT, const unsigned short* __restrict__ nd,
        const float* __restrict__ log_scale, const float* __restrict__ alpha, int l,
        unsigned short* __restrict__ y, float* __restrict__ part) {
    int blk0 = blockIdx.x;
    int blk = (blk0 & 7) * 64 + (blk0 >> 3);  // XCD-bijective swizzle (512 % 8 == 0)
    int b = blk >> 4, ib = blk & 15;
    int i0 = ib * 64;
    int tid = threadIdx.x, lane = tid & 63, wid = tid >> 6;
    int wr = wid & 1, wc = wid >> 1;          // row half (32 rows), col quarter (cols wc*64..+64)
    __shared__ __align__(16) unsigned short esL[2][64 * 64];   // 16 KB dbuf, swizzled
    __shared__ __align__(16) unsigned short mtL[2][256 * 64];  // 64 KB dbuf
    float sc = log_scale[0] * alpha[l];

    // norm coefficients (accv scratch lives in esL before main loop)
    float* accvA = (float*)esL;
    if (hasnorm && tid < 256) {
        int st = tid >> 7, d = tid & 127;
        float s = 0.f;
#pragma unroll
        for (int c = 0; c < 16; c++) s += part2[(size_t)(b * 32 + c * 2 + st) * 128 + d];
        accvA[tid] = s;
    }
    __syncthreads();

    int wcm = wc & 1;                          // d-quarter within 0..127 for this wave
    float rsc[4], rsh[4];
#pragma unroll
    for (int cf = 0; cf < 4; cf++) {
        int d = wcm * 64 + cf * 16 + (lane & 15);
        float scv = 1.f, shv = 0.f;
        if (hasnorm) {
            float mu = accvA[d] * (1.f / S);
            float var = accvA[128 + d] * (1.f / S) - mu * mu;
            float rs = rsqrtf(var + EPSN);
            scv = rs * gp[d];
            shv = bp[d] - mu * scv;
        }
        rsc[cf] = scv; rsh[cf] = shv;
    }
    __syncthreads();   // done with accvA scratch before esL[0] is written

    f32x4 acc[2][4];
#pragma unroll
    for (int rf = 0; rf < 2; rf++)
#pragma unroll
        for (int cf = 0; cf < 4; cf++) acc[rf][cf] = {0.f, 0.f, 0.f, 0.f};

    // es staging: 1 octet/thread (row = tid>>3, octet og = tid&7)
    int erow = tid >> 3, og = tid & 7;
    int gi = i0 + erow; if (gi > 999) gi = 999;
    const unsigned short* ndr = nd + (size_t)b * 1000 * 1024 + (size_t)gi * 1024 + og * 8;
    const unsigned short* mtb = mT + (size_t)b * 16 * 16384;
    int esoff = erow * 64 + ((og ^ (erow & 7)) * 8);
    int ldsbase = (wid << 6) * 8;             // wave-uniform: wid*64 lanes * 8 shorts

    // prologue: stage chunk 0 (es via regs, mT direct-to-LDS), prefetch cn chunk 1
    s16x8 cn = *(const s16x8*)(ndr);
    {
        s16x8 o0;
#pragma unroll
        for (int j = 0; j < 8; j++)
            o0[j] = (short)f2bf(__expf(-sc * bf2f((unsigned short)cn[j])));
        *(s16x8*)&esL[0][esoff] = o0;
    }
    cn = *(const s16x8*)(ndr + 64);
#pragma unroll
    for (int j = 0; j < 4; j++)
        gload_lds16(mtb + (size_t)(j * 512 + tid) * 8, &mtL[0][j * 512 * 8 + ldsbase]);
    __syncthreads();

    int cur = 0;
    for (int kc = 0; kc < 16; kc++) {
        if (kc < 15) {
            // stage chunk kc+1 into buf[cur^1]: es from regs, mT direct-to-LDS
            s16x8 o0;
#pragma unroll
            for (int j = 0; j < 8; j++)
                o0[j] = (short)f2bf(__expf(-sc * bf2f((unsigned short)cn[j])));
            *(s16x8*)&esL[cur ^ 1][esoff] = o0;
#pragma unroll
            for (int j = 0; j < 4; j++)
                gload_lds16(mtb + (size_t)(kc + 1) * 16384 + (size_t)(j * 512 + tid) * 8,
                            &mtL[cur ^ 1][j * 512 * 8 + ldsbase]);
            int kn2 = (kc + 2 <= 15) ? kc + 2 : 15;
            cn = *(const s16x8*)(ndr + kn2 * 64);
        }
#pragma unroll
        for (int ks = 0; ks < 2; ks++) {
            int ag = ks * 4 + (lane >> 4);
            int arow0 = wr * 32 + (lane & 15);
            int arow1 = arow0 + 16;
            s16x8 a0 = *(const s16x8*)&esL[cur][arow0 * 64 + ((ag ^ (arow0 & 7)) * 8)];
            s16x8 a1 = *(const s16x8*)&esL[cur][arow1 * 64 + ((ag ^ (arow1 & 7)) * 8)];
            __builtin_amdgcn_s_setprio(1);
#pragma unroll
            for (int cf = 0; cf < 4; cf++) {
                int c = wc * 64 + cf * 16 + (lane & 15);
                s16x8 bf = *(const s16x8*)&mtL[cur][c * 64 + ((ag ^ (c & 7)) * 8)];
                acc[0][cf] = MFMA32(a0, bf, acc[0][cf]);
                acc[1][cf] = MFMA32(a1, bf, acc[1][cf]);
            }
            __builtin_amdgcn_s_setprio(0);
        }
        __syncthreads();   // drains vmcnt: buf[cur^1] ready; buf[cur] free for rewrite next iter
        cur ^= 1;
    }

    // epilogue: den waves (wc>=2) publish via LDS, num waves (wc<2) finish + stats
    float* pw = (float*)mtL[0];               // [64 rows][128 d] f32 = 32 KB
    if (wc >= 2) {
#pragma unroll
        for (int cf = 0; cf < 4; cf++) {
            int dcol = (wc - 2) * 64 + cf * 16 + (lane & 15);
#pragma unroll
            for (int rf = 0; rf < 2; rf++)
#pragma unroll
                for (int r = 0; r < 4; r++) {
                    int lrow = wr * 32 + rf * 16 + (lane >> 4) * 4 + r;
                    pw[lrow * 128 + dcol] = acc[rf][cf][r];
                }
        }
    }
    __syncthreads();
    float* sw = (float*)esL;                  // stats partials [2 row-halves][2 stat][128]
    if (wc < 2) {
#pragma unroll
        for (int cf = 0; cf < 4; cf++) {
            int d = wc * 64 + cf * 16 + (lane & 15);
            float s = 0.f, s2 = 0.f;
#pragma unroll
            for (int rf = 0; rf < 2; rf++)
#pragma unroll
                for (int r = 0; r < 4; r++) {
                    int lrow = wr * 32 + rf * 16 + (lane >> 4) * 4 + r;
                    int i = i0 + lrow;
                    if (i < S) {
                        size_t off = ((size_t)b * S + i) * D + d;
                        float w = n2n(acc[rf][cf][r]) / n2n(pw[lrow * 128 + d]);
                        float xv = bf2f(yprev[off]) * rsc[cf] + rsh[cf];
                        float yv = xv + bf2f(sqb[off]) * w;
                        y[off] = f2bf(yv);
                        s += yv;
                        s2 = fmaf(yv, yv, s2);
                    }
                }
            s += __shfl_xor(s, 16); s += __shfl_xor(s, 32);
            s2 += __shfl_xor(s2, 16); s2 += __shfl_xor(s2, 32);
            if (lane < 16) {
                sw[(wr * 2 + 0) * 128 + d] = s;
                sw[(wr * 2 + 1) * 128 + d] = s2;
            }
        }
    }
    __syncthreads();
    if (tid < 256) {
        int st = tid >> 7, d = tid & 127;
        float v = sw[(0 * 2 + st) * 128 + d] + sw[(1 * 2 + st) * 128 + d];
        part[((size_t)(b * 16 + ib) * 2 + st) * 128 + d] = v;
    }
}

// ---------------- fused FFN: 2x2 wave quadrants in both GEMMs (bf16 residual) ----------------
__global__ __launch_bounds__(256) void k_ffn(
        const unsigned short* __restrict__ ya, const float* __restrict__ part1,
        const float* __restrict__ gp, const float* __restrict__ bp,
        const unsigned short* __restrict__ w1b, const unsigned short* __restrict__ w2b,
        const float* __restrict__ bW1, const float* __restrict__ bW2,
        unsigned short* __restrict__ yb, float* __restrict__ part) {
    int blk = blockIdx.x;
    int b = blk >> 4, rb = blk & 15;
    int r0 = rb * 64;
    int tid = threadIdx.x, lane = tid & 63, wid = tid >> 6;
    int wr2 = wid & 1, wc2 = wid >> 1;        // 32-row half, col half
    __shared__ __align__(16) unsigned short hs[64 * 128];    // normed h bf16, octet-swizzled
    __shared__ __align__(16) unsigned short w1c[64 * 128];   // W1 chunk [64 f][128 k], swizzled
    __shared__ __align__(16) unsigned short tc[64 * 72];     // t chunk [64 row][64 f], stride 144B
    __shared__ __align__(16) unsigned short w2c[128 * 64];   // W2 chunk [128 d][64 f], swizzled
    __shared__ float nsc[128], nsh[128];
    __shared__ float accv[256];

    {
        int st = tid >> 7, d = tid & 127;
        float s = 0.f;
#pragma unroll
        for (int c = 0; c < 16; c++) s += part1[(size_t)(b * 32 + c * 2 + st) * 128 + d];
        accv[tid] = s;
    }
    __syncthreads();
    if (tid < 128) {
        float mu = accv[tid] * (1.f / S);
        float var = accv[128 + tid] * (1.f / S) - mu * mu;
        float rs = rsqrtf(var + EPSN);
        float scv = rs * gp[tid];
        nsc[tid] = scv;
        nsh[tid] = bp[tid] - mu * scv;
    }
    __syncthreads();

    // stage normed h (64 rows x 128 k), octet-swizzled (bf16 source)
    {
        int i = tid >> 2;
        int gs = r0 + i; if (gs >= S) gs = S - 1;
        const unsigned short* gpx = ya + ((size_t)b * S + gs) * D;
#pragma unroll
        for (int q = 0; q < 4; q++) {
            int col = (tid & 3) * 32 + q * 8;
            int g = col >> 3;
            s16x8 v = *(const s16x8*)(gpx + col);
            const float* scp = &nsc[col];
            const float* shp = &nsh[col];
            s16x8 p;
#pragma unroll
            for (int j = 0; j < 8; j++)
                p[j] = (short)f2bf(bf2f((unsigned short)v[j]) * scp[j] + shp[j]);
            *(s16x8*)&hs[i * 128 + ((g ^ (i & 7)) * 8)] = p;
        }
    }

    f32x4 yacc[2][4];
#pragma unroll
    for (int rf = 0; rf < 2; rf++)
#pragma unroll
        for (int cf = 0; cf < 4; cf++) yacc[rf][cf] = {0.f, 0.f, 0.f, 0.f};

    for (int fc = 0; fc < 8; fc++) {
        int c0 = fc * 64;
        // stage W1 chunk [64 f][128 k], swizzled
        {
            int f = tid >> 2;
#pragma unroll
            for (int q = 0; q < 4; q++) {
                int col = (tid & 3) * 32 + q * 8;
                int g = col >> 3;
                s16x8 w = *(const s16x8*)(w1b + (size_t)(c0 + f) * D + col);
                *(s16x8*)&w1c[f * 128 + ((g ^ (f & 7)) * 8)] = w;
            }
        }
        // stage W2 chunk [128 d][64 f], swizzled
        {
            int d2 = tid >> 1;
#pragma unroll
            for (int q = 0; q < 4; q++) {
                int g = (tid & 1) * 4 + q;
                s16x8 w = *(const s16x8*)(w2b + (size_t)d2 * F + c0 + g * 8);
                *(s16x8*)&w2c[d2 * 64 + ((g ^ (d2 & 7)) * 8)] = w;
            }
        }
        __syncthreads();
        // GEMM1: t = relu(h @ W1c^T + bW1); wave quadrant 32 rows x 32 cols
        f32x4 tacc[2][2];
#pragma unroll
        for (int rf = 0; rf < 2; rf++)
#pragma unroll
            for (int cf = 0; cf < 2; cf++) tacc[rf][cf] = {0.f, 0.f, 0.f, 0.f};
#pragma unroll
        for (int ks = 0; ks < 4; ks++) {
            int g = ks * 4 + (lane >> 4);
            int arow0 = wr2 * 32 + (lane & 15);
            int arow1 = arow0 + 16;
            s16x8 a0 = *(const s16x8*)&hs[arow0 * 128 + ((g ^ (arow0 & 7)) * 8)];
            s16x8 a1 = *(const s16x8*)&hs[arow1 * 128 + ((g ^ (arow1 & 7)) * 8)];
#pragma unroll
            for (int cf = 0; cf < 2; cf++) {
                int brow = wc2 * 32 + cf * 16 + (lane & 15);
                s16x8 bf = *(const s16x8*)&w1c[brow * 128 + ((g ^ (brow & 7)) * 8)];
                tacc[0][cf] = MFMA32(a0, bf, tacc[0][cf]);
                tacc[1][cf] = MFMA32(a1, bf, tacc[1][cf]);
            }
        }
#pragma unroll
        for (int rf = 0; rf < 2; rf++)
#pragma unroll
            for (int cf = 0; cf < 2; cf++) {
                int col = wc2 * 32 + cf * 16 + (lane & 15);
                float bias = bW1[c0 + col];
#pragma unroll
                for (int r = 0; r < 4; r++) {
                    int rl = wr2 * 32 + rf * 16 + (lane >> 4) * 4 + r;
                    tc[rl * 72 + col] = f2bf(fmaxf(tacc[rf][cf][r] + bias, 0.f));
                }
            }
        __syncthreads();
        // GEMM2: yacc += t @ W2c^T; wave quadrant 32 rows x 64 d-cols
#pragma unroll
        for (int ks = 0; ks < 2; ks++) {
            int ko = ks * 32 + (lane >> 4) * 8;
            int g = ks * 4 + (lane >> 4);
            int arow0 = wr2 * 32 + (lane & 15);
            int arow1 = arow0 + 16;
            s16x8 a0 = *(const s16x8*)&tc[arow0 * 72 + ko];
            s16x8 a1 = *(const s16x8*)&tc[arow1 * 72 + ko];
#pragma unroll
            for (int cf = 0; cf < 4; cf++) {
                int brow = wc2 * 64 + cf * 16 + (lane & 15);
                s16x8 bf = *(const s16x8*)&w2c[brow * 64 + ((g ^ (brow & 7)) * 8)];
                yacc[0][cf] = MFMA32(a0, bf, yacc[0][cf]);
                yacc[1][cf] = MFMA32(a1, bf, yacc[1][cf]);
            }
        }
        __syncthreads();
    }

    // epilogue: yb = h + ff + bias, stats (wave covers rows wr2*32..+32, d wc2*64..+64)
    float* pw = (float*)w1c;                  // [2 row-halves][2 stat][128] f32
#pragma unroll
    for (int cf = 0; cf < 4; cf++) {
        int d = wc2 * 64 + cf * 16 + (lane & 15);
        float bias = bW2[d];
        float s = 0.f, s2 = 0.f;
#pragma unroll
        for (int rf = 0; rf < 2; rf++)
#pragma unroll
            for (int r = 0; r < 4; r++) {
                int rl = wr2 * 32 + rf * 16 + (lane >> 4) * 4 + r;
                int row = r0 + rl;
                if (row < S) {
                    float hval = bf2f(hs[rl * 128 + (((d >> 3) ^ (rl & 7)) * 8) + (d & 7)]);
                    float yv = hval + yacc[rf][cf][r] + bias;
                    yb[((size_t)b * S + row) * D + d] = f2bf(yv);
                    s += yv;
                    s2 = fmaf(yv, yv, s2);
                }
            }
        s += __shfl_xor(s, 16); s += __shfl_xor(s, 32);
        s2 += __shfl_xor(s2, 16); s2 += __shfl_xor(s2, 32);
        if (lane < 16) {
            pw[(wr2 * 2 + 0) * 128 + d] = s;
            pw[(wr2 * 2 + 1) * 128 + d] = s2;
        }
    }
    __syncthreads();
    {
        int st = tid >> 7, d = tid & 127;
        float v = pw[(0 * 2 + st) * 128 + d] + pw[(1 * 2 + st) * 128 + d];
        part[((size_t)(b * 16 + rb) * 2 + st) * 128 + d] = v;
    }
}

// ---------------- final reduce + norm ----------------
__global__ __launch_bounds__(256) void k_finalize(
        const float* __restrict__ part, float* __restrict__ acc) {
    int i = blockIdx.x * 256 + threadIdx.x;
    int b = i >> 8, k = i & 255;
    float s = 0.f;
#pragma unroll
    for (int c = 0; c < 16; c++) s += part[(size_t)(b * 16 + c) * 256 + k];
    acc[i] = s;
}

__global__ __launch_bounds__(256) void k_norm(
        const unsigned short* __restrict__ y, const float* __restrict__ acc,
        const float* __restrict__ g, const float* __restrict__ bb,
        float* __restrict__ out) {
    size_t i = (size_t)blockIdx.x * 256 + threadIdx.x;
    int d = (int)(i % D);
    int b = (int)(i / ((size_t)S * D));
    float mu = acc[b * 256 + d] * (1.f / S);
    float var = acc[b * 256 + 128 + d] * (1.f / S) - mu * mu;
    float v = (bf2f(y[i]) - mu) * rsqrtf(var + EPSN);
    out[i] = v * g[d] + bb[d];
}

extern "C" void kernel_launch(void* const* d_in, const int* in_sizes, int n_in,
                              void* d_out, int out_size, void* d_ws, size_t ws_size,
                              hipStream_t stream) {
    const float* depot = (const float*)d_in[0];
    const float* node  = (const float*)d_in[1];
    const float* dist  = (const float*)d_in[2];
    const float* log_scale = (const float*)d_in[3];
    const int*   flag  = (const int*)d_in[4];
    const float* Wd   = (const float*)d_in[5];
    const float* bd   = (const float*)d_in[6];
    const float* Wn   = (const float*)d_in[7];
    const float* bn   = (const float*)d_in[8];
    const float* Win  = (const float*)d_in[9];
    const float* bin_ = (const float*)d_in[10];
    const float* Wout = (const float*)d_in[11];
    const float* bout = (const float*)d_in[12];
    const float* Wq   = (const float*)d_in[13];
    const float* Wk   = (const float*)d_in[14];
    const float* Wv   = (const float*)d_in[15];
    const float* alpha= (const float*)d_in[16];
    const float* g1   = (const float*)d_in[17];
    const float* b1   = (const float*)d_in[18];
    const float* W1   = (const float*)d_in[19];
    const float* bW1  = (const float*)d_in[20];
    const float* W2   = (const float*)d_in[21];
    const float* bW2  = (const float*)d_in[22];
    const float* g2   = (const float*)d_in[23];
    const float* b2   = (const float*)d_in[24];

    float* ws = (float*)d_ws;
    size_t nxd = (size_t)B * S * D;                       // 4,096,000
    unsigned short* ya = (unsigned short*)ws;             // bf16 residual streams
    unsigned short* yb = ya + nxd;
    float* part1 = ws + nxd;                              // (2*nxd shorts == nxd floats)
    float* part2 = part1 + 131072;
    float* accb2 = part2 + 131072;                        // B*256
    unsigned short* sqb = (unsigned short*)(accb2 + 8192);          // B*S*D bf16
    unsigned short* mT  = sqb + nxd;                                // B*16*256*64
    unsigned short* wbf = mT + (size_t)B * 16 * 256 * 64;           // L*WSTR
    unsigned short* nd  = wbf + (size_t)L * WSTR;                   // B*1000*1024

    k_wprep<<<dim3(88, 6), 256, 0, stream>>>(Wq, Wk, Wv, W1, W2, wbf);
    k_prep<<<B * S, 256, 0, stream>>>(dist, nd);
    k_embed<<<B * S, 128, 0, stream>>>(depot, node, Wd, bd, Wn, bn, yb);
    k_rowxform<<<B, 128, 0, stream>>>(yb, Win, bin_, flag, 0);
    k_rowxform<<<B, 128, 0, stream>>>(yb, Wout, bout, flag, 1);

    for (int l = 0; l < L; l++) {
        int hasnorm = (l > 0) ? 1 : 0;
        const float* gpn = g2 + (l > 0 ? (l - 1) : 0) * D;
        const float* bpn = b2 + (l > 0 ? (l - 1) : 0) * D;
        const unsigned short* wl = wbf + (size_t)l * WSTR;
        k_qkv<<<B * 16, 256, 0, stream>>>(yb, part2, hasnorm, gpn, bpn, wl, sqb, mT);
        k_attn<<<B * 16, 512, 0, stream>>>(yb, part2, hasnorm, gpn, bpn,
                                           sqb, mT, nd, log_scale, alpha, l, ya, part1);
        k_ffn<<<B * 16, 256, 0, stream>>>(ya, part1, g1 + l * D, b1 + l * D,
                                          wl + 49152, wl + 114688,
                                          bW1 + (size_t)l * F, bW2 + (size_t)l * D, yb, part2);
    }
    k_finalize<<<32, 256, 0, stream>>>(part2, accb2);
    k_norm<<<B * S * D / 256, 256, 0, stream>>>(yb, accb2, g2 + 5 * D, b2 + 5 * D, (float*)d_out);
}